// Round 1
// baseline (10970.000 us; speedup 1.0000x reference)
//
#include <hip/hip_runtime.h>
#include <hip/hip_bf16.h>
#include <math.h>

// ---------------------------------------------------------------------------
// VQ-VAE full forward, fp32 direct kernels. Correctness-first baseline.
// Shapes: B=8, x[8,3,256,256]; latent 64x64, D=128, K=1024.
// Outputs: d_out[0]=loss, d_out[1..1572864]=recon (NCHW), d_out[1572865]=perplexity
// ---------------------------------------------------------------------------

#define CC_COST 0.25

// ---------------- generic direct conv ----------------
// out[b][oc][y][x] = (OUT_RELU?relu:id)( sum_{c,dy,dx} f(in[b][c][y*S+dy-P][x*S+dx-P]) * w[oc][c][dy][dx]
//                                         + (ADD_RES ? res[idx] : 0) )
// f = relu if IN_RELU.
template<int K, int S, int P, bool IN_RELU, bool OUT_RELU, bool ADD_RES>
__global__ __launch_bounds__(256) void conv_direct(
    const float* __restrict__ in, const float* __restrict__ w,
    const float* __restrict__ res, float* __restrict__ out,
    int B, int Cin, int Cout, int Hin, int Win, int Hout, int Wout)
{
    int total = B * Cout * Hout * Wout;
    int idx = blockIdx.x * 256 + threadIdx.x;
    if (idx >= total) return;
    int x = idx % Wout; int t = idx / Wout;
    int y = t % Hout;   t /= Hout;
    int oc = t % Cout;  int b = t / Cout;

    int iy0 = y * S - P;
    int ix0 = x * S - P;
    const float* wp = w + oc * Cin * K * K;
    const float* ip = in + b * Cin * Hin * Win;

    float acc = 0.f;
    #pragma unroll 4
    for (int c = 0; c < Cin; ++c) {
        const float* ipc = ip + c * Hin * Win;
        const float* wpc = wp + c * K * K;
        #pragma unroll
        for (int dy = 0; dy < K; ++dy) {
            int iy = iy0 + dy;
            if ((unsigned)iy >= (unsigned)Hin) continue;
            const float* row = ipc + iy * Win;
            #pragma unroll
            for (int dx = 0; dx < K; ++dx) {
                int ix = ix0 + dx;
                if ((unsigned)ix >= (unsigned)Win) continue;
                float v = row[ix];
                if (IN_RELU) v = fmaxf(v, 0.f);
                acc = fmaf(v, wpc[dy * K + dx], acc);
            }
        }
    }
    if (ADD_RES) acc += res[idx];
    if (OUT_RELU) acc = fmaxf(acc, 0.f);
    out[idx] = acc;
}

// ---------------- transposed conv 4x4 s2 p1, relu(in), relu(out) ----------------
// torch layout w[Cin][Cout][4][4]; out[oy] gets taps where iy=(oy+1-ky)/2 integer.
__global__ __launch_bounds__(256) void deconv4x4_relu(
    const float* __restrict__ in,   // [B,Cin,Hin,Win], pre-activation (relu applied here)
    const float* __restrict__ w,    // [Cin][Cout][4][4]
    float* __restrict__ out,        // [B,Cout,2Hin,2Win]
    int B, int Cin, int Cout, int Hin, int Win)
{
    int Hout = Hin * 2, Wout = Win * 2;
    int total = B * Cout * Hout * Wout;
    int idx = blockIdx.x * 256 + threadIdx.x;
    if (idx >= total) return;
    int ox = idx % Wout; int t = idx / Wout;
    int oy = t % Hout;   t /= Hout;
    int oc = t % Cout;   int b = t / Cout;

    int ky0 = (oy + 1) & 1;   // wave-uniform (oy uniform per wave)
    const float* ip = in + b * Cin * Hin * Win;
    float acc = 0.f;
    for (int c = 0; c < Cin; ++c) {
        const float* ipc = ip + c * Hin * Win;
        const float* wpc = w + (c * Cout + oc) * 16;
        #pragma unroll
        for (int kk = 0; kk < 2; ++kk) {
            int ky = ky0 + kk * 2;
            int iy = (oy + 1 - ky) / 2;          // numerator guaranteed even
            if ((unsigned)iy >= (unsigned)Hin) continue;
            const float* row = ipc + iy * Win;
            #pragma unroll
            for (int kx = 0; kx < 4; ++kx) {
                int num = ox + 1 - kx;
                if (num & 1) continue;
                int ix = num / 2;
                if ((unsigned)ix >= (unsigned)Win) continue;
                float v = fmaxf(row[ix], 0.f);
                acc = fmaf(v, wpc[ky * 4 + kx], acc);
            }
        }
    }
    out[idx] = fmaxf(acc, 0.f);
}

// ---------------- codebook prep: transpose + ||e||^2 ----------------
__global__ void prep_codebook(const float* __restrict__ cb,
                              float* __restrict__ cbT,   // [128][1024]
                              float* __restrict__ ce2)   // [1024]
{
    int k = blockIdx.x * 256 + threadIdx.x;
    if (k >= 1024) return;
    float s = 0.f;
    for (int d = 0; d < 128; ++d) {
        float v = cb[k * 128 + d];
        cbT[d * 1024 + k] = v;
        s = fmaf(v, v, s);
    }
    ce2[k] = s;
}

__global__ void zero_counts_kernel(unsigned int* __restrict__ counts)
{
    int i = blockIdx.x * 256 + threadIdx.x;
    if (i < 1024) counts[i] = 0u;
}

// ---------------- VQ argmin: one wave per pixel ----------------
__global__ __launch_bounds__(256) void vq_argmin(
    const float* __restrict__ z,     // NCHW [8,128,64,64]
    const float* __restrict__ cbT,   // [128][1024]
    const float* __restrict__ ce2,   // [1024]
    int* __restrict__ idx_out,       // [32768]
    unsigned int* __restrict__ counts)
{
    __shared__ float zl[4][128];
    int wid  = threadIdx.x >> 6;
    int lane = threadIdx.x & 63;
    int pix = blockIdx.x * 4 + wid;          // 0..32767
    int b = pix >> 12;                        // 4096 pixels per batch
    int p = pix & 4095;

    zl[wid][lane]      = z[(b * 128 + lane)      * 4096 + p];
    zl[wid][lane + 64] = z[(b * 128 + lane + 64) * 4096 + p];
    __syncthreads();

    float best = 3.4e38f; int bidx = 0;
    for (int t = 0; t < 16; ++t) {
        int k = t * 64 + lane;
        float s = 0.f;
        #pragma unroll 8
        for (int d = 0; d < 128; ++d)
            s = fmaf(zl[wid][d], cbT[d * 1024 + k], s);
        float dist = ce2[k] - 2.f * s;        // + |z|^2 const: argmin-equivalent
        if (dist < best) { best = dist; bidx = k; }   // strict <: first-min per lane
    }
    // cross-lane arg-reduce, prefer smaller index on exact tie
    for (int off = 32; off > 0; off >>= 1) {
        float ob = __shfl_down(best, off);
        int   oi = __shfl_down(bidx, off);
        if (ob < best || (ob == best && oi < bidx)) { best = ob; bidx = oi; }
    }
    if (lane == 0) {
        idx_out[pix] = bidx;
        atomicAdd(&counts[bidx], 1u);
    }
}

// ---------------- gather quantized (NCHW) + deterministic loss partials ----------------
__global__ __launch_bounds__(256) void gather_q_loss(
    const float* __restrict__ z,     // NCHW
    const float* __restrict__ cbT,   // [128][1024]
    const int* __restrict__ idxv,    // [32768]
    float* __restrict__ q,           // NCHW
    double* __restrict__ partial)    // [gridDim.x]
{
    int e = blockIdx.x * 256 + threadIdx.x;   // 0 .. 4194303
    int p = e & 4095;
    int d = (e >> 12) & 127;
    int b = e >> 19;
    int iv = idxv[(b << 12) + p];
    float qv = cbT[d * 1024 + iv];
    float zv = z[e];
    q[e] = qv;
    float diff = qv - zv;
    float sq = diff * diff;
    // wave reduce
    for (int off = 32; off > 0; off >>= 1) sq += __shfl_down(sq, off);
    __shared__ float red[4];
    int wid = threadIdx.x >> 6, lane = threadIdx.x & 63;
    if (lane == 0) red[wid] = sq;
    __syncthreads();
    if (threadIdx.x == 0)
        partial[blockIdx.x] = (double)red[0] + red[1] + red[2] + red[3];
}

// ---------------- fused bilinear-2x (align_corners) + conv3x3 64->3 + 2*sigmoid-1 ----
__global__ __launch_bounds__(256) void upconv_sigmoid(
    const float* __restrict__ in,   // [B,64,128,128] post-relu
    const float* __restrict__ w,    // [3][64][3][3]
    float* __restrict__ out)        // [B,3,256,256]
{
    int idx = blockIdx.x * 256 + threadIdx.x;   // B*256*256
    if (idx >= 8 * 256 * 256) return;
    int x = idx & 255; int t = idx >> 8;
    int y = t & 255;   int b = t >> 8;

    const float scale = 127.0f / 255.0f;
    int ylo[3], yhi[3], xlo[3], xhi[3];
    float fy[3], fx[3];
    bool yv[3], xv[3];
    #pragma unroll
    for (int j = 0; j < 3; ++j) {
        int uy = y + j - 1;
        yv[j] = ((unsigned)uy < 256u);
        float pos = (yv[j] ? uy : 0) * scale;
        int lo = (int)floorf(pos);
        ylo[j] = lo; yhi[j] = min(lo + 1, 127); fy[j] = pos - (float)lo;

        int ux = x + j - 1;
        xv[j] = ((unsigned)ux < 256u);
        float p2 = (xv[j] ? ux : 0) * scale;
        int lo2 = (int)floorf(p2);
        xlo[j] = lo2; xhi[j] = min(lo2 + 1, 127); fx[j] = p2 - (float)lo2;
    }

    float acc0 = 0.f, acc1 = 0.f, acc2 = 0.f;
    const float* ip = in + b * 64 * 16384;
    for (int c = 0; c < 64; ++c) {
        const float* pc = ip + c * 16384;
        #pragma unroll
        for (int j = 0; j < 3; ++j) {
            if (!yv[j]) continue;
            const float* r0 = pc + ylo[j] * 128;
            const float* r1 = pc + yhi[j] * 128;
            float fyj = fy[j];
            #pragma unroll
            for (int i = 0; i < 3; ++i) {
                if (!xv[i]) continue;
                float a = r0[xlo[i]], bb = r0[xhi[i]];
                float cc = r1[xlo[i]], dd = r1[xhi[i]];
                float top = a + (bb - a) * fx[i];
                float bot = cc + (dd - cc) * fx[i];
                float U = top + (bot - top) * fyj;
                int widx = c * 9 + j * 3 + i;
                acc0 = fmaf(U, w[0 * 576 + widx], acc0);
                acc1 = fmaf(U, w[1 * 576 + widx], acc1);
                acc2 = fmaf(U, w[2 * 576 + widx], acc2);
            }
        }
    }
    int obase = b * 3 * 65536 + y * 256 + x;
    out[obase]            = 2.f / (1.f + expf(-acc0)) - 1.f;
    out[obase + 65536]    = 2.f / (1.f + expf(-acc1)) - 1.f;
    out[obase + 131072]   = 2.f / (1.f + expf(-acc2)) - 1.f;
}

// ---------------- finalize: loss + perplexity ----------------
__global__ __launch_bounds__(256) void finalize_kernel(
    const double* __restrict__ partial,      // [16384]
    const unsigned int* __restrict__ counts, // [1024]
    float* __restrict__ dout)                // dout[0]=loss, dout[1572865]=perplexity
{
    __shared__ double sd[256];
    __shared__ double lossSh;
    int tid = threadIdx.x;
    double s = 0.0;
    for (int i = tid; i < 16384; i += 256) s += partial[i];
    sd[tid] = s; __syncthreads();
    for (int off = 128; off > 0; off >>= 1) {
        if (tid < off) sd[tid] += sd[tid + off];
        __syncthreads();
    }
    if (tid == 0) lossSh = CC_COST * sd[0] / 4194304.0;
    __syncthreads();

    double h = 0.0;
    for (int k = tid; k < 1024; k += 256) {
        double p = (double)counts[k] / 32768.0;
        h += p * log(p + 1e-10);
    }
    sd[tid] = h; __syncthreads();
    for (int off = 128; off > 0; off >>= 1) {
        if (tid < off) sd[tid] += sd[tid + off];
        __syncthreads();
    }
    if (tid == 0) {
        dout[0]       = (float)lossSh;
        dout[1572865] = (float)exp(-sd[0]);
    }
}

// ---------------------------------------------------------------------------
extern "C" void kernel_launch(void* const* d_in, const int* in_sizes, int n_in,
                              void* d_out, int out_size, void* d_ws, size_t ws_size,
                              hipStream_t stream)
{
    const float* x        = (const float*)d_in[0];
    const float* enc_c1   = (const float*)d_in[1];
    const float* enc_c2   = (const float*)d_in[2];
    const float* enc_c3   = (const float*)d_in[3];
    const float* enc_r1a  = (const float*)d_in[4];
    const float* enc_r1b  = (const float*)d_in[5];
    const float* enc_r2a  = (const float*)d_in[6];
    const float* enc_r2b  = (const float*)d_in[7];
    const float* pre_vq_w = (const float*)d_in[8];
    const float* codebook = (const float*)d_in[9];
    const float* dec_c1   = (const float*)d_in[10];
    const float* dec_r1a  = (const float*)d_in[11];
    const float* dec_r1b  = (const float*)d_in[12];
    const float* dec_r2a  = (const float*)d_in[13];
    const float* dec_r2b  = (const float*)d_in[14];
    const float* dec_dc   = (const float*)d_in[15];
    const float* dec_c3   = (const float*)d_in[16];
    float* dout = (float*)d_out;

    char* ws = (char*)d_ws;
    float* h1   = (float*)ws;            ws += 33554432;  // [8,64,128,128]
    float* bufA = (float*)ws;            ws += 16777216;  // [8,128,64,64]
    float* bufB = (float*)ws;            ws += 16777216;  // [8,128,64,64]
    float* bufT = (float*)ws;            ws += 4194304;   // [8,32,64,64]
    float* zb   = (float*)ws;            ws += 16777216;  // z NCHW
    float* qb   = (float*)ws;            ws += 16777216;  // quantized NCHW
    float* cbT  = (float*)ws;            ws += 524288;    // [128][1024]
    float* ce2  = (float*)ws;            ws += 4096;      // [1024]
    int*   idxb = (int*)ws;              ws += 131072;    // [32768]
    unsigned int* counts = (unsigned int*)ws; ws += 4096; // [1024]
    double* partial = (double*)ws;       ws += 131072;    // [16384] doubles

    auto nb = [](int n) { return (n + 255) / 256; };

    // VQ prep (independent of encoder)
    zero_counts_kernel<<<4, 256, 0, stream>>>(counts);
    prep_codebook<<<4, 256, 0, stream>>>(codebook, cbT, ce2);

    // ---- encoder ----
    conv_direct<4,2,1,false,true ,false><<<nb(8*64*128*128), 256, 0, stream>>>(
        x, enc_c1, nullptr, h1, 8, 3, 64, 256, 256, 128, 128);
    conv_direct<4,2,1,false,true ,false><<<nb(8*128*64*64), 256, 0, stream>>>(
        h1, enc_c2, nullptr, bufA, 8, 64, 128, 128, 128, 64, 64);
    conv_direct<3,1,1,false,false,false><<<nb(8*128*64*64), 256, 0, stream>>>(
        bufA, enc_c3, nullptr, bufB, 8, 128, 128, 64, 64, 64, 64);
    // res block 1
    conv_direct<3,1,1,true ,false,false><<<nb(8*32*64*64), 256, 0, stream>>>(
        bufB, enc_r1a, nullptr, bufT, 8, 128, 32, 64, 64, 64, 64);
    conv_direct<1,1,0,true ,false,true ><<<nb(8*128*64*64), 256, 0, stream>>>(
        bufT, enc_r1b, bufB, bufB, 8, 32, 128, 64, 64, 64, 64);
    // res block 2
    conv_direct<3,1,1,true ,false,false><<<nb(8*32*64*64), 256, 0, stream>>>(
        bufB, enc_r2a, nullptr, bufT, 8, 128, 32, 64, 64, 64, 64);
    conv_direct<1,1,0,true ,false,true ><<<nb(8*128*64*64), 256, 0, stream>>>(
        bufT, enc_r2b, bufB, bufB, 8, 32, 128, 64, 64, 64, 64);
    // pre-VQ 1x1 (folds the res-stack's final relu via IN_RELU)
    conv_direct<1,1,0,true ,false,false><<<nb(8*128*64*64), 256, 0, stream>>>(
        bufB, pre_vq_w, nullptr, zb, 8, 128, 128, 64, 64, 64, 64);

    // ---- VQ ----
    vq_argmin<<<8192, 256, 0, stream>>>(zb, cbT, ce2, idxb, counts);
    gather_q_loss<<<16384, 256, 0, stream>>>(zb, cbT, idxb, qb, partial);

    // ---- decoder ----
    conv_direct<3,1,1,false,false,false><<<nb(8*128*64*64), 256, 0, stream>>>(
        qb, dec_c1, nullptr, bufA, 8, 128, 128, 64, 64, 64, 64);
    conv_direct<3,1,1,true ,false,false><<<nb(8*32*64*64), 256, 0, stream>>>(
        bufA, dec_r1a, nullptr, bufT, 8, 128, 32, 64, 64, 64, 64);
    conv_direct<1,1,0,true ,false,true ><<<nb(8*128*64*64), 256, 0, stream>>>(
        bufT, dec_r1b, bufA, bufA, 8, 32, 128, 64, 64, 64, 64);
    conv_direct<3,1,1,true ,false,false><<<nb(8*32*64*64), 256, 0, stream>>>(
        bufA, dec_r2a, nullptr, bufT, 8, 128, 32, 64, 64, 64, 64);
    conv_direct<1,1,0,true ,false,true ><<<nb(8*128*64*64), 256, 0, stream>>>(
        bufT, dec_r2b, bufA, bufA, 8, 32, 128, 64, 64, 64, 64);
    // transposed conv (res-stack final relu folded in), relu out -> h1 [8,64,128,128]
    deconv4x4_relu<<<nb(8*64*128*128), 256, 0, stream>>>(
        bufA, dec_dc, h1, 8, 128, 64, 64, 64);
    // fused bilinear2x + conv3x3 + 2*sigmoid-1 -> recon at dout+1
    upconv_sigmoid<<<nb(8*256*256), 256, 0, stream>>>(h1, dec_c3, dout + 1);

    // ---- scalars ----
    finalize_kernel<<<1, 256, 0, stream>>>(partial, counts, dout);
}

// Round 2
// 1995.949 us; speedup vs baseline: 5.4961x; 5.4961x over previous
//
#include <hip/hip_runtime.h>
#include <hip/hip_bf16.h>
#include <math.h>

#define CC_COST 0.25

// ===========================================================================
// VQ-VAE forward, fp32, register-blocked tiled conv kernels.
// d_out[0]=loss, d_out[1..1572864]=recon NCHW, d_out[1572865]=perplexity
// ===========================================================================

// ---------------- weight transforms ----------------
// OIHW [oc][c][kk] -> wT [c][kk][oc]
__global__ void wt_oihw_k(const float* __restrict__ w, float* __restrict__ wT,
                          int Cout, int Cin, int KK)
{
    int i = blockIdx.x * 256 + threadIdx.x;
    int total = Cout * Cin * KK;
    if (i >= total) return;
    int oc = i % Cout; int t2 = i / Cout; int t = t2 % KK; int c = t2 / KK;
    wT[i] = w[(oc * Cin + c) * KK + t];
}

// deconv torch layout [Cin=128][Cout=64][16] -> wT [c][16][oc]
__global__ void wt_deconv_k(const float* __restrict__ w, float* __restrict__ wT)
{
    int i = blockIdx.x * 256 + threadIdx.x;
    if (i >= 128 * 16 * 64) return;
    int oc = i & 63; int t = (i >> 6) & 15; int c = i >> 10;
    wT[i] = w[(c * 64 + oc) * 16 + t];
}

// dec_c3 [3][64][9] -> wT3 [c][9][3]
__global__ void wt_c3_k(const float* __restrict__ w, float* __restrict__ wT)
{
    int i = blockIdx.x * 256 + threadIdx.x;
    if (i >= 1728) return;
    int o = i % 3; int t = (i / 3) % 9; int c = i / 27;
    wT[i] = w[(o * 64 + c) * 9 + t];
}

// ---------------- conv 3x3 s1 p1 on 64x64, tiled ----------------
// threads = (COUT/OCB) x (64/PXB) = 256; one (b,y) row per block.
template<int CIN, int COUT, int OCB, int PXB, int CC, bool IN_RELU>
__global__ __launch_bounds__(256) void conv3x3_k(
    const float* __restrict__ in, const float* __restrict__ wT,
    float* __restrict__ out)
{
    constexpr int NPXG = 64 / PXB;
    constexpr int NOCG = COUT / OCB;
    static_assert(NPXG * NOCG == 256, "bad tile");
    constexpr int WTP = 68;   // 66 used cols, padded to mult-of-4 stride
    __shared__ __align__(16) float ls_in[CC][3][WTP];
    __shared__ __align__(16) float ls_w[CC][9][COUT];

    int tid = threadIdx.x;
    int pxg = tid % NPXG, ocg = tid / NPXG;
    int x0 = pxg * PXB, oc0 = ocg * OCB;
    int y = blockIdx.x & 63, b = blockIdx.x >> 6;
    const float* inb = in + (size_t)b * CIN * 4096;

    float acc[OCB][PXB];
    #pragma unroll
    for (int o = 0; o < OCB; ++o)
        #pragma unroll
        for (int p = 0; p < PXB; ++p) acc[o][p] = 0.f;

    for (int c0 = 0; c0 < CIN; c0 += CC) {
        __syncthreads();
        for (int i = tid; i < CC * 3 * 66; i += 256) {
            int xx = i % 66; int t = i / 66; int r = t % 3; int cc = t / 3;
            int gy = y - 1 + r, gx = xx - 1;
            float v = 0.f;
            if ((unsigned)gy < 64u && (unsigned)gx < 64u) {
                v = inb[(c0 + cc) * 4096 + gy * 64 + gx];
                if (IN_RELU) v = fmaxf(v, 0.f);
            }
            ls_in[cc][r][xx] = v;
        }
        const float* wsrc = wT + (size_t)c0 * 9 * COUT;
        for (int i = tid; i < CC * 9 * COUT; i += 256)
            (&ls_w[0][0][0])[i] = wsrc[i];
        __syncthreads();

        for (int cc = 0; cc < CC; ++cc) {
            float rv[3][PXB + 2];
            #pragma unroll
            for (int r = 0; r < 3; ++r) {
                const float* base = &ls_in[cc][r][x0];
                #pragma unroll
                for (int q = 0; q < PXB / 4; ++q) {
                    float4 v = *reinterpret_cast<const float4*>(base + 4 * q);
                    rv[r][4*q+0] = v.x; rv[r][4*q+1] = v.y;
                    rv[r][4*q+2] = v.z; rv[r][4*q+3] = v.w;
                }
                rv[r][PXB]     = base[PXB];
                rv[r][PXB + 1] = base[PXB + 1];
            }
            const float* lw = &ls_w[cc][0][0];
            #pragma unroll
            for (int dy = 0; dy < 3; ++dy) {
                #pragma unroll
                for (int dx = 0; dx < 3; ++dx) {
                    const float* wp = lw + (dy * 3 + dx) * COUT + oc0;
                    float wv[OCB];
                    if constexpr (OCB == 4) {
                        float4 w4 = *reinterpret_cast<const float4*>(wp);
                        wv[0] = w4.x; wv[1] = w4.y; wv[2] = w4.z; wv[3] = w4.w;
                    } else {
                        float2 w2 = *reinterpret_cast<const float2*>(wp);
                        wv[0] = w2.x; wv[1] = w2.y;
                    }
                    #pragma unroll
                    for (int p = 0; p < PXB; ++p) {
                        float iv = rv[dy][p + dx];
                        #pragma unroll
                        for (int o = 0; o < OCB; ++o)
                            acc[o][p] = fmaf(iv, wv[o], acc[o][p]);
                    }
                }
            }
        }
    }
    #pragma unroll
    for (int o = 0; o < OCB; ++o) {
        float* op = out + (((size_t)b * COUT + oc0 + o) * 64 + y) * 64 + x0;
        #pragma unroll
        for (int q = 0; q < PXB / 4; ++q) {
            float4 v = make_float4(acc[o][4*q], acc[o][4*q+1],
                                   acc[o][4*q+2], acc[o][4*q+3]);
            *reinterpret_cast<float4*>(op + 4 * q) = v;
        }
    }
}

// ---------------- conv 1x1 on 64x64 (COUT must be 128) ----------------
template<int CIN, int COUT, int CC, bool IN_RELU, bool ADD_RES>
__global__ __launch_bounds__(256) void conv1x1_k(
    const float* __restrict__ in, const float* __restrict__ wT,
    const float* __restrict__ res, float* __restrict__ out)
{
    static_assert(COUT == 128, "tile assumes 128");
    __shared__ __align__(16) float ls_in[CC][64];
    __shared__ __align__(16) float ls_w[CC][COUT];
    int tid = threadIdx.x;
    int pxg = tid & 7, ocg = tid >> 3;
    int x0 = pxg * 8, oc0 = ocg * 4;
    int y = blockIdx.x & 63, b = blockIdx.x >> 6;

    float acc[4][8];
    #pragma unroll
    for (int o = 0; o < 4; ++o)
        #pragma unroll
        for (int p = 0; p < 8; ++p) acc[o][p] = 0.f;

    for (int c0 = 0; c0 < CIN; c0 += CC) {
        __syncthreads();
        for (int i = tid; i < CC * 64; i += 256) {
            int xx = i & 63, cc = i >> 6;
            float v = in[(((size_t)b * CIN + c0 + cc) * 64 + y) * 64 + xx];
            if (IN_RELU) v = fmaxf(v, 0.f);
            ls_in[cc][xx] = v;
        }
        const float* wsrc = wT + (size_t)c0 * COUT;
        for (int i = tid; i < CC * COUT; i += 256)
            (&ls_w[0][0])[i] = wsrc[i];
        __syncthreads();

        for (int cc = 0; cc < CC; ++cc) {
            float rv[8];
            const float* base = &ls_in[cc][x0];
            float4 v0 = *reinterpret_cast<const float4*>(base);
            float4 v1 = *reinterpret_cast<const float4*>(base + 4);
            rv[0]=v0.x; rv[1]=v0.y; rv[2]=v0.z; rv[3]=v0.w;
            rv[4]=v1.x; rv[5]=v1.y; rv[6]=v1.z; rv[7]=v1.w;
            float4 w4 = *reinterpret_cast<const float4*>(&ls_w[cc][oc0]);
            float wv[4] = {w4.x, w4.y, w4.z, w4.w};
            #pragma unroll
            for (int p = 0; p < 8; ++p)
                #pragma unroll
                for (int o = 0; o < 4; ++o)
                    acc[o][p] = fmaf(rv[p], wv[o], acc[o][p]);
        }
    }
    #pragma unroll
    for (int o = 0; o < 4; ++o) {
        float* op = out + (((size_t)b * COUT + oc0 + o) * 64 + y) * 64 + x0;
        const float* rp = res + (((size_t)b * COUT + oc0 + o) * 64 + y) * 64 + x0;
        #pragma unroll
        for (int q = 0; q < 2; ++q) {
            float4 v = make_float4(acc[o][4*q], acc[o][4*q+1],
                                   acc[o][4*q+2], acc[o][4*q+3]);
            if (ADD_RES) {
                float4 r4 = *reinterpret_cast<const float4*>(rp + 4 * q);
                v.x += r4.x; v.y += r4.y; v.z += r4.z; v.w += r4.w;
            }
            *reinterpret_cast<float4*>(op + 4 * q) = v;
        }
    }
}

// ---------------- conv 4x4 s2 p1, relu out ----------------
template<int CIN, int COUT, int WOUT, int CC>
__global__ __launch_bounds__(256) void conv4x4s2_k(
    const float* __restrict__ in, const float* __restrict__ wT,
    float* __restrict__ out)
{
    constexpr int WIN = WOUT * 2;
    constexpr int NPXG = WOUT / 8, NOCG = COUT / 4;
    static_assert(NPXG * NOCG == 256, "bad tile");
    constexpr int WUSE = 2 * WOUT + 2;
    constexpr int WTP = (WUSE + 3) & ~3;
    __shared__ __align__(16) float ls_in[CC][4][WTP];
    __shared__ __align__(16) float ls_w[CC][16][COUT];

    int tid = threadIdx.x;
    int pxg = tid % NPXG, ocg = tid / NPXG;
    int x0 = pxg * 8, oc0 = ocg * 4;
    int y = blockIdx.x % WOUT, b = blockIdx.x / WOUT;
    const float* inb = in + (size_t)b * CIN * WIN * WIN;

    float acc[4][8];
    #pragma unroll
    for (int o = 0; o < 4; ++o)
        #pragma unroll
        for (int p = 0; p < 8; ++p) acc[o][p] = 0.f;

    for (int c0 = 0; c0 < CIN; c0 += CC) {
        __syncthreads();
        for (int i = tid; i < CC * 4 * WUSE; i += 256) {
            int xx = i % WUSE; int t = i / WUSE; int r = t & 3; int cc = t >> 2;
            int gy = 2 * y - 1 + r, gx = xx - 1;
            float v = 0.f;
            if ((unsigned)gy < (unsigned)WIN && (unsigned)gx < (unsigned)WIN)
                v = inb[(c0 + cc) * WIN * WIN + gy * WIN + gx];
            ls_in[cc][r][xx] = v;
        }
        const float* wsrc = wT + (size_t)c0 * 16 * COUT;
        for (int i = tid; i < CC * 16 * COUT; i += 256)
            (&ls_w[0][0][0])[i] = wsrc[i];
        __syncthreads();

        for (int cc = 0; cc < CC; ++cc) {
            const float* lw = &ls_w[cc][0][0];
            #pragma unroll
            for (int ky = 0; ky < 4; ++ky) {
                float rv[18];
                const float* base = &ls_in[cc][ky][2 * x0];
                #pragma unroll
                for (int q = 0; q < 4; ++q) {
                    float4 v = *reinterpret_cast<const float4*>(base + 4 * q);
                    rv[4*q]=v.x; rv[4*q+1]=v.y; rv[4*q+2]=v.z; rv[4*q+3]=v.w;
                }
                rv[16] = base[16]; rv[17] = base[17];
                #pragma unroll
                for (int kx = 0; kx < 4; ++kx) {
                    float4 w4 = *reinterpret_cast<const float4*>(
                        lw + (ky * 4 + kx) * COUT + oc0);
                    float wv[4] = {w4.x, w4.y, w4.z, w4.w};
                    #pragma unroll
                    for (int p = 0; p < 8; ++p) {
                        float iv = rv[2 * p + kx];
                        #pragma unroll
                        for (int o = 0; o < 4; ++o)
                            acc[o][p] = fmaf(iv, wv[o], acc[o][p]);
                    }
                }
            }
        }
    }
    #pragma unroll
    for (int o = 0; o < 4; ++o) {
        float* op = out + (((size_t)b * COUT + oc0 + o) * WOUT + y) * WOUT + x0;
        #pragma unroll
        for (int q = 0; q < 2; ++q) {
            float4 v = make_float4(fmaxf(acc[o][4*q],0.f), fmaxf(acc[o][4*q+1],0.f),
                                   fmaxf(acc[o][4*q+2],0.f), fmaxf(acc[o][4*q+3],0.f));
            *reinterpret_cast<float4*>(op + 4 * q) = v;
        }
    }
}

// ---------------- deconv 4x4 s2 p1, 128->64, relu(in) folded, relu out ------
#define DECONV_TAPS(RV, KY)                                                   \
    {                                                                         \
        int ky_ = (KY);                                                       \
        _Pragma("unroll")                                                     \
        for (int kx = 0; kx < 4; ++kx) {                                      \
            float4 w4 = *reinterpret_cast<const float4*>(                     \
                lw + (ky_ * 4 + kx) * 64 + oc0);                              \
            float wv[4] = {w4.x, w4.y, w4.z, w4.w};                           \
            if (kx & 1) {                                                     \
                _Pragma("unroll")                                             \
                for (int ph = 0; ph < 4; ++ph) {                              \
                    float iv = RV[(kx == 1) ? (ph + 1) : ph];                 \
                    _Pragma("unroll")                                         \
                    for (int o = 0; o < 4; ++o)                               \
                        acc[o][2*ph] = fmaf(iv, wv[o], acc[o][2*ph]);         \
                }                                                             \
            } else {                                                          \
                _Pragma("unroll")                                             \
                for (int ph = 0; ph < 4; ++ph) {                              \
                    float iv = RV[(kx == 0) ? (ph + 2) : (ph + 1)];           \
                    _Pragma("unroll")                                         \
                    for (int o = 0; o < 4; ++o)                               \
                        acc[o][2*ph+1] = fmaf(iv, wv[o], acc[o][2*ph+1]);     \
                }                                                             \
            }                                                                 \
        }                                                                     \
    }

template<int CC>
__global__ __launch_bounds__(256) void deconv_k(
    const float* __restrict__ in,   // [8,128,64,64] pre-relu
    const float* __restrict__ wT,   // [c][16][64]
    float* __restrict__ out)        // [8,64,128,128]
{
    __shared__ __align__(16) float ls_in[CC][2][68];
    __shared__ __align__(16) float ls_w[CC][16][64];
    int tid = threadIdx.x;
    int pxg = tid & 15, ocg = tid >> 4;
    int x0 = pxg * 8, oc0 = ocg * 4, xh = pxg * 4;
    int oy = blockIdx.x & 127, b = blockIdx.x >> 7;
    int r1 = (oy + 1) >> 1;
    int ky0 = (oy + 1) & 1;
    const float* inb = in + (size_t)b * 128 * 4096;

    float acc[4][8];
    #pragma unroll
    for (int o = 0; o < 4; ++o)
        #pragma unroll
        for (int p = 0; p < 8; ++p) acc[o][p] = 0.f;

    for (int c0 = 0; c0 < 128; c0 += CC) {
        __syncthreads();
        for (int i = tid; i < CC * 2 * 66; i += 256) {
            int xx = i % 66; int t = i / 66; int rr = t & 1; int cc = t >> 1;
            int iy = r1 - 1 + rr, gx = xx - 1;
            float v = 0.f;
            if ((unsigned)iy < 64u && (unsigned)gx < 64u)
                v = fmaxf(inb[(c0 + cc) * 4096 + iy * 64 + gx], 0.f);
            ls_in[cc][rr][xx] = v;
        }
        const float* wsrc = wT + (size_t)c0 * 16 * 64;
        for (int i = tid; i < CC * 16 * 64; i += 256)
            (&ls_w[0][0][0])[i] = wsrc[i];
        __syncthreads();

        for (int cc = 0; cc < CC; ++cc) {
            float rvA[6], rvB[6];
            {
                const float* bA = &ls_in[cc][1][xh];
                float4 v = *reinterpret_cast<const float4*>(bA);
                rvA[0]=v.x; rvA[1]=v.y; rvA[2]=v.z; rvA[3]=v.w;
                rvA[4]=bA[4]; rvA[5]=bA[5];
                const float* bB = &ls_in[cc][0][xh];
                float4 u = *reinterpret_cast<const float4*>(bB);
                rvB[0]=u.x; rvB[1]=u.y; rvB[2]=u.z; rvB[3]=u.w;
                rvB[4]=bB[4]; rvB[5]=bB[5];
            }
            const float* lw = &ls_w[cc][0][0];
            DECONV_TAPS(rvA, ky0);
            DECONV_TAPS(rvB, ky0 + 2);
        }
    }
    #pragma unroll
    for (int o = 0; o < 4; ++o) {
        float* op = out + (((size_t)b * 64 + oc0 + o) * 128 + oy) * 128 + x0;
        #pragma unroll
        for (int q = 0; q < 2; ++q) {
            float4 v = make_float4(fmaxf(acc[o][4*q],0.f), fmaxf(acc[o][4*q+1],0.f),
                                   fmaxf(acc[o][4*q+2],0.f), fmaxf(acc[o][4*q+3],0.f));
            *reinterpret_cast<float4*>(op + 4 * q) = v;
        }
    }
}

// ---------------- fused bilinear-2x(align) + conv3x3 64->3 + 2*sigmoid-1 ----
template<int CC>
__global__ __launch_bounds__(256) void upconv_k(
    const float* __restrict__ in,    // h1 [8,64,128,128] post-relu
    const float* __restrict__ wT3,   // [64][9][3]
    float* __restrict__ out)         // [8,3,256,256]
{
    __shared__ __align__(16) float ls_u[CC][6][260];
    __shared__ float ls_w[64 * 27];
    int tid = threadIdx.x;
    int pxg = tid & 63, row = tid >> 6;
    int x0 = pxg * 4;
    int yblk = blockIdx.x & 63, b = blockIdx.x >> 6;
    int y0 = yblk * 4, y = y0 + row;
    const float SCL = 127.0f / 255.0f;
    const float* hb = in + (size_t)b * 64 * 16384;

    for (int i = tid; i < 1728; i += 256) ls_w[i] = wT3[i];

    float acc[3][4];
    #pragma unroll
    for (int o = 0; o < 3; ++o)
        #pragma unroll
        for (int p = 0; p < 4; ++p) acc[o][p] = 0.f;

    for (int c0 = 0; c0 < 64; c0 += CC) {
        __syncthreads();
        for (int i = tid; i < CC * 6 * 258; i += 256) {
            int xx = i % 258; int t = i / 258; int r = t % 6; int cc = t / 6;
            int uy = y0 - 1 + r, gx = xx - 1;
            float v = 0.f;
            if ((unsigned)uy < 256u && (unsigned)gx < 256u) {
                float py = uy * SCL;
                int ylo = (int)py; int yhi = min(ylo + 1, 127); float fy = py - ylo;
                float px = gx * SCL;
                int xlo = (int)px; int xhi = min(xlo + 1, 127); float fx = px - xlo;
                const float* hp = hb + (c0 + cc) * 16384 + ylo * 128;
                const float* hq = hb + (c0 + cc) * 16384 + yhi * 128;
                float a = hp[xlo], b2 = hp[xhi], c2 = hq[xlo], d2 = hq[xhi];
                float top = a + (b2 - a) * fx;
                float bot = c2 + (d2 - c2) * fx;
                v = top + (bot - top) * fy;
            }
            ls_u[cc][r][xx] = v;
        }
        __syncthreads();

        for (int cc = 0; cc < CC; ++cc) {
            #pragma unroll
            for (int j = 0; j < 3; ++j) {
                float rv[6];
                const float* base = &ls_u[cc][row + j][x0];
                float4 v = *reinterpret_cast<const float4*>(base);
                rv[0]=v.x; rv[1]=v.y; rv[2]=v.z; rv[3]=v.w;
                rv[4]=base[4]; rv[5]=base[5];
                #pragma unroll
                for (int i2 = 0; i2 < 3; ++i2) {
                    const float* wp = &ls_w[((c0 + cc) * 9 + (j * 3 + i2)) * 3];
                    float w0 = wp[0], w1 = wp[1], w2 = wp[2];
                    #pragma unroll
                    for (int p = 0; p < 4; ++p) {
                        float iv = rv[p + i2];
                        acc[0][p] = fmaf(iv, w0, acc[0][p]);
                        acc[1][p] = fmaf(iv, w1, acc[1][p]);
                        acc[2][p] = fmaf(iv, w2, acc[2][p]);
                    }
                }
            }
        }
    }
    #pragma unroll
    for (int o = 0; o < 3; ++o) {
        float4 v;
        v.x = 2.f / (1.f + expf(-acc[o][0])) - 1.f;
        v.y = 2.f / (1.f + expf(-acc[o][1])) - 1.f;
        v.z = 2.f / (1.f + expf(-acc[o][2])) - 1.f;
        v.w = 2.f / (1.f + expf(-acc[o][3])) - 1.f;
        float* op = out + (((size_t)b * 3 + o) * 256 + y) * 256 + x0;
        *reinterpret_cast<float4*>(op) = v;
    }
}

// ---------------- codebook prep ----------------
__global__ void prep_codebook(const float* __restrict__ cb,
                              float* __restrict__ cbT, float* __restrict__ ce2)
{
    int k = blockIdx.x * 256 + threadIdx.x;
    if (k >= 1024) return;
    float s = 0.f;
    for (int d = 0; d < 128; ++d) {
        float v = cb[k * 128 + d];
        cbT[d * 1024 + k] = v;
        s = fmaf(v, v, s);
    }
    ce2[k] = s;
}

__global__ void zero_counts_kernel(unsigned int* __restrict__ counts)
{
    int i = blockIdx.x * 256 + threadIdx.x;
    if (i < 1024) counts[i] = 0u;
}

// ---------------- VQ argmin: one wave per pixel ----------------
__global__ __launch_bounds__(256) void vq_argmin(
    const float* __restrict__ z, const float* __restrict__ cbT,
    const float* __restrict__ ce2, int* __restrict__ idx_out,
    unsigned int* __restrict__ counts)
{
    __shared__ float zl[4][128];
    int wid = threadIdx.x >> 6, lane = threadIdx.x & 63;
    int pix = blockIdx.x * 4 + wid;
    int b = pix >> 12, p = pix & 4095;

    zl[wid][lane]      = z[((size_t)b * 128 + lane)      * 4096 + p];
    zl[wid][lane + 64] = z[((size_t)b * 128 + lane + 64) * 4096 + p];
    __syncthreads();

    float best = 3.4e38f; int bidx = 0;
    for (int t = 0; t < 16; ++t) {
        int k = t * 64 + lane;
        float s = 0.f;
        #pragma unroll 8
        for (int d = 0; d < 128; ++d)
            s = fmaf(zl[wid][d], cbT[d * 1024 + k], s);
        float dist = ce2[k] - 2.f * s;
        if (dist < best) { best = dist; bidx = k; }
    }
    for (int off = 32; off > 0; off >>= 1) {
        float ob = __shfl_down(best, off);
        int   oi = __shfl_down(bidx, off);
        if (ob < best || (ob == best && oi < bidx)) { best = ob; bidx = oi; }
    }
    if (lane == 0) {
        idx_out[pix] = bidx;
        atomicAdd(&counts[bidx], 1u);
    }
}

// ---------------- gather quantized + deterministic loss partials ------------
__global__ __launch_bounds__(256) void gather_q_loss(
    const float* __restrict__ z, const float* __restrict__ cbT,
    const int* __restrict__ idxv, float* __restrict__ q,
    double* __restrict__ partial)
{
    int e = blockIdx.x * 256 + threadIdx.x;
    int p = e & 4095;
    int d = (e >> 12) & 127;
    int b = e >> 19;
    int iv = idxv[(b << 12) + p];
    float qv = cbT[d * 1024 + iv];
    float zv = z[e];
    q[e] = qv;
    float diff = qv - zv;
    float sq = diff * diff;
    for (int off = 32; off > 0; off >>= 1) sq += __shfl_down(sq, off);
    __shared__ float red[4];
    int wid = threadIdx.x >> 6, lane = threadIdx.x & 63;
    if (lane == 0) red[wid] = sq;
    __syncthreads();
    if (threadIdx.x == 0)
        partial[blockIdx.x] = (double)red[0] + red[1] + red[2] + red[3];
}

// ---------------- finalize ----------------
__global__ __launch_bounds__(256) void finalize_kernel(
    const double* __restrict__ partial, const unsigned int* __restrict__ counts,
    float* __restrict__ dout)
{
    __shared__ double sd[256];
    __shared__ double lossSh;
    int tid = threadIdx.x;
    double s = 0.0;
    for (int i = tid; i < 16384; i += 256) s += partial[i];
    sd[tid] = s; __syncthreads();
    for (int off = 128; off > 0; off >>= 1) {
        if (tid < off) sd[tid] += sd[tid + off];
        __syncthreads();
    }
    if (tid == 0) lossSh = CC_COST * sd[0] / 4194304.0;
    __syncthreads();

    double h = 0.0;
    for (int k = tid; k < 1024; k += 256) {
        double pp = (double)counts[k] / 32768.0;
        h += pp * log(pp + 1e-10);
    }
    sd[tid] = h; __syncthreads();
    for (int off = 128; off > 0; off >>= 1) {
        if (tid < off) sd[tid] += sd[tid + off];
        __syncthreads();
    }
    if (tid == 0) {
        dout[0]       = (float)lossSh;
        dout[1572865] = (float)exp(-sd[0]);
    }
}

// ===========================================================================
extern "C" void kernel_launch(void* const* d_in, const int* in_sizes, int n_in,
                              void* d_out, int out_size, void* d_ws, size_t ws_size,
                              hipStream_t stream)
{
    const float* x        = (const float*)d_in[0];
    const float* enc_c1   = (const float*)d_in[1];
    const float* enc_c2   = (const float*)d_in[2];
    const float* enc_c3   = (const float*)d_in[3];
    const float* enc_r1a  = (const float*)d_in[4];
    const float* enc_r1b  = (const float*)d_in[5];
    const float* enc_r2a  = (const float*)d_in[6];
    const float* enc_r2b  = (const float*)d_in[7];
    const float* pre_vq_w = (const float*)d_in[8];
    const float* codebook = (const float*)d_in[9];
    const float* dec_c1   = (const float*)d_in[10];
    const float* dec_r1a  = (const float*)d_in[11];
    const float* dec_r1b  = (const float*)d_in[12];
    const float* dec_r2a  = (const float*)d_in[13];
    const float* dec_r2b  = (const float*)d_in[14];
    const float* dec_dc   = (const float*)d_in[15];
    const float* dec_c3   = (const float*)d_in[16];
    float* dout = (float*)d_out;

    char* wsp = (char*)d_ws;
    auto alloc = [&](size_t bytes) {
        void* p = (void*)wsp;
        wsp += (bytes + 255) & ~(size_t)255;
        return p;
    };
    float* h1   = (float*)alloc(8ull*64*128*128*4);   // 32MB; also qb alias
    float* bufA = (float*)alloc(8ull*128*64*64*4);    // 16MB; also zb alias
    float* bufB = (float*)alloc(8ull*128*64*64*4);    // 16MB
    float* bufT = (float*)alloc(8ull*32*64*64*4);     // 4MB
    float* cbT  = (float*)alloc(128*1024*4);
    float* ce2  = (float*)alloc(1024*4);
    int*   idxb = (int*)alloc(32768*4);
    unsigned int* counts = (unsigned int*)alloc(1024*4);
    double* partial = (double*)alloc(16384*8);
    float* wt_ec1  = (float*)alloc(3072*4);
    float* wt_ec2  = (float*)alloc(131072*4);
    float* wt_ec3  = (float*)alloc(147456*4);
    float* wt_er1a = (float*)alloc(36864*4);
    float* wt_er1b = (float*)alloc(4096*4);
    float* wt_er2a = (float*)alloc(36864*4);
    float* wt_er2b = (float*)alloc(4096*4);
    float* wt_pvq  = (float*)alloc(16384*4);
    float* wt_dc1  = (float*)alloc(147456*4);
    float* wt_dr1a = (float*)alloc(36864*4);
    float* wt_dr1b = (float*)alloc(4096*4);
    float* wt_dr2a = (float*)alloc(36864*4);
    float* wt_dr2b = (float*)alloc(4096*4);
    float* wt_ddc  = (float*)alloc(131072*4);
    float* wt_dc3  = (float*)alloc(1728*4);
    float* zb = bufA;   // alias: pre_vq out, dead before dec_c1 writes bufA
    float* qb = h1;     // alias: dead before deconv overwrites h1

    auto nb = [](int n) { return (n + 255) / 256; };

    // VQ prep
    zero_counts_kernel<<<4, 256, 0, stream>>>(counts);
    prep_codebook<<<4, 256, 0, stream>>>(codebook, cbT, ce2);

    // weight transforms
    wt_oihw_k<<<nb(3072),   256, 0, stream>>>(enc_c1,  wt_ec1,  64, 3, 16);
    wt_oihw_k<<<nb(131072), 256, 0, stream>>>(enc_c2,  wt_ec2, 128, 64, 16);
    wt_oihw_k<<<nb(147456), 256, 0, stream>>>(enc_c3,  wt_ec3, 128, 128, 9);
    wt_oihw_k<<<nb(36864),  256, 0, stream>>>(enc_r1a, wt_er1a, 32, 128, 9);
    wt_oihw_k<<<nb(4096),   256, 0, stream>>>(enc_r1b, wt_er1b, 128, 32, 1);
    wt_oihw_k<<<nb(36864),  256, 0, stream>>>(enc_r2a, wt_er2a, 32, 128, 9);
    wt_oihw_k<<<nb(4096),   256, 0, stream>>>(enc_r2b, wt_er2b, 128, 32, 1);
    wt_oihw_k<<<nb(16384),  256, 0, stream>>>(pre_vq_w, wt_pvq, 128, 128, 1);
    wt_oihw_k<<<nb(147456), 256, 0, stream>>>(dec_c1,  wt_dc1, 128, 128, 9);
    wt_oihw_k<<<nb(36864),  256, 0, stream>>>(dec_r1a, wt_dr1a, 32, 128, 9);
    wt_oihw_k<<<nb(4096),   256, 0, stream>>>(dec_r1b, wt_dr1b, 128, 32, 1);
    wt_oihw_k<<<nb(36864),  256, 0, stream>>>(dec_r2a, wt_dr2a, 32, 128, 9);
    wt_oihw_k<<<nb(4096),   256, 0, stream>>>(dec_r2b, wt_dr2b, 128, 32, 1);
    wt_deconv_k<<<nb(131072), 256, 0, stream>>>(dec_dc, wt_ddc);
    wt_c3_k<<<nb(1728), 256, 0, stream>>>(dec_c3, wt_dc3);

    // ---- encoder ----
    conv4x4s2_k<3, 64, 128, 3><<<1024, 256, 0, stream>>>(x, wt_ec1, h1);
    conv4x4s2_k<64, 128, 64, 2><<<512, 256, 0, stream>>>(h1, wt_ec2, bufA);
    conv3x3_k<128, 128, 4, 8, 4, false><<<512, 256, 0, stream>>>(bufA, wt_ec3, bufB);
    conv3x3_k<128, 32, 2, 4, 8, true><<<512, 256, 0, stream>>>(bufB, wt_er1a, bufT);
    conv1x1_k<32, 128, 32, true, true><<<512, 256, 0, stream>>>(bufT, wt_er1b, bufB, bufB);
    conv3x3_k<128, 32, 2, 4, 8, true><<<512, 256, 0, stream>>>(bufB, wt_er2a, bufT);
    conv1x1_k<32, 128, 32, true, true><<<512, 256, 0, stream>>>(bufT, wt_er2b, bufB, bufB);
    conv1x1_k<128, 128, 32, true, false><<<512, 256, 0, stream>>>(bufB, wt_pvq, bufB, zb);

    // ---- VQ ----
    vq_argmin<<<8192, 256, 0, stream>>>(zb, cbT, ce2, idxb, counts);
    gather_q_loss<<<16384, 256, 0, stream>>>(zb, cbT, idxb, qb, partial);

    // ---- decoder ----
    conv3x3_k<128, 128, 4, 8, 4, false><<<512, 256, 0, stream>>>(qb, wt_dc1, bufA);
    conv3x3_k<128, 32, 2, 4, 8, true><<<512, 256, 0, stream>>>(bufA, wt_dr1a, bufT);
    conv1x1_k<32, 128, 32, true, true><<<512, 256, 0, stream>>>(bufT, wt_dr1b, bufA, bufA);
    conv3x3_k<128, 32, 2, 4, 8, true><<<512, 256, 0, stream>>>(bufA, wt_dr2a, bufT);
    conv1x1_k<32, 128, 32, true, true><<<512, 256, 0, stream>>>(bufT, wt_dr2b, bufA, bufA);
    deconv_k<4><<<1024, 256, 0, stream>>>(bufA, wt_ddc, h1);
    upconv_k<2><<<512, 256, 0, stream>>>(h1, wt_dc3, dout + 1);

    // ---- scalars ----
    finalize_kernel<<<1, 256, 0, stream>>>(partial, counts, dout);
}

// Round 4
// 1668.417 us; speedup vs baseline: 6.5751x; 1.1963x over previous
//
#include <hip/hip_runtime.h>
#include <hip/hip_bf16.h>
#include <math.h>

#define CC_COST 0.25

// ===========================================================================
// VQ-VAE forward, fp32, register-blocked tiled conv kernels + GEMM-style VQ.
// d_out[0]=loss, d_out[1..1572864]=recon NCHW, d_out[1572865]=perplexity
// ===========================================================================

// ---------------- weight transforms ----------------
// OIHW [oc][c][kk] -> wT [c][kk][oc]
__global__ void wt_oihw_k(const float* __restrict__ w, float* __restrict__ wT,
                          int Cout, int Cin, int KK)
{
    int i = blockIdx.x * 256 + threadIdx.x;
    int total = Cout * Cin * KK;
    if (i >= total) return;
    int oc = i % Cout; int t2 = i / Cout; int t = t2 % KK; int c = t2 / KK;
    wT[i] = w[(oc * Cin + c) * KK + t];
}

// deconv torch layout [Cin=128][Cout=64][16] -> wT [c][16][oc]
__global__ void wt_deconv_k(const float* __restrict__ w, float* __restrict__ wT)
{
    int i = blockIdx.x * 256 + threadIdx.x;
    if (i >= 128 * 16 * 64) return;
    int oc = i & 63; int t = (i >> 6) & 15; int c = i >> 10;
    wT[i] = w[(c * 64 + oc) * 16 + t];
}

// dec_c3 [3][64][9] -> wT3 [c][9][3]
__global__ void wt_c3_k(const float* __restrict__ w, float* __restrict__ wT)
{
    int i = blockIdx.x * 256 + threadIdx.x;
    if (i >= 1728) return;
    int o = i % 3; int t = (i / 3) % 9; int c = i / 27;
    wT[i] = w[(o * 64 + c) * 9 + t];
}

// ---------------- conv 3x3 s1 p1 on 64x64, tiled ----------------
template<int CIN, int COUT, int OCB, int PXB, int CC, bool IN_RELU>
__global__ __launch_bounds__(256) void conv3x3_k(
    const float* __restrict__ in, const float* __restrict__ wT,
    float* __restrict__ out)
{
    constexpr int NPXG = 64 / PXB;
    constexpr int NOCG = COUT / OCB;
    static_assert(NPXG * NOCG == 256, "bad tile");
    constexpr int WTP = 68;
    __shared__ __align__(16) float ls_in[CC][3][WTP];
    __shared__ __align__(16) float ls_w[CC][9][COUT];

    int tid = threadIdx.x;
    int pxg = tid % NPXG, ocg = tid / NPXG;
    int x0 = pxg * PXB, oc0 = ocg * OCB;
    int y = blockIdx.x & 63, b = blockIdx.x >> 6;
    const float* inb = in + (size_t)b * CIN * 4096;

    float acc[OCB][PXB];
    #pragma unroll
    for (int o = 0; o < OCB; ++o)
        #pragma unroll
        for (int p = 0; p < PXB; ++p) acc[o][p] = 0.f;

    for (int c0 = 0; c0 < CIN; c0 += CC) {
        __syncthreads();
        for (int i = tid; i < CC * 3 * 66; i += 256) {
            int xx = i % 66; int t = i / 66; int r = t % 3; int cc = t / 3;
            int gy = y - 1 + r, gx = xx - 1;
            float v = 0.f;
            if ((unsigned)gy < 64u && (unsigned)gx < 64u) {
                v = inb[(c0 + cc) * 4096 + gy * 64 + gx];
                if (IN_RELU) v = fmaxf(v, 0.f);
            }
            ls_in[cc][r][xx] = v;
        }
        const float* wsrc = wT + (size_t)c0 * 9 * COUT;
        for (int i = tid; i < CC * 9 * COUT; i += 256)
            (&ls_w[0][0][0])[i] = wsrc[i];
        __syncthreads();

        for (int cc = 0; cc < CC; ++cc) {
            float rv[3][PXB + 2];
            #pragma unroll
            for (int r = 0; r < 3; ++r) {
                const float* base = &ls_in[cc][r][x0];
                #pragma unroll
                for (int q = 0; q < PXB / 4; ++q) {
                    float4 v = *reinterpret_cast<const float4*>(base + 4 * q);
                    rv[r][4*q+0] = v.x; rv[r][4*q+1] = v.y;
                    rv[r][4*q+2] = v.z; rv[r][4*q+3] = v.w;
                }
                rv[r][PXB]     = base[PXB];
                rv[r][PXB + 1] = base[PXB + 1];
            }
            const float* lw = &ls_w[cc][0][0];
            #pragma unroll
            for (int dy = 0; dy < 3; ++dy) {
                #pragma unroll
                for (int dx = 0; dx < 3; ++dx) {
                    const float* wp = lw + (dy * 3 + dx) * COUT + oc0;
                    float wv[OCB];
                    if constexpr (OCB == 4) {
                        float4 w4 = *reinterpret_cast<const float4*>(wp);
                        wv[0] = w4.x; wv[1] = w4.y; wv[2] = w4.z; wv[3] = w4.w;
                    } else {
                        float2 w2 = *reinterpret_cast<const float2*>(wp);
                        wv[0] = w2.x; wv[1] = w2.y;
                    }
                    #pragma unroll
                    for (int p = 0; p < PXB; ++p) {
                        float iv = rv[dy][p + dx];
                        #pragma unroll
                        for (int o = 0; o < OCB; ++o)
                            acc[o][p] = fmaf(iv, wv[o], acc[o][p]);
                    }
                }
            }
        }
    }
    #pragma unroll
    for (int o = 0; o < OCB; ++o) {
        float* op = out + (((size_t)b * COUT + oc0 + o) * 64 + y) * 64 + x0;
        #pragma unroll
        for (int q = 0; q < PXB / 4; ++q) {
            float4 v = make_float4(acc[o][4*q], acc[o][4*q+1],
                                   acc[o][4*q+2], acc[o][4*q+3]);
            *reinterpret_cast<float4*>(op + 4 * q) = v;
        }
    }
}

// ---------------- conv 1x1 on 64x64 (COUT must be 128) ----------------
template<int CIN, int COUT, int CC, bool IN_RELU, bool ADD_RES>
__global__ __launch_bounds__(256) void conv1x1_k(
    const float* __restrict__ in, const float* __restrict__ wT,
    const float* __restrict__ res, float* __restrict__ out)
{
    static_assert(COUT == 128, "tile assumes 128");
    __shared__ __align__(16) float ls_in[CC][64];
    __shared__ __align__(16) float ls_w[CC][COUT];
    int tid = threadIdx.x;
    int pxg = tid & 7, ocg = tid >> 3;
    int x0 = pxg * 8, oc0 = ocg * 4;
    int y = blockIdx.x & 63, b = blockIdx.x >> 6;

    float acc[4][8];
    #pragma unroll
    for (int o = 0; o < 4; ++o)
        #pragma unroll
        for (int p = 0; p < 8; ++p) acc[o][p] = 0.f;

    for (int c0 = 0; c0 < CIN; c0 += CC) {
        __syncthreads();
        for (int i = tid; i < CC * 64; i += 256) {
            int xx = i & 63, cc = i >> 6;
            float v = in[(((size_t)b * CIN + c0 + cc) * 64 + y) * 64 + xx];
            if (IN_RELU) v = fmaxf(v, 0.f);
            ls_in[cc][xx] = v;
        }
        const float* wsrc = wT + (size_t)c0 * COUT;
        for (int i = tid; i < CC * COUT; i += 256)
            (&ls_w[0][0])[i] = wsrc[i];
        __syncthreads();

        for (int cc = 0; cc < CC; ++cc) {
            float rv[8];
            const float* base = &ls_in[cc][x0];
            float4 v0 = *reinterpret_cast<const float4*>(base);
            float4 v1 = *reinterpret_cast<const float4*>(base + 4);
            rv[0]=v0.x; rv[1]=v0.y; rv[2]=v0.z; rv[3]=v0.w;
            rv[4]=v1.x; rv[5]=v1.y; rv[6]=v1.z; rv[7]=v1.w;
            float4 w4 = *reinterpret_cast<const float4*>(&ls_w[cc][oc0]);
            float wv[4] = {w4.x, w4.y, w4.z, w4.w};
            #pragma unroll
            for (int p = 0; p < 8; ++p)
                #pragma unroll
                for (int o = 0; o < 4; ++o)
                    acc[o][p] = fmaf(rv[p], wv[o], acc[o][p]);
        }
    }
    #pragma unroll
    for (int o = 0; o < 4; ++o) {
        float* op = out + (((size_t)b * COUT + oc0 + o) * 64 + y) * 64 + x0;
        const float* rp = res + (((size_t)b * COUT + oc0 + o) * 64 + y) * 64 + x0;
        #pragma unroll
        for (int q = 0; q < 2; ++q) {
            float4 v = make_float4(acc[o][4*q], acc[o][4*q+1],
                                   acc[o][4*q+2], acc[o][4*q+3]);
            if (ADD_RES) {
                float4 r4 = *reinterpret_cast<const float4*>(rp + 4 * q);
                v.x += r4.x; v.y += r4.y; v.z += r4.z; v.w += r4.w;
            }
            *reinterpret_cast<float4*>(op + 4 * q) = v;
        }
    }
}

// ---------------- conv 4x4 s2 p1, relu out ----------------
template<int CIN, int COUT, int WOUT, int CC>
__global__ __launch_bounds__(256) void conv4x4s2_k(
    const float* __restrict__ in, const float* __restrict__ wT,
    float* __restrict__ out)
{
    constexpr int WIN = WOUT * 2;
    constexpr int NPXG = WOUT / 8, NOCG = COUT / 4;
    static_assert(NPXG * NOCG == 256, "bad tile");
    constexpr int WUSE = 2 * WOUT + 2;
    constexpr int WTP = (WUSE + 3) & ~3;
    __shared__ __align__(16) float ls_in[CC][4][WTP];
    __shared__ __align__(16) float ls_w[CC][16][COUT];

    int tid = threadIdx.x;
    int pxg = tid % NPXG, ocg = tid / NPXG;
    int x0 = pxg * 8, oc0 = ocg * 4;
    int y = blockIdx.x % WOUT, b = blockIdx.x / WOUT;
    const float* inb = in + (size_t)b * CIN * WIN * WIN;

    float acc[4][8];
    #pragma unroll
    for (int o = 0; o < 4; ++o)
        #pragma unroll
        for (int p = 0; p < 8; ++p) acc[o][p] = 0.f;

    for (int c0 = 0; c0 < CIN; c0 += CC) {
        __syncthreads();
        for (int i = tid; i < CC * 4 * WUSE; i += 256) {
            int xx = i % WUSE; int t = i / WUSE; int r = t & 3; int cc = t >> 2;
            int gy = 2 * y - 1 + r, gx = xx - 1;
            float v = 0.f;
            if ((unsigned)gy < (unsigned)WIN && (unsigned)gx < (unsigned)WIN)
                v = inb[(c0 + cc) * WIN * WIN + gy * WIN + gx];
            ls_in[cc][r][xx] = v;
        }
        const float* wsrc = wT + (size_t)c0 * 16 * COUT;
        for (int i = tid; i < CC * 16 * COUT; i += 256)
            (&ls_w[0][0][0])[i] = wsrc[i];
        __syncthreads();

        for (int cc = 0; cc < CC; ++cc) {
            const float* lw = &ls_w[cc][0][0];
            #pragma unroll
            for (int ky = 0; ky < 4; ++ky) {
                float rv[18];
                const float* base = &ls_in[cc][ky][2 * x0];
                #pragma unroll
                for (int q = 0; q < 4; ++q) {
                    float4 v = *reinterpret_cast<const float4*>(base + 4 * q);
                    rv[4*q]=v.x; rv[4*q+1]=v.y; rv[4*q+2]=v.z; rv[4*q+3]=v.w;
                }
                rv[16] = base[16]; rv[17] = base[17];
                #pragma unroll
                for (int kx = 0; kx < 4; ++kx) {
                    float4 w4 = *reinterpret_cast<const float4*>(
                        lw + (ky * 4 + kx) * COUT + oc0);
                    float wv[4] = {w4.x, w4.y, w4.z, w4.w};
                    #pragma unroll
                    for (int p = 0; p < 8; ++p) {
                        float iv = rv[2 * p + kx];
                        #pragma unroll
                        for (int o = 0; o < 4; ++o)
                            acc[o][p] = fmaf(iv, wv[o], acc[o][p]);
                    }
                }
            }
        }
    }
    #pragma unroll
    for (int o = 0; o < 4; ++o) {
        float* op = out + (((size_t)b * COUT + oc0 + o) * WOUT + y) * WOUT + x0;
        #pragma unroll
        for (int q = 0; q < 2; ++q) {
            float4 v = make_float4(fmaxf(acc[o][4*q],0.f), fmaxf(acc[o][4*q+1],0.f),
                                   fmaxf(acc[o][4*q+2],0.f), fmaxf(acc[o][4*q+3],0.f));
            *reinterpret_cast<float4*>(op + 4 * q) = v;
        }
    }
}

// ---------------- deconv 4x4 s2 p1, 128->64, relu(in) folded, relu out ------
#define DECONV_TAPS(RV, KY)                                                   \
    {                                                                         \
        int ky_ = (KY);                                                       \
        _Pragma("unroll")                                                     \
        for (int kx = 0; kx < 4; ++kx) {                                      \
            float4 w4 = *reinterpret_cast<const float4*>(                     \
                lw + (ky_ * 4 + kx) * 64 + oc0);                              \
            float wv[4] = {w4.x, w4.y, w4.z, w4.w};                           \
            if (kx & 1) {                                                     \
                _Pragma("unroll")                                             \
                for (int ph = 0; ph < 4; ++ph) {                              \
                    float iv = RV[(kx == 1) ? (ph + 1) : ph];                 \
                    _Pragma("unroll")                                         \
                    for (int o = 0; o < 4; ++o)                               \
                        acc[o][2*ph] = fmaf(iv, wv[o], acc[o][2*ph]);         \
                }                                                             \
            } else {                                                          \
                _Pragma("unroll")                                             \
                for (int ph = 0; ph < 4; ++ph) {                              \
                    float iv = RV[(kx == 0) ? (ph + 2) : (ph + 1)];           \
                    _Pragma("unroll")                                         \
                    for (int o = 0; o < 4; ++o)                               \
                        acc[o][2*ph+1] = fmaf(iv, wv[o], acc[o][2*ph+1]);     \
                }                                                             \
            }                                                                 \
        }                                                                     \
    }

template<int CC>
__global__ __launch_bounds__(256) void deconv_k(
    const float* __restrict__ in, const float* __restrict__ wT,
    float* __restrict__ out)
{
    __shared__ __align__(16) float ls_in[CC][2][68];
    __shared__ __align__(16) float ls_w[CC][16][64];
    int tid = threadIdx.x;
    int pxg = tid & 15, ocg = tid >> 4;
    int x0 = pxg * 8, oc0 = ocg * 4, xh = pxg * 4;
    int oy = blockIdx.x & 127, b = blockIdx.x >> 7;
    int r1 = (oy + 1) >> 1;
    int ky0 = (oy + 1) & 1;
    const float* inb = in + (size_t)b * 128 * 4096;

    float acc[4][8];
    #pragma unroll
    for (int o = 0; o < 4; ++o)
        #pragma unroll
        for (int p = 0; p < 8; ++p) acc[o][p] = 0.f;

    for (int c0 = 0; c0 < 128; c0 += CC) {
        __syncthreads();
        for (int i = tid; i < CC * 2 * 66; i += 256) {
            int xx = i % 66; int t = i / 66; int rr = t & 1; int cc = t >> 1;
            int iy = r1 - 1 + rr, gx = xx - 1;
            float v = 0.f;
            if ((unsigned)iy < 64u && (unsigned)gx < 64u)
                v = fmaxf(inb[(c0 + cc) * 4096 + iy * 64 + gx], 0.f);
            ls_in[cc][rr][xx] = v;
        }
        const float* wsrc = wT + (size_t)c0 * 16 * 64;
        for (int i = tid; i < CC * 16 * 64; i += 256)
            (&ls_w[0][0][0])[i] = wsrc[i];
        __syncthreads();

        for (int cc = 0; cc < CC; ++cc) {
            float rvA[6], rvB[6];
            {
                const float* bA = &ls_in[cc][1][xh];
                float4 v = *reinterpret_cast<const float4*>(bA);
                rvA[0]=v.x; rvA[1]=v.y; rvA[2]=v.z; rvA[3]=v.w;
                rvA[4]=bA[4]; rvA[5]=bA[5];
                const float* bB = &ls_in[cc][0][xh];
                float4 u = *reinterpret_cast<const float4*>(bB);
                rvB[0]=u.x; rvB[1]=u.y; rvB[2]=u.z; rvB[3]=u.w;
                rvB[4]=bB[4]; rvB[5]=bB[5];
            }
            const float* lw = &ls_w[cc][0][0];
            DECONV_TAPS(rvA, ky0);
            DECONV_TAPS(rvB, ky0 + 2);
        }
    }
    #pragma unroll
    for (int o = 0; o < 4; ++o) {
        float* op = out + (((size_t)b * 64 + oc0 + o) * 128 + oy) * 128 + x0;
        #pragma unroll
        for (int q = 0; q < 2; ++q) {
            float4 v = make_float4(fmaxf(acc[o][4*q],0.f), fmaxf(acc[o][4*q+1],0.f),
                                   fmaxf(acc[o][4*q+2],0.f), fmaxf(acc[o][4*q+3],0.f));
            *reinterpret_cast<float4*>(op + 4 * q) = v;
        }
    }
}

// ---------------- fused bilinear-2x(align) + conv3x3 64->3 + 2*sigmoid-1 ----
template<int CC>
__global__ __launch_bounds__(256) void upconv_k(
    const float* __restrict__ in, const float* __restrict__ wT3,
    float* __restrict__ out)
{
    __shared__ __align__(16) float ls_u[CC][6][260];
    __shared__ float ls_w[64 * 27];
    int tid = threadIdx.x;
    int pxg = tid & 63, row = tid >> 6;
    int x0 = pxg * 4;
    int yblk = blockIdx.x & 63, b = blockIdx.x >> 6;
    int y0 = yblk * 4, y = y0 + row;
    const float SCL = 127.0f / 255.0f;
    const float* hb = in + (size_t)b * 64 * 16384;

    for (int i = tid; i < 1728; i += 256) ls_w[i] = wT3[i];

    float acc[3][4];
    #pragma unroll
    for (int o = 0; o < 3; ++o)
        #pragma unroll
        for (int p = 0; p < 4; ++p) acc[o][p] = 0.f;

    for (int c0 = 0; c0 < 64; c0 += CC) {
        __syncthreads();
        for (int i = tid; i < CC * 6 * 258; i += 256) {
            int xx = i % 258; int t = i / 258; int r = t % 6; int cc = t / 6;
            int uy = y0 - 1 + r, gx = xx - 1;
            float v = 0.f;
            if ((unsigned)uy < 256u && (unsigned)gx < 256u) {
                float py = uy * SCL;
                int ylo = (int)py; int yhi = min(ylo + 1, 127); float fy = py - ylo;
                float px = gx * SCL;
                int xlo = (int)px; int xhi = min(xlo + 1, 127); float fx = px - xlo;
                const float* hp = hb + (c0 + cc) * 16384 + ylo * 128;
                const float* hq = hb + (c0 + cc) * 16384 + yhi * 128;
                float a = hp[xlo], b2 = hp[xhi], c2 = hq[xlo], d2 = hq[xhi];
                float top = a + (b2 - a) * fx;
                float bot = c2 + (d2 - c2) * fx;
                v = top + (bot - top) * fy;
            }
            ls_u[cc][r][xx] = v;
        }
        __syncthreads();

        for (int cc = 0; cc < CC; ++cc) {
            #pragma unroll
            for (int j = 0; j < 3; ++j) {
                float rv[6];
                const float* base = &ls_u[cc][row + j][x0];
                float4 v = *reinterpret_cast<const float4*>(base);
                rv[0]=v.x; rv[1]=v.y; rv[2]=v.z; rv[3]=v.w;
                rv[4]=base[4]; rv[5]=base[5];
                #pragma unroll
                for (int i2 = 0; i2 < 3; ++i2) {
                    const float* wp = &ls_w[((c0 + cc) * 9 + (j * 3 + i2)) * 3];
                    float w0 = wp[0], w1 = wp[1], w2 = wp[2];
                    #pragma unroll
                    for (int p = 0; p < 4; ++p) {
                        float iv = rv[p + i2];
                        acc[0][p] = fmaf(iv, w0, acc[0][p]);
                        acc[1][p] = fmaf(iv, w1, acc[1][p]);
                        acc[2][p] = fmaf(iv, w2, acc[2][p]);
                    }
                }
            }
        }
    }
    #pragma unroll
    for (int o = 0; o < 3; ++o) {
        float4 v;
        v.x = 2.f / (1.f + expf(-acc[o][0])) - 1.f;
        v.y = 2.f / (1.f + expf(-acc[o][1])) - 1.f;
        v.z = 2.f / (1.f + expf(-acc[o][2])) - 1.f;
        v.w = 2.f / (1.f + expf(-acc[o][3])) - 1.f;
        float* op = out + (((size_t)b * 3 + o) * 256 + y) * 256 + x0;
        *reinterpret_cast<float4*>(op) = v;
    }
}

// ---------------- codebook prep ----------------
__global__ void prep_codebook(const float* __restrict__ cb,
                              float* __restrict__ cbT, float* __restrict__ ce2)
{
    int k = blockIdx.x * 256 + threadIdx.x;
    if (k >= 1024) return;
    float s = 0.f;
    for (int d = 0; d < 128; ++d) {
        float v = cb[k * 128 + d];
        cbT[d * 1024 + k] = v;
        s = fmaf(v, v, s);
    }
    ce2[k] = s;
}

__global__ void zero_counts_kernel(unsigned int* __restrict__ counts)
{
    int i = blockIdx.x * 256 + threadIdx.x;
    if (i < 1024) counts[i] = 0u;
}

// ---------------- fused VQ: GEMM-style argmin + gather + q-write + loss -----
// 512 threads, 64 pixels/block, 512 blocks. 8x8 register tile per thread.
__global__ __launch_bounds__(512) void vq_fused(
    const float* __restrict__ z,     // NCHW [8,128,64,64]
    const float* __restrict__ cb,    // original [1024][128]
    const float* __restrict__ cbT,   // [128][1024]
    const float* __restrict__ ce2,   // [1024]
    unsigned int* __restrict__ counts,
    float* __restrict__ q,           // NCHW
    double* __restrict__ partial)    // [512]
{
    __shared__ float zl[128][64];    // 32 KB
    __shared__ int sidx[64];
    __shared__ float red[8];

    int tid = threadIdx.x;
    int codeg = tid & 63;            // lane within wave
    int pixg  = tid >> 6;            // wave id (0..7) -> 8 pixels each
    int b  = blockIdx.x >> 6;
    int p0 = (blockIdx.x & 63) * 64;

    // stage z tile: [128 d][64 pix]
    for (int i = tid; i < 8192; i += 512) {
        int d = i >> 6, pix = i & 63;
        zl[d][pix] = z[((size_t)b * 128 + d) * 4096 + p0 + pix];
    }
    __syncthreads();

    float best[8];
    int   bidx[8];
    #pragma unroll
    for (int j = 0; j < 8; ++j) { best[j] = 3.4e38f; bidx[j] = 0; }

    // k-tiles of 512 codes: each thread 8 pixels x 8 codes
    for (int kt = 0; kt < 2; ++kt) {
        int k0 = kt * 512 + codeg * 8;
        float acc[8][8];
        #pragma unroll
        for (int p = 0; p < 8; ++p)
            #pragma unroll
            for (int c = 0; c < 8; ++c) acc[p][c] = 0.f;

        const float* cbp = cbT + k0;
        for (int d = 0; d < 128; ++d) {
            float4 z0 = *reinterpret_cast<const float4*>(&zl[d][pixg * 8]);
            float4 z1 = *reinterpret_cast<const float4*>(&zl[d][pixg * 8 + 4]);
            float zv[8] = {z0.x, z0.y, z0.z, z0.w, z1.x, z1.y, z1.z, z1.w};
            float4 c0 = *reinterpret_cast<const float4*>(cbp + (size_t)d * 1024);
            float4 c1 = *reinterpret_cast<const float4*>(cbp + (size_t)d * 1024 + 4);
            float cv[8] = {c0.x, c0.y, c0.z, c0.w, c1.x, c1.y, c1.z, c1.w};
            #pragma unroll
            for (int p = 0; p < 8; ++p)
                #pragma unroll
                for (int c = 0; c < 8; ++c)
                    acc[p][c] = fmaf(zv[p], cv[c], acc[p][c]);
        }
        float4 e0 = *reinterpret_cast<const float4*>(ce2 + k0);
        float4 e1 = *reinterpret_cast<const float4*>(ce2 + k0 + 4);
        float ev[8] = {e0.x, e0.y, e0.z, e0.w, e1.x, e1.y, e1.z, e1.w};
        #pragma unroll
        for (int c = 0; c < 8; ++c) {
            #pragma unroll
            for (int p = 0; p < 8; ++p) {
                float dist = ev[c] - 2.f * acc[p][c];
                if (dist < best[p]) { best[p] = dist; bidx[p] = k0 + c; }
            }
        }
    }

    // cross-lane argmin per pixel (prefer smaller index on tie)
    #pragma unroll
    for (int j = 0; j < 8; ++j) {
        float bv = best[j]; int bi = bidx[j];
        #pragma unroll
        for (int off = 32; off > 0; off >>= 1) {
            float ov = __shfl_xor(bv, off);
            int   oi = __shfl_xor(bi, off);
            if (ov < bv || (ov == bv && oi < bi)) { bv = ov; bi = oi; }
        }
        if (codeg == 0) {
            sidx[pixg * 8 + j] = bi;
            atomicAdd(&counts[bi], 1u);
        }
    }
    __syncthreads();

    // gather + q write + loss partial. thread: pix = tid&63, dg = tid>>6 (16 d each)
    int pix = tid & 63, dg = tid >> 6;
    int kidx = sidx[pix];
    const float* crow = cb + (size_t)kidx * 128 + dg * 16;
    float sq = 0.f;
    size_t qbase = ((size_t)b * 128 + dg * 16) * 4096 + p0 + pix;
    #pragma unroll
    for (int ii = 0; ii < 4; ++ii) {
        float4 c4 = *reinterpret_cast<const float4*>(crow + 4 * ii);
        float vals[4] = {c4.x, c4.y, c4.z, c4.w};
        #pragma unroll
        for (int jj = 0; jj < 4; ++jj) {
            int d = dg * 16 + ii * 4 + jj;
            float qv = vals[jj];
            float zv = zl[d][pix];
            float df = qv - zv;
            sq = fmaf(df, df, sq);
            q[qbase + (size_t)(ii * 4 + jj) * 4096] = qv;
        }
    }
    #pragma unroll
    for (int off = 32; off > 0; off >>= 1) sq += __shfl_xor(sq, off);
    if ((tid & 63) == 0) red[tid >> 6] = sq;
    __syncthreads();
    if (tid == 0) {
        double s = 0.0;
        #pragma unroll
        for (int w = 0; w < 8; ++w) s += (double)red[w];
        partial[blockIdx.x] = s;
    }
}

// ---------------- finalize ----------------
__global__ __launch_bounds__(256) void finalize_kernel(
    const double* __restrict__ partial, const unsigned int* __restrict__ counts,
    float* __restrict__ dout)
{
    __shared__ double sd[256];
    __shared__ double lossSh;
    int tid = threadIdx.x;
    double s = 0.0;
    for (int i = tid; i < 512; i += 256) s += partial[i];
    sd[tid] = s; __syncthreads();
    for (int off = 128; off > 0; off >>= 1) {
        if (tid < off) sd[tid] += sd[tid + off];
        __syncthreads();
    }
    if (tid == 0) lossSh = CC_COST * sd[0] / 4194304.0;
    __syncthreads();

    double h = 0.0;
    for (int k = tid; k < 1024; k += 256) {
        double pp = (double)counts[k] / 32768.0;
        h += pp * log(pp + 1e-10);
    }
    sd[tid] = h; __syncthreads();
    for (int off = 128; off > 0; off >>= 1) {
        if (tid < off) sd[tid] += sd[tid + off];
        __syncthreads();
    }
    if (tid == 0) {
        dout[0]       = (float)lossSh;
        dout[1572865] = (float)exp(-sd[0]);
    }
}

// ===========================================================================
extern "C" void kernel_launch(void* const* d_in, const int* in_sizes, int n_in,
                              void* d_out, int out_size, void* d_ws, size_t ws_size,
                              hipStream_t stream)
{
    const float* x        = (const float*)d_in[0];
    const float* enc_c1   = (const float*)d_in[1];
    const float* enc_c2   = (const float*)d_in[2];
    const float* enc_c3   = (const float*)d_in[3];
    const float* enc_r1a  = (const float*)d_in[4];
    const float* enc_r1b  = (const float*)d_in[5];
    const float* enc_r2a  = (const float*)d_in[6];
    const float* enc_r2b  = (const float*)d_in[7];
    const float* pre_vq_w = (const float*)d_in[8];
    const float* codebook = (const float*)d_in[9];
    const float* dec_c1   = (const float*)d_in[10];
    const float* dec_r1a  = (const float*)d_in[11];
    const float* dec_r1b  = (const float*)d_in[12];
    const float* dec_r2a  = (const float*)d_in[13];
    const float* dec_r2b  = (const float*)d_in[14];
    const float* dec_dc   = (const float*)d_in[15];
    const float* dec_c3   = (const float*)d_in[16];
    float* dout = (float*)d_out;

    char* wsp = (char*)d_ws;
    auto alloc = [&](size_t bytes) {
        void* p = (void*)wsp;
        wsp += (bytes + 255) & ~(size_t)255;
        return p;
    };
    float* h1   = (float*)alloc(8ull*64*128*128*4);   // 32MB; also qb alias
    float* bufA = (float*)alloc(8ull*128*64*64*4);    // 16MB; also zb alias
    float* bufB = (float*)alloc(8ull*128*64*64*4);    // 16MB
    float* bufT = (float*)alloc(8ull*32*64*64*4);     // 4MB
    float* cbT  = (float*)alloc(128*1024*4);
    float* ce2  = (float*)alloc(1024*4);
    unsigned int* counts = (unsigned int*)alloc(1024*4);
    double* partial = (double*)alloc(512*8);
    float* wt_ec1  = (float*)alloc(3072*4);
    float* wt_ec2  = (float*)alloc(131072*4);
    float* wt_ec3  = (float*)alloc(147456*4);
    float* wt_er1a = (float*)alloc(36864*4);
    float* wt_er1b = (float*)alloc(4096*4);
    float* wt_er2a = (float*)alloc(36864*4);
    float* wt_er2b = (float*)alloc(4096*4);
    float* wt_pvq  = (float*)alloc(16384*4);
    float* wt_dc1  = (float*)alloc(147456*4);
    float* wt_dr1a = (float*)alloc(36864*4);
    float* wt_dr1b = (float*)alloc(4096*4);
    float* wt_dr2a = (float*)alloc(36864*4);
    float* wt_dr2b = (float*)alloc(4096*4);
    float* wt_ddc  = (float*)alloc(131072*4);
    float* wt_dc3  = (float*)alloc(1728*4);
    float* zb = bufA;   // alias: pre_vq out, dead before dec_c1 writes bufA
    float* qb = h1;     // alias: dead before deconv overwrites h1

    auto nb = [](int n) { return (n + 255) / 256; };

    // VQ prep
    zero_counts_kernel<<<4, 256, 0, stream>>>(counts);
    prep_codebook<<<4, 256, 0, stream>>>(codebook, cbT, ce2);

    // weight transforms
    wt_oihw_k<<<nb(3072),   256, 0, stream>>>(enc_c1,  wt_ec1,  64, 3, 16);
    wt_oihw_k<<<nb(131072), 256, 0, stream>>>(enc_c2,  wt_ec2, 128, 64, 16);
    wt_oihw_k<<<nb(147456), 256, 0, stream>>>(enc_c3,  wt_ec3, 128, 128, 9);
    wt_oihw_k<<<nb(36864),  256, 0, stream>>>(enc_r1a, wt_er1a, 32, 128, 9);
    wt_oihw_k<<<nb(4096),   256, 0, stream>>>(enc_r1b, wt_er1b, 128, 32, 1);
    wt_oihw_k<<<nb(36864),  256, 0, stream>>>(enc_r2a, wt_er2a, 32, 128, 9);
    wt_oihw_k<<<nb(4096),   256, 0, stream>>>(enc_r2b, wt_er2b, 128, 32, 1);
    wt_oihw_k<<<nb(16384),  256, 0, stream>>>(pre_vq_w, wt_pvq, 128, 128, 1);
    wt_oihw_k<<<nb(147456), 256, 0, stream>>>(dec_c1,  wt_dc1, 128, 128, 9);
    wt_oihw_k<<<nb(36864),  256, 0, stream>>>(dec_r1a, wt_dr1a, 32, 128, 9);
    wt_oihw_k<<<nb(4096),   256, 0, stream>>>(dec_r1b, wt_dr1b, 128, 32, 1);
    wt_oihw_k<<<nb(36864),  256, 0, stream>>>(dec_r2a, wt_dr2a, 32, 128, 9);
    wt_oihw_k<<<nb(4096),   256, 0, stream>>>(dec_r2b, wt_dr2b, 128, 32, 1);
    wt_deconv_k<<<nb(131072), 256, 0, stream>>>(dec_dc, wt_ddc);
    wt_c3_k<<<nb(1728), 256, 0, stream>>>(dec_c3, wt_dc3);

    // ---- encoder ----
    conv4x4s2_k<3, 64, 128, 3><<<1024, 256, 0, stream>>>(x, wt_ec1, h1);
    conv4x4s2_k<64, 128, 64, 2><<<512, 256, 0, stream>>>(h1, wt_ec2, bufA);
    conv3x3_k<128, 128, 4, 8, 4, false><<<512, 256, 0, stream>>>(bufA, wt_ec3, bufB);
    conv3x3_k<128, 32, 2, 4, 8, true><<<512, 256, 0, stream>>>(bufB, wt_er1a, bufT);
    conv1x1_k<32, 128, 32, true, true><<<512, 256, 0, stream>>>(bufT, wt_er1b, bufB, bufB);
    conv3x3_k<128, 32, 2, 4, 8, true><<<512, 256, 0, stream>>>(bufB, wt_er2a, bufT);
    conv1x1_k<32, 128, 32, true, true><<<512, 256, 0, stream>>>(bufT, wt_er2b, bufB, bufB);
    conv1x1_k<128, 128, 32, true, false><<<512, 256, 0, stream>>>(bufB, wt_pvq, bufB, zb);

    // ---- VQ (fused argmin + gather + loss) ----
    vq_fused<<<512, 512, 0, stream>>>(zb, codebook, cbT, ce2, counts, qb, partial);

    // ---- decoder ----
    conv3x3_k<128, 128, 4, 8, 4, false><<<512, 256, 0, stream>>>(qb, wt_dc1, bufA);
    conv3x3_k<128, 32, 2, 4, 8, true><<<512, 256, 0, stream>>>(bufA, wt_dr1a, bufT);
    conv1x1_k<32, 128, 32, true, true><<<512, 256, 0, stream>>>(bufT, wt_dr1b, bufA, bufA);
    conv3x3_k<128, 32, 2, 4, 8, true><<<512, 256, 0, stream>>>(bufA, wt_dr2a, bufT);
    conv1x1_k<32, 128, 32, true, true><<<512, 256, 0, stream>>>(bufT, wt_dr2b, bufA, bufA);
    deconv_k<4><<<1024, 256, 0, stream>>>(bufA, wt_ddc, h1);
    upconv_k<2><<<512, 256, 0, stream>>>(h1, wt_dc3, dout + 1);

    // ---- scalars ----
    finalize_kernel<<<1, 256, 0, stream>>>(partial, counts, dout);
}

// Round 5
// 1502.223 us; speedup vs baseline: 7.3025x; 1.1106x over previous
//
#include <hip/hip_runtime.h>
#include <hip/hip_bf16.h>
#include <math.h>

#define CC_COST 0.25

// ===========================================================================
// VQ-VAE forward, fp32, register-blocked tiled conv kernels + GEMM-style VQ.
// d_out[0]=loss, d_out[1..1572864]=recon NCHW, d_out[1572865]=perplexity
// ===========================================================================

// ---------------- batched weight transforms ----------------
// kind 0: OIHW [oc][c][kk] -> [c][kk][oc]
// kind 1: deconv [c=128][oc=64][16] -> [c][16][oc]
// kind 2: dec_c3 [3][64][9] -> [c][9][3]
struct WtJobs {
    const float* src[15];
    float* dst[15];
    int cout[15], cin[15], kk[15], kind[15];
    int blk0[16];
};

__global__ void wt_batch_k(WtJobs J)
{
    int blk = blockIdx.x;
    int j = 0;
    while (j < 14 && blk >= J.blk0[j + 1]) ++j;
    int i = (blk - J.blk0[j]) * 256 + threadIdx.x;
    int total = J.cout[j] * J.cin[j] * J.kk[j];
    if (i >= total) return;
    const float* src = J.src[j];
    float* dst = J.dst[j];
    int kind = J.kind[j];
    if (kind == 0) {
        int Cout = J.cout[j], Cin = J.cin[j], KK = J.kk[j];
        int oc = i % Cout; int t2 = i / Cout; int t = t2 % KK; int c = t2 / KK;
        dst[i] = src[(oc * Cin + c) * KK + t];
    } else if (kind == 1) {
        int oc = i & 63; int t = (i >> 6) & 15; int c = i >> 10;
        dst[i] = src[(c * 64 + oc) * 16 + t];
    } else {
        int o = i % 3; int t = (i / 3) % 9; int c = i / 27;
        dst[i] = src[(o * 64 + c) * 9 + t];
    }
}

// ---------------- conv 3x3 s1 p1 on 64x64, tiled, optional oc-slice --------
template<int CIN, int COUT, int OCB, int PXB, int CC, bool IN_RELU, int WOC, int NSLICE>
__global__ __launch_bounds__(256) void conv3x3_k(
    const float* __restrict__ in, const float* __restrict__ wT,
    float* __restrict__ out)
{
    constexpr int NPXG = 64 / PXB;
    constexpr int NOCG = COUT / OCB;
    static_assert(NPXG * NOCG == 256, "bad tile");
    constexpr int WTP = 68;
    __shared__ __align__(16) float ls_in[CC][3][WTP];
    __shared__ __align__(16) float ls_w[CC][9][COUT];

    int tid = threadIdx.x;
    int pxg = tid % NPXG, ocg = tid / NPXG;
    int x0 = pxg * PXB, oc0 = ocg * OCB;
    int blk = blockIdx.x;
    int y = blk & 63; int rest = blk >> 6;
    int slice = rest % NSLICE; int b = rest / NSLICE;
    int oc_base = slice * COUT;
    const float* inb = in + (size_t)b * CIN * 4096;

    float acc[OCB][PXB];
    #pragma unroll
    for (int o = 0; o < OCB; ++o)
        #pragma unroll
        for (int p = 0; p < PXB; ++p) acc[o][p] = 0.f;

    for (int c0 = 0; c0 < CIN; c0 += CC) {
        __syncthreads();
        for (int i = tid; i < CC * 3 * 66; i += 256) {
            int xx = i % 66; int t = i / 66; int r = t % 3; int cc = t / 3;
            int gy = y - 1 + r, gx = xx - 1;
            float v = 0.f;
            if ((unsigned)gy < 64u && (unsigned)gx < 64u) {
                v = inb[(c0 + cc) * 4096 + gy * 64 + gx];
                if (IN_RELU) v = fmaxf(v, 0.f);
            }
            ls_in[cc][r][xx] = v;
        }
        const float* wsrc = wT + (size_t)c0 * 9 * WOC + oc_base;
        for (int i = tid; i < CC * 9 * COUT; i += 256) {
            int o = i % COUT; int tt = (i / COUT) % 9; int cc = i / (9 * COUT);
            ls_w[cc][tt][o] = wsrc[(cc * 9 + tt) * WOC + o];
        }
        __syncthreads();

        for (int cc = 0; cc < CC; ++cc) {
            float rv[3][PXB + 2];
            #pragma unroll
            for (int r = 0; r < 3; ++r) {
                const float* base = &ls_in[cc][r][x0];
                #pragma unroll
                for (int q = 0; q < PXB / 4; ++q) {
                    float4 v = *reinterpret_cast<const float4*>(base + 4 * q);
                    rv[r][4*q+0] = v.x; rv[r][4*q+1] = v.y;
                    rv[r][4*q+2] = v.z; rv[r][4*q+3] = v.w;
                }
                rv[r][PXB]     = base[PXB];
                rv[r][PXB + 1] = base[PXB + 1];
            }
            const float* lw = &ls_w[cc][0][0];
            #pragma unroll
            for (int dy = 0; dy < 3; ++dy) {
                #pragma unroll
                for (int dx = 0; dx < 3; ++dx) {
                    const float* wp = lw + (dy * 3 + dx) * COUT + oc0;
                    float wv[OCB];
                    if constexpr (OCB == 4) {
                        float4 w4 = *reinterpret_cast<const float4*>(wp);
                        wv[0] = w4.x; wv[1] = w4.y; wv[2] = w4.z; wv[3] = w4.w;
                    } else {
                        float2 w2 = *reinterpret_cast<const float2*>(wp);
                        wv[0] = w2.x; wv[1] = w2.y;
                    }
                    #pragma unroll
                    for (int p = 0; p < PXB; ++p) {
                        float iv = rv[dy][p + dx];
                        #pragma unroll
                        for (int o = 0; o < OCB; ++o)
                            acc[o][p] = fmaf(iv, wv[o], acc[o][p]);
                    }
                }
            }
        }
    }
    #pragma unroll
    for (int o = 0; o < OCB; ++o) {
        float* op = out + (((size_t)b * (COUT * NSLICE) + oc_base + oc0 + o) * 64 + y) * 64 + x0;
        #pragma unroll
        for (int q = 0; q < PXB / 4; ++q) {
            float4 v = make_float4(acc[o][4*q], acc[o][4*q+1],
                                   acc[o][4*q+2], acc[o][4*q+3]);
            *reinterpret_cast<float4*>(op + 4 * q) = v;
        }
    }
}

// ---------------- split-K res conv3x3: 128->32, relu(in), raw out ----------
__global__ __launch_bounds__(512) void conv3x3_res_k(
    const float* __restrict__ in, const float* __restrict__ wT,  // [c][9][32]
    float* __restrict__ out)
{
    constexpr int CC = 8;
    __shared__ __align__(16) float ls_in[2][CC][3][68];
    __shared__ __align__(16) float ls_w[2][CC][9][32];
    __shared__ float ts[8][256];
    int tid = threadIdx.x;
    int g = tid >> 8, t = tid & 255;
    int pxg = t & 15, ocg = t >> 4;     // PXB=4, OCB=2
    int x0 = pxg * 4, oc0 = ocg * 2;
    int y = blockIdx.x & 63, b = blockIdx.x >> 6;
    const float* inb = in + ((size_t)b * 128 + g * 64) * 4096;

    float acc[2][4];
    #pragma unroll
    for (int o = 0; o < 2; ++o)
        #pragma unroll
        for (int p = 0; p < 4; ++p) acc[o][p] = 0.f;

    for (int c0 = 0; c0 < 64; c0 += CC) {
        __syncthreads();
        for (int i = t; i < CC * 3 * 66; i += 256) {
            int xx = i % 66; int tt = i / 66; int r = tt % 3; int cc = tt / 3;
            int gy = y - 1 + r, gx = xx - 1;
            float v = 0.f;
            if ((unsigned)gy < 64u && (unsigned)gx < 64u)
                v = fmaxf(inb[(c0 + cc) * 4096 + gy * 64 + gx], 0.f);
            ls_in[g][cc][r][xx] = v;
        }
        const float* wsrc = wT + (size_t)(g * 64 + c0) * 9 * 32;
        for (int i = t; i < CC * 9 * 32; i += 256)
            (&ls_w[g][0][0][0])[i] = wsrc[i];
        __syncthreads();

        for (int cc = 0; cc < CC; ++cc) {
            float rv[3][6];
            #pragma unroll
            for (int r = 0; r < 3; ++r) {
                const float* base = &ls_in[g][cc][r][x0];
                float4 v = *reinterpret_cast<const float4*>(base);
                rv[r][0]=v.x; rv[r][1]=v.y; rv[r][2]=v.z; rv[r][3]=v.w;
                rv[r][4]=base[4]; rv[r][5]=base[5];
            }
            const float* lw = &ls_w[g][cc][0][0];
            #pragma unroll
            for (int dy = 0; dy < 3; ++dy) {
                #pragma unroll
                for (int dx = 0; dx < 3; ++dx) {
                    float2 w2 = *reinterpret_cast<const float2*>(lw + (dy * 3 + dx) * 32 + oc0);
                    float wv[2] = {w2.x, w2.y};
                    #pragma unroll
                    for (int p = 0; p < 4; ++p) {
                        float iv = rv[dy][p + dx];
                        acc[0][p] = fmaf(iv, wv[0], acc[0][p]);
                        acc[1][p] = fmaf(iv, wv[1], acc[1][p]);
                    }
                }
            }
        }
    }
    if (g == 0) {
        #pragma unroll
        for (int o = 0; o < 2; ++o)
            #pragma unroll
            for (int p = 0; p < 4; ++p) ts[o * 4 + p][t] = acc[o][p];
    }
    __syncthreads();
    if (g == 1) {
        #pragma unroll
        for (int o = 0; o < 2; ++o) {
            float4 v = make_float4(ts[o*4+0][t] + acc[o][0], ts[o*4+1][t] + acc[o][1],
                                   ts[o*4+2][t] + acc[o][2], ts[o*4+3][t] + acc[o][3]);
            float* op = out + (((size_t)b * 32 + oc0 + o) * 64 + y) * 64 + x0;
            *reinterpret_cast<float4*>(op) = v;
        }
    }
}

// ---------------- conv 1x1 on 64x64 (COUT must be 128) ----------------
template<int CIN, int COUT, int CC, bool IN_RELU, bool ADD_RES>
__global__ __launch_bounds__(256) void conv1x1_k(
    const float* __restrict__ in, const float* __restrict__ wT,
    const float* __restrict__ res, float* __restrict__ out)
{
    static_assert(COUT == 128, "tile assumes 128");
    __shared__ __align__(16) float ls_in[CC][64];
    __shared__ __align__(16) float ls_w[CC][COUT];
    int tid = threadIdx.x;
    int pxg = tid & 7, ocg = tid >> 3;
    int x0 = pxg * 8, oc0 = ocg * 4;
    int y = blockIdx.x & 63, b = blockIdx.x >> 6;

    float acc[4][8];
    #pragma unroll
    for (int o = 0; o < 4; ++o)
        #pragma unroll
        for (int p = 0; p < 8; ++p) acc[o][p] = 0.f;

    for (int c0 = 0; c0 < CIN; c0 += CC) {
        __syncthreads();
        for (int i = tid; i < CC * 64; i += 256) {
            int xx = i & 63, cc = i >> 6;
            float v = in[(((size_t)b * CIN + c0 + cc) * 64 + y) * 64 + xx];
            if (IN_RELU) v = fmaxf(v, 0.f);
            ls_in[cc][xx] = v;
        }
        const float* wsrc = wT + (size_t)c0 * COUT;
        for (int i = tid; i < CC * COUT; i += 256)
            (&ls_w[0][0])[i] = wsrc[i];
        __syncthreads();

        for (int cc = 0; cc < CC; ++cc) {
            float rv[8];
            const float* base = &ls_in[cc][x0];
            float4 v0 = *reinterpret_cast<const float4*>(base);
            float4 v1 = *reinterpret_cast<const float4*>(base + 4);
            rv[0]=v0.x; rv[1]=v0.y; rv[2]=v0.z; rv[3]=v0.w;
            rv[4]=v1.x; rv[5]=v1.y; rv[6]=v1.z; rv[7]=v1.w;
            float4 w4 = *reinterpret_cast<const float4*>(&ls_w[cc][oc0]);
            float wv[4] = {w4.x, w4.y, w4.z, w4.w};
            #pragma unroll
            for (int p = 0; p < 8; ++p)
                #pragma unroll
                for (int o = 0; o < 4; ++o)
                    acc[o][p] = fmaf(rv[p], wv[o], acc[o][p]);
        }
    }
    #pragma unroll
    for (int o = 0; o < 4; ++o) {
        float* op = out + (((size_t)b * COUT + oc0 + o) * 64 + y) * 64 + x0;
        const float* rp = res + (((size_t)b * COUT + oc0 + o) * 64 + y) * 64 + x0;
        #pragma unroll
        for (int q = 0; q < 2; ++q) {
            float4 v = make_float4(acc[o][4*q], acc[o][4*q+1],
                                   acc[o][4*q+2], acc[o][4*q+3]);
            if (ADD_RES) {
                float4 r4 = *reinterpret_cast<const float4*>(rp + 4 * q);
                v.x += r4.x; v.y += r4.y; v.z += r4.z; v.w += r4.w;
            }
            *reinterpret_cast<float4*>(op + 4 * q) = v;
        }
    }
}

// ---------------- conv 4x4 s2 p1, relu out, optional oc-slice ----------------
template<int CIN, int COUT, int WOUT, int CC, int OCB, int WOC, int NSLICE>
__global__ __launch_bounds__(256) void conv4x4s2_k(
    const float* __restrict__ in, const float* __restrict__ wT,
    float* __restrict__ out)
{
    constexpr int WIN = WOUT * 2;
    constexpr int NPXG = WOUT / 8, NOCG = COUT / OCB;
    static_assert(NPXG * NOCG == 256, "bad tile");
    constexpr int WUSE = 2 * WOUT + 2;
    constexpr int WTP = (WUSE + 3) & ~3;
    __shared__ __align__(16) float ls_in[CC][4][WTP];
    __shared__ __align__(16) float ls_w[CC][16][COUT];

    int tid = threadIdx.x;
    int pxg = tid % NPXG, ocg = tid / NPXG;
    int x0 = pxg * 8, oc0 = ocg * OCB;
    int blk = blockIdx.x;
    int y = blk % WOUT; int rest = blk / WOUT;
    int slice = rest % NSLICE; int b = rest / NSLICE;
    int oc_base = slice * COUT;
    const float* inb = in + (size_t)b * CIN * WIN * WIN;

    float acc[OCB][8];
    #pragma unroll
    for (int o = 0; o < OCB; ++o)
        #pragma unroll
        for (int p = 0; p < 8; ++p) acc[o][p] = 0.f;

    for (int c0 = 0; c0 < CIN; c0 += CC) {
        __syncthreads();
        for (int i = tid; i < CC * 4 * WUSE; i += 256) {
            int xx = i % WUSE; int t = i / WUSE; int r = t & 3; int cc = t >> 2;
            int gy = 2 * y - 1 + r, gx = xx - 1;
            float v = 0.f;
            if ((unsigned)gy < (unsigned)WIN && (unsigned)gx < (unsigned)WIN)
                v = inb[(c0 + cc) * WIN * WIN + gy * WIN + gx];
            ls_in[cc][r][xx] = v;
        }
        const float* wsrc = wT + (size_t)c0 * 16 * WOC + oc_base;
        for (int i = tid; i < CC * 16 * COUT; i += 256) {
            int o = i % COUT; int tt = (i / COUT) % 16; int cc = i / (16 * COUT);
            ls_w[cc][tt][o] = wsrc[(cc * 16 + tt) * WOC + o];
        }
        __syncthreads();

        for (int cc = 0; cc < CC; ++cc) {
            const float* lw = &ls_w[cc][0][0];
            #pragma unroll
            for (int ky = 0; ky < 4; ++ky) {
                float rv[18];
                const float* base = &ls_in[cc][ky][2 * x0];
                #pragma unroll
                for (int q = 0; q < 4; ++q) {
                    float4 v = *reinterpret_cast<const float4*>(base + 4 * q);
                    rv[4*q]=v.x; rv[4*q+1]=v.y; rv[4*q+2]=v.z; rv[4*q+3]=v.w;
                }
                rv[16] = base[16]; rv[17] = base[17];
                #pragma unroll
                for (int kx = 0; kx < 4; ++kx) {
                    const float* wp = lw + (ky * 4 + kx) * COUT + oc0;
                    float wv[OCB];
                    if constexpr (OCB == 4) {
                        float4 w4 = *reinterpret_cast<const float4*>(wp);
                        wv[0]=w4.x; wv[1]=w4.y; wv[2]=w4.z; wv[3]=w4.w;
                    } else {
                        float2 w2 = *reinterpret_cast<const float2*>(wp);
                        wv[0]=w2.x; wv[1]=w2.y;
                    }
                    #pragma unroll
                    for (int p = 0; p < 8; ++p) {
                        float iv = rv[2 * p + kx];
                        #pragma unroll
                        for (int o = 0; o < OCB; ++o)
                            acc[o][p] = fmaf(iv, wv[o], acc[o][p]);
                    }
                }
            }
        }
    }
    #pragma unroll
    for (int o = 0; o < OCB; ++o) {
        float* op = out + (((size_t)b * (COUT * NSLICE) + oc_base + oc0 + o) * WOUT + y) * WOUT + x0;
        #pragma unroll
        for (int q = 0; q < 2; ++q) {
            float4 v = make_float4(fmaxf(acc[o][4*q],0.f), fmaxf(acc[o][4*q+1],0.f),
                                   fmaxf(acc[o][4*q+2],0.f), fmaxf(acc[o][4*q+3],0.f));
            *reinterpret_cast<float4*>(op + 4 * q) = v;
        }
    }
}

// ---------------- deconv 4x4 s2 p1, 128->64, relu(in) folded, relu out ------
#define DECONV_TAPS(RV, KY)                                                   \
    {                                                                         \
        int ky_ = (KY);                                                       \
        _Pragma("unroll")                                                     \
        for (int kx = 0; kx < 4; ++kx) {                                      \
            float4 w4 = *reinterpret_cast<const float4*>(                     \
                lw + (ky_ * 4 + kx) * 64 + oc0);                              \
            float wv[4] = {w4.x, w4.y, w4.z, w4.w};                           \
            if (kx & 1) {                                                     \
                _Pragma("unroll")                                             \
                for (int ph = 0; ph < 4; ++ph) {                              \
                    float iv = RV[(kx == 1) ? (ph + 1) : ph];                 \
                    _Pragma("unroll")                                         \
                    for (int o = 0; o < 4; ++o)                               \
                        acc[o][2*ph] = fmaf(iv, wv[o], acc[o][2*ph]);         \
                }                                                             \
            } else {                                                          \
                _Pragma("unroll")                                             \
                for (int ph = 0; ph < 4; ++ph) {                              \
                    float iv = RV[(kx == 0) ? (ph + 2) : (ph + 1)];           \
                    _Pragma("unroll")                                         \
                    for (int o = 0; o < 4; ++o)                               \
                        acc[o][2*ph+1] = fmaf(iv, wv[o], acc[o][2*ph+1]);     \
                }                                                             \
            }                                                                 \
        }                                                                     \
    }

template<int CC>
__global__ __launch_bounds__(256) void deconv_k(
    const float* __restrict__ in, const float* __restrict__ wT,
    float* __restrict__ out)
{
    __shared__ __align__(16) float ls_in[CC][2][68];
    __shared__ __align__(16) float ls_w[CC][16][64];
    int tid = threadIdx.x;
    int pxg = tid & 15, ocg = tid >> 4;
    int x0 = pxg * 8, oc0 = ocg * 4, xh = pxg * 4;
    int oy = blockIdx.x & 127, b = blockIdx.x >> 7;
    int r1 = (oy + 1) >> 1;
    int ky0 = (oy + 1) & 1;
    const float* inb = in + (size_t)b * 128 * 4096;

    float acc[4][8];
    #pragma unroll
    for (int o = 0; o < 4; ++o)
        #pragma unroll
        for (int p = 0; p < 8; ++p) acc[o][p] = 0.f;

    for (int c0 = 0; c0 < 128; c0 += CC) {
        __syncthreads();
        for (int i = tid; i < CC * 2 * 66; i += 256) {
            int xx = i % 66; int t = i / 66; int rr = t & 1; int cc = t >> 1;
            int iy = r1 - 1 + rr, gx = xx - 1;
            float v = 0.f;
            if ((unsigned)iy < 64u && (unsigned)gx < 64u)
                v = fmaxf(inb[(c0 + cc) * 4096 + iy * 64 + gx], 0.f);
            ls_in[cc][rr][xx] = v;
        }
        const float* wsrc = wT + (size_t)c0 * 16 * 64;
        for (int i = tid; i < CC * 16 * 64; i += 256)
            (&ls_w[0][0][0])[i] = wsrc[i];
        __syncthreads();

        for (int cc = 0; cc < CC; ++cc) {
            float rvA[6], rvB[6];
            {
                const float* bA = &ls_in[cc][1][xh];
                float4 v = *reinterpret_cast<const float4*>(bA);
                rvA[0]=v.x; rvA[1]=v.y; rvA[2]=v.z; rvA[3]=v.w;
                rvA[4]=bA[4]; rvA[5]=bA[5];
                const float* bB = &ls_in[cc][0][xh];
                float4 u = *reinterpret_cast<const float4*>(bB);
                rvB[0]=u.x; rvB[1]=u.y; rvB[2]=u.z; rvB[3]=u.w;
                rvB[4]=bB[4]; rvB[5]=bB[5];
            }
            const float* lw = &ls_w[cc][0][0];
            DECONV_TAPS(rvA, ky0);
            DECONV_TAPS(rvB, ky0 + 2);
        }
    }
    #pragma unroll
    for (int o = 0; o < 4; ++o) {
        float* op = out + (((size_t)b * 64 + oc0 + o) * 128 + oy) * 128 + x0;
        #pragma unroll
        for (int q = 0; q < 2; ++q) {
            float4 v = make_float4(fmaxf(acc[o][4*q],0.f), fmaxf(acc[o][4*q+1],0.f),
                                   fmaxf(acc[o][4*q+2],0.f), fmaxf(acc[o][4*q+3],0.f));
            *reinterpret_cast<float4*>(op + 4 * q) = v;
        }
    }
}

// ---------------- fused bilinear-2x(align) + conv3x3 64->3 + 2*sigmoid-1 ----
template<int CC>
__global__ __launch_bounds__(256) void upconv_k(
    const float* __restrict__ in, const float* __restrict__ wT3,
    float* __restrict__ out)
{
    __shared__ __align__(16) float ls_u[CC][6][260];
    __shared__ float ls_w[64 * 27];
    int tid = threadIdx.x;
    int pxg = tid & 63, row = tid >> 6;
    int x0 = pxg * 4;
    int yblk = blockIdx.x & 63, b = blockIdx.x >> 6;
    int y0 = yblk * 4, y = y0 + row;
    const float SCL = 127.0f / 255.0f;
    const float* hb = in + (size_t)b * 64 * 16384;

    for (int i = tid; i < 1728; i += 256) ls_w[i] = wT3[i];

    float acc[3][4];
    #pragma unroll
    for (int o = 0; o < 3; ++o)
        #pragma unroll
        for (int p = 0; p < 4; ++p) acc[o][p] = 0.f;

    for (int c0 = 0; c0 < 64; c0 += CC) {
        __syncthreads();
        for (int i = tid; i < CC * 6 * 258; i += 256) {
            int xx = i % 258; int t = i / 258; int r = t % 6; int cc = t / 6;
            int uy = y0 - 1 + r, gx = xx - 1;
            float v = 0.f;
            if ((unsigned)uy < 256u && (unsigned)gx < 256u) {
                float py = uy * SCL;
                int ylo = (int)py; int yhi = min(ylo + 1, 127); float fy = py - ylo;
                float px = gx * SCL;
                int xlo = (int)px; int xhi = min(xlo + 1, 127); float fx = px - xlo;
                const float* hp = hb + (c0 + cc) * 16384 + ylo * 128;
                const float* hq = hb + (c0 + cc) * 16384 + yhi * 128;
                float a = hp[xlo], b2 = hp[xhi], c2 = hq[xlo], d2 = hq[xhi];
                float top = a + (b2 - a) * fx;
                float bot = c2 + (d2 - c2) * fx;
                v = top + (bot - top) * fy;
            }
            ls_u[cc][r][xx] = v;
        }
        __syncthreads();

        for (int cc = 0; cc < CC; ++cc) {
            #pragma unroll
            for (int j = 0; j < 3; ++j) {
                float rv[6];
                const float* base = &ls_u[cc][row + j][x0];
                float4 v = *reinterpret_cast<const float4*>(base);
                rv[0]=v.x; rv[1]=v.y; rv[2]=v.z; rv[3]=v.w;
                rv[4]=base[4]; rv[5]=base[5];
                #pragma unroll
                for (int i2 = 0; i2 < 3; ++i2) {
                    const float* wp = &ls_w[((c0 + cc) * 9 + (j * 3 + i2)) * 3];
                    float w0 = wp[0], w1 = wp[1], w2 = wp[2];
                    #pragma unroll
                    for (int p = 0; p < 4; ++p) {
                        float iv = rv[p + i2];
                        acc[0][p] = fmaf(iv, w0, acc[0][p]);
                        acc[1][p] = fmaf(iv, w1, acc[1][p]);
                        acc[2][p] = fmaf(iv, w2, acc[2][p]);
                    }
                }
            }
        }
    }
    #pragma unroll
    for (int o = 0; o < 3; ++o) {
        float4 v;
        v.x = 2.f / (1.f + expf(-acc[o][0])) - 1.f;
        v.y = 2.f / (1.f + expf(-acc[o][1])) - 1.f;
        v.z = 2.f / (1.f + expf(-acc[o][2])) - 1.f;
        v.w = 2.f / (1.f + expf(-acc[o][3])) - 1.f;
        float* op = out + (((size_t)b * 3 + o) * 256 + y) * 256 + x0;
        *reinterpret_cast<float4*>(op) = v;
    }
}

// ---------------- codebook prep (also zeroes counts) ----------------
__global__ void prep_codebook(const float* __restrict__ cb,
                              float* __restrict__ cbT, float* __restrict__ ce2,
                              unsigned int* __restrict__ counts)
{
    int k = blockIdx.x * 256 + threadIdx.x;
    if (k >= 1024) return;
    float s = 0.f;
    for (int d = 0; d < 128; ++d) {
        float v = cb[k * 128 + d];
        cbT[d * 1024 + k] = v;
        s = fmaf(v, v, s);
    }
    ce2[k] = s;
    counts[k] = 0u;
}

// ---------------- fused VQ v2: 32 px/block, 1024 blocks ----------------
__global__ __launch_bounds__(512) void vq_fused(
    const float* __restrict__ z,     // NCHW [8,128,64,64]
    const float* __restrict__ cb,    // original [1024][128]
    const float* __restrict__ cbT,   // [128][1024]
    const float* __restrict__ ce2,   // [1024]
    unsigned int* __restrict__ counts,
    float* __restrict__ q,           // NCHW
    double* __restrict__ partial)    // [1024]
{
    __shared__ float zl[128][32];    // 16 KB
    __shared__ int sidx[32];
    __shared__ float red[8];

    int tid = threadIdx.x;
    int lane = tid & 63;
    int w = tid >> 6;                // 8 waves, 4 pixels each
    int b = blockIdx.x >> 7;
    int p0 = (blockIdx.x & 127) * 32;

    for (int i = tid; i < 4096; i += 512) {
        int d = i >> 5, pix = i & 31;
        zl[d][pix] = z[((size_t)b * 128 + d) * 4096 + p0 + pix];
    }
    __syncthreads();

    float best[4]; int bidx[4];
    #pragma unroll
    for (int j = 0; j < 4; ++j) { best[j] = 3.4e38f; bidx[j] = 0; }

    for (int kt = 0; kt < 2; ++kt) {
        int k0 = kt * 512 + lane * 8;
        float acc[4][8];
        #pragma unroll
        for (int p = 0; p < 4; ++p)
            #pragma unroll
            for (int c = 0; c < 8; ++c) acc[p][c] = 0.f;

        const float* cbp = cbT + k0;
        for (int d = 0; d < 128; ++d) {
            float4 zq = *reinterpret_cast<const float4*>(&zl[d][w * 4]);
            float zv[4] = {zq.x, zq.y, zq.z, zq.w};
            float4 c0 = *reinterpret_cast<const float4*>(cbp + (size_t)d * 1024);
            float4 c1 = *reinterpret_cast<const float4*>(cbp + (size_t)d * 1024 + 4);
            float cv[8] = {c0.x, c0.y, c0.z, c0.w, c1.x, c1.y, c1.z, c1.w};
            #pragma unroll
            for (int p = 0; p < 4; ++p)
                #pragma unroll
                for (int c = 0; c < 8; ++c)
                    acc[p][c] = fmaf(zv[p], cv[c], acc[p][c]);
        }
        float4 e0 = *reinterpret_cast<const float4*>(ce2 + k0);
        float4 e1 = *reinterpret_cast<const float4*>(ce2 + k0 + 4);
        float ev[8] = {e0.x, e0.y, e0.z, e0.w, e1.x, e1.y, e1.z, e1.w};
        #pragma unroll
        for (int c = 0; c < 8; ++c) {
            #pragma unroll
            for (int p = 0; p < 4; ++p) {
                float dist = ev[c] - 2.f * acc[p][c];
                if (dist < best[p]) { best[p] = dist; bidx[p] = k0 + c; }
            }
        }
    }

    #pragma unroll
    for (int j = 0; j < 4; ++j) {
        float bv = best[j]; int bi = bidx[j];
        #pragma unroll
        for (int off = 32; off > 0; off >>= 1) {
            float ov = __shfl_xor(bv, off);
            int   oi = __shfl_xor(bi, off);
            if (ov < bv || (ov == bv && oi < bi)) { bv = ov; bi = oi; }
        }
        if (lane == 0) {
            sidx[w * 4 + j] = bi;
            atomicAdd(&counts[bi], 1u);
        }
    }
    __syncthreads();

    // gather + q write + loss: pix = tid&31, dg = tid>>5 (16 groups x 8 d)
    int pix = tid & 31, dg = tid >> 5;
    int kidx = sidx[pix];
    const float* crow = cb + (size_t)kidx * 128 + dg * 8;
    float sq = 0.f;
    size_t qbase = ((size_t)b * 128 + dg * 8) * 4096 + p0 + pix;
    float4 c4a = *reinterpret_cast<const float4*>(crow);
    float4 c4b = *reinterpret_cast<const float4*>(crow + 4);
    float vals[8] = {c4a.x, c4a.y, c4a.z, c4a.w, c4b.x, c4b.y, c4b.z, c4b.w};
    #pragma unroll
    for (int jj = 0; jj < 8; ++jj) {
        float qv = vals[jj];
        float zv = zl[dg * 8 + jj][pix];
        float df = qv - zv;
        sq = fmaf(df, df, sq);
        q[qbase + (size_t)jj * 4096] = qv;
    }
    #pragma unroll
    for (int off = 32; off > 0; off >>= 1) sq += __shfl_xor(sq, off);
    if (lane == 0) red[w] = sq;
    __syncthreads();
    if (tid == 0) {
        double s = 0.0;
        #pragma unroll
        for (int ww = 0; ww < 8; ++ww) s += (double)red[ww];
        partial[blockIdx.x] = s;
    }
}

// ---------------- finalize ----------------
__global__ __launch_bounds__(256) void finalize_kernel(
    const double* __restrict__ partial, const unsigned int* __restrict__ counts,
    float* __restrict__ dout)
{
    __shared__ double sd[256];
    __shared__ double lossSh;
    int tid = threadIdx.x;
    double s = 0.0;
    for (int i = tid; i < 1024; i += 256) s += partial[i];
    sd[tid] = s; __syncthreads();
    for (int off = 128; off > 0; off >>= 1) {
        if (tid < off) sd[tid] += sd[tid + off];
        __syncthreads();
    }
    if (tid == 0) lossSh = CC_COST * sd[0] / 4194304.0;
    __syncthreads();

    double h = 0.0;
    for (int k = tid; k < 1024; k += 256) {
        double pp = (double)counts[k] / 32768.0;
        h += pp * log(pp + 1e-10);
    }
    sd[tid] = h; __syncthreads();
    for (int off = 128; off > 0; off >>= 1) {
        if (tid < off) sd[tid] += sd[tid + off];
        __syncthreads();
    }
    if (tid == 0) {
        dout[0]       = (float)lossSh;
        dout[1572865] = (float)exp(-sd[0]);
    }
}

// ===========================================================================
extern "C" void kernel_launch(void* const* d_in, const int* in_sizes, int n_in,
                              void* d_out, int out_size, void* d_ws, size_t ws_size,
                              hipStream_t stream)
{
    const float* x        = (const float*)d_in[0];
    const float* enc_c1   = (const float*)d_in[1];
    const float* enc_c2   = (const float*)d_in[2];
    const float* enc_c3   = (const float*)d_in[3];
    const float* enc_r1a  = (const float*)d_in[4];
    const float* enc_r1b  = (const float*)d_in[5];
    const float* enc_r2a  = (const float*)d_in[6];
    const float* enc_r2b  = (const float*)d_in[7];
    const float* pre_vq_w = (const float*)d_in[8];
    const float* codebook = (const float*)d_in[9];
    const float* dec_c1   = (const float*)d_in[10];
    const float* dec_r1a  = (const float*)d_in[11];
    const float* dec_r1b  = (const float*)d_in[12];
    const float* dec_r2a  = (const float*)d_in[13];
    const float* dec_r2b  = (const float*)d_in[14];
    const float* dec_dc   = (const float*)d_in[15];
    const float* dec_c3   = (const float*)d_in[16];
    float* dout = (float*)d_out;

    char* wsp = (char*)d_ws;
    auto alloc = [&](size_t bytes) {
        void* p = (void*)wsp;
        wsp += (bytes + 255) & ~(size_t)255;
        return p;
    };
    float* h1   = (float*)alloc(8ull*64*128*128*4);   // 32MB; also qb alias
    float* bufA = (float*)alloc(8ull*128*64*64*4);    // 16MB; also zb alias
    float* bufB = (float*)alloc(8ull*128*64*64*4);    // 16MB
    float* bufT = (float*)alloc(8ull*32*64*64*4);     // 4MB
    float* cbT  = (float*)alloc(128*1024*4);
    float* ce2  = (float*)alloc(1024*4);
    unsigned int* counts = (unsigned int*)alloc(1024*4);
    double* partial = (double*)alloc(1024*8);
    float* wt_ec1  = (float*)alloc(3072*4);
    float* wt_ec2  = (float*)alloc(131072*4);
    float* wt_ec3  = (float*)alloc(147456*4);
    float* wt_er1a = (float*)alloc(36864*4);
    float* wt_er1b = (float*)alloc(4096*4);
    float* wt_er2a = (float*)alloc(36864*4);
    float* wt_er2b = (float*)alloc(4096*4);
    float* wt_pvq  = (float*)alloc(16384*4);
    float* wt_dc1  = (float*)alloc(147456*4);
    float* wt_dr1a = (float*)alloc(36864*4);
    float* wt_dr1b = (float*)alloc(4096*4);
    float* wt_dr2a = (float*)alloc(36864*4);
    float* wt_dr2b = (float*)alloc(4096*4);
    float* wt_ddc  = (float*)alloc(131072*4);
    float* wt_dc3  = (float*)alloc(1728*4);
    float* zb = bufA;   // alias: pre_vq out, dead before dec_c1 writes bufA
    float* qb = h1;     // alias: dead before deconv overwrites h1

    // VQ prep (+counts zero)
    prep_codebook<<<4, 256, 0, stream>>>(codebook, cbT, ce2, counts);

    // batched weight transforms
    WtJobs J;
    const float* srcs[15] = {enc_c1, enc_c2, enc_c3, enc_r1a, enc_r1b, enc_r2a,
                             enc_r2b, pre_vq_w, dec_c1, dec_r1a, dec_r1b,
                             dec_r2a, dec_r2b, dec_dc, dec_c3};
    float* dsts[15] = {wt_ec1, wt_ec2, wt_ec3, wt_er1a, wt_er1b, wt_er2a,
                       wt_er2b, wt_pvq, wt_dc1, wt_dr1a, wt_dr1b,
                       wt_dr2a, wt_dr2b, wt_ddc, wt_dc3};
    int couts[15] = {64, 128, 128, 32, 128, 32, 128, 128, 128, 32, 128, 32, 128, 64, 3};
    int cins[15]  = {3, 64, 128, 128, 32, 128, 32, 128, 128, 128, 32, 128, 32, 128, 64};
    int kks[15]   = {16, 16, 9, 9, 1, 9, 1, 1, 9, 9, 1, 9, 1, 16, 9};
    int kinds[15] = {0, 0, 0, 0, 0, 0, 0, 0, 0, 0, 0, 0, 0, 1, 2};
    int off = 0;
    for (int j = 0; j < 15; ++j) {
        J.src[j] = srcs[j]; J.dst[j] = dsts[j];
        J.cout[j] = couts[j]; J.cin[j] = cins[j]; J.kk[j] = kks[j];
        J.kind[j] = kinds[j];
        J.blk0[j] = off;
        off += (couts[j] * cins[j] * kks[j] + 255) / 256;
    }
    J.blk0[15] = off;
    wt_batch_k<<<off, 256, 0, stream>>>(J);

    // ---- encoder ----
    conv4x4s2_k<3, 64, 128, 3, 4, 64, 1><<<1024, 256, 0, stream>>>(x, wt_ec1, h1);
    conv4x4s2_k<64, 64, 64, 4, 2, 128, 2><<<1024, 256, 0, stream>>>(h1, wt_ec2, bufA);
    conv3x3_k<128, 64, 4, 4, 8, false, 128, 2><<<1024, 256, 0, stream>>>(bufA, wt_ec3, bufB);
    conv3x3_res_k<<<512, 512, 0, stream>>>(bufB, wt_er1a, bufT);
    conv1x1_k<32, 128, 32, true, true><<<512, 256, 0, stream>>>(bufT, wt_er1b, bufB, bufB);
    conv3x3_res_k<<<512, 512, 0, stream>>>(bufB, wt_er2a, bufT);
    conv1x1_k<32, 128, 32, true, true><<<512, 256, 0, stream>>>(bufT, wt_er2b, bufB, bufB);
    conv1x1_k<128, 128, 32, true, false><<<512, 256, 0, stream>>>(bufB, wt_pvq, bufB, zb);

    // ---- VQ (fused argmin + gather + loss) ----
    vq_fused<<<1024, 512, 0, stream>>>(zb, codebook, cbT, ce2, counts, qb, partial);

    // ---- decoder ----
    conv3x3_k<128, 64, 4, 4, 8, false, 128, 2><<<1024, 256, 0, stream>>>(qb, wt_dc1, bufA);
    conv3x3_res_k<<<512, 512, 0, stream>>>(bufA, wt_dr1a, bufT);
    conv1x1_k<32, 128, 32, true, true><<<512, 256, 0, stream>>>(bufT, wt_dr1b, bufA, bufA);
    conv3x3_res_k<<<512, 512, 0, stream>>>(bufA, wt_dr2a, bufT);
    conv1x1_k<32, 128, 32, true, true><<<512, 256, 0, stream>>>(bufT, wt_dr2b, bufA, bufA);
    deconv_k<4><<<1024, 256, 0, stream>>>(bufA, wt_ddc, h1);
    upconv_k<2><<<512, 256, 0, stream>>>(h1, wt_dc3, dout + 1);

    // ---- scalars ----
    finalize_kernel<<<1, 256, 0, stream>>>(partial, counts, dout);
}

// Round 6
// 1471.015 us; speedup vs baseline: 7.4574x; 1.0212x over previous
//
#include <hip/hip_runtime.h>
#include <hip/hip_bf16.h>
#include <math.h>

#define CC_COST 0.25

// ===========================================================================
// VQ-VAE forward, fp32, register-blocked tiled conv kernels + GEMM-style VQ.
// d_out[0]=loss, d_out[1..1572864]=recon NCHW, d_out[1572865]=perplexity
// ===========================================================================

// ---------------- batched weight transforms ----------------
// kind 0: OIHW [oc][c][kk] -> [c][kk][oc]
// kind 1: deconv [c=128][oc=64][16] -> [c][16][oc]
// kind 2: dec_c3 [3][64][9] -> [c][9][3]
struct WtJobs {
    const float* src[15];
    float* dst[15];
    int cout[15], cin[15], kk[15], kind[15];
    int blk0[16];
};

__global__ void wt_batch_k(WtJobs J)
{
    int blk = blockIdx.x;
    int j = 0;
    while (j < 14 && blk >= J.blk0[j + 1]) ++j;
    int i = (blk - J.blk0[j]) * 256 + threadIdx.x;
    int total = J.cout[j] * J.cin[j] * J.kk[j];
    if (i >= total) return;
    const float* src = J.src[j];
    float* dst = J.dst[j];
    int kind = J.kind[j];
    if (kind == 0) {
        int Cout = J.cout[j], Cin = J.cin[j], KK = J.kk[j];
        int oc = i % Cout; int t2 = i / Cout; int t = t2 % KK; int c = t2 / KK;
        dst[i] = src[(oc * Cin + c) * KK + t];
    } else if (kind == 1) {
        int oc = i & 63; int t = (i >> 6) & 15; int c = i >> 10;
        dst[i] = src[(c * 64 + oc) * 16 + t];
    } else {
        int o = i % 3; int t = (i / 3) % 9; int c = i / 27;
        dst[i] = src[(o * 64 + c) * 9 + t];
    }
}

// ---------------- conv 3x3 s1 p1 on 64x64, tiled, optional oc-slice --------
template<int CIN, int COUT, int OCB, int PXB, int CC, bool IN_RELU, int WOC, int NSLICE>
__global__ __launch_bounds__(256) void conv3x3_k(
    const float* __restrict__ in, const float* __restrict__ wT,
    float* __restrict__ out)
{
    constexpr int NPXG = 64 / PXB;
    constexpr int NOCG = COUT / OCB;
    static_assert(NPXG * NOCG == 256, "bad tile");
    constexpr int WTP = 68;
    __shared__ __align__(16) float ls_in[CC][3][WTP];
    __shared__ __align__(16) float ls_w[CC][9][COUT];

    int tid = threadIdx.x;
    int pxg = tid % NPXG, ocg = tid / NPXG;
    int x0 = pxg * PXB, oc0 = ocg * OCB;
    int blk = blockIdx.x;
    int y = blk & 63; int rest = blk >> 6;
    int slice = rest % NSLICE; int b = rest / NSLICE;
    int oc_base = slice * COUT;
    const float* inb = in + (size_t)b * CIN * 4096;

    float acc[OCB][PXB];
    #pragma unroll
    for (int o = 0; o < OCB; ++o)
        #pragma unroll
        for (int p = 0; p < PXB; ++p) acc[o][p] = 0.f;

    for (int c0 = 0; c0 < CIN; c0 += CC) {
        __syncthreads();
        for (int i = tid; i < CC * 3 * 66; i += 256) {
            int xx = i % 66; int t = i / 66; int r = t % 3; int cc = t / 3;
            int gy = y - 1 + r, gx = xx - 1;
            float v = 0.f;
            if ((unsigned)gy < 64u && (unsigned)gx < 64u) {
                v = inb[(c0 + cc) * 4096 + gy * 64 + gx];
                if (IN_RELU) v = fmaxf(v, 0.f);
            }
            ls_in[cc][r][xx] = v;
        }
        const float* wsrc = wT + (size_t)c0 * 9 * WOC + oc_base;
        for (int i = tid; i < CC * 9 * COUT; i += 256) {
            int o = i % COUT; int tt = (i / COUT) % 9; int cc = i / (9 * COUT);
            ls_w[cc][tt][o] = wsrc[(cc * 9 + tt) * WOC + o];
        }
        __syncthreads();

        for (int cc = 0; cc < CC; ++cc) {
            float rv[3][PXB + 2];
            #pragma unroll
            for (int r = 0; r < 3; ++r) {
                const float* base = &ls_in[cc][r][x0];
                #pragma unroll
                for (int q = 0; q < PXB / 4; ++q) {
                    float4 v = *reinterpret_cast<const float4*>(base + 4 * q);
                    rv[r][4*q+0] = v.x; rv[r][4*q+1] = v.y;
                    rv[r][4*q+2] = v.z; rv[r][4*q+3] = v.w;
                }
                rv[r][PXB]     = base[PXB];
                rv[r][PXB + 1] = base[PXB + 1];
            }
            const float* lw = &ls_w[cc][0][0];
            #pragma unroll
            for (int dy = 0; dy < 3; ++dy) {
                #pragma unroll
                for (int dx = 0; dx < 3; ++dx) {
                    const float* wp = lw + (dy * 3 + dx) * COUT + oc0;
                    float wv[OCB];
                    if constexpr (OCB == 4) {
                        float4 w4 = *reinterpret_cast<const float4*>(wp);
                        wv[0] = w4.x; wv[1] = w4.y; wv[2] = w4.z; wv[3] = w4.w;
                    } else {
                        float2 w2 = *reinterpret_cast<const float2*>(wp);
                        wv[0] = w2.x; wv[1] = w2.y;
                    }
                    #pragma unroll
                    for (int p = 0; p < PXB; ++p) {
                        float iv = rv[dy][p + dx];
                        #pragma unroll
                        for (int o = 0; o < OCB; ++o)
                            acc[o][p] = fmaf(iv, wv[o], acc[o][p]);
                    }
                }
            }
        }
    }
    #pragma unroll
    for (int o = 0; o < OCB; ++o) {
        float* op = out + (((size_t)b * (COUT * NSLICE) + oc_base + oc0 + o) * 64 + y) * 64 + x0;
        #pragma unroll
        for (int q = 0; q < PXB / 4; ++q) {
            float4 v = make_float4(acc[o][4*q], acc[o][4*q+1],
                                   acc[o][4*q+2], acc[o][4*q+3]);
            *reinterpret_cast<float4*>(op + 4 * q) = v;
        }
    }
}

// ---------------- split-K res conv3x3: 128->32, relu(in), raw out ----------
__global__ __launch_bounds__(512) void conv3x3_res_k(
    const float* __restrict__ in, const float* __restrict__ wT,  // [c][9][32]
    float* __restrict__ out)
{
    constexpr int CC = 8;
    __shared__ __align__(16) float ls_in[2][CC][3][68];
    __shared__ __align__(16) float ls_w[2][CC][9][32];
    __shared__ float ts[8][256];
    int tid = threadIdx.x;
    int g = tid >> 8, t = tid & 255;
    int pxg = t & 15, ocg = t >> 4;     // PXB=4, OCB=2
    int x0 = pxg * 4, oc0 = ocg * 2;
    int y = blockIdx.x & 63, b = blockIdx.x >> 6;
    const float* inb = in + ((size_t)b * 128 + g * 64) * 4096;

    float acc[2][4];
    #pragma unroll
    for (int o = 0; o < 2; ++o)
        #pragma unroll
        for (int p = 0; p < 4; ++p) acc[o][p] = 0.f;

    for (int c0 = 0; c0 < 64; c0 += CC) {
        __syncthreads();
        for (int i = t; i < CC * 3 * 66; i += 256) {
            int xx = i % 66; int tt = i / 66; int r = tt % 3; int cc = tt / 3;
            int gy = y - 1 + r, gx = xx - 1;
            float v = 0.f;
            if ((unsigned)gy < 64u && (unsigned)gx < 64u)
                v = fmaxf(inb[(c0 + cc) * 4096 + gy * 64 + gx], 0.f);
            ls_in[g][cc][r][xx] = v;
        }
        const float* wsrc = wT + (size_t)(g * 64 + c0) * 9 * 32;
        for (int i = t; i < CC * 9 * 32; i += 256)
            (&ls_w[g][0][0][0])[i] = wsrc[i];
        __syncthreads();

        for (int cc = 0; cc < CC; ++cc) {
            float rv[3][6];
            #pragma unroll
            for (int r = 0; r < 3; ++r) {
                const float* base = &ls_in[g][cc][r][x0];
                float4 v = *reinterpret_cast<const float4*>(base);
                rv[r][0]=v.x; rv[r][1]=v.y; rv[r][2]=v.z; rv[r][3]=v.w;
                rv[r][4]=base[4]; rv[r][5]=base[5];
            }
            const float* lw = &ls_w[g][cc][0][0];
            #pragma unroll
            for (int dy = 0; dy < 3; ++dy) {
                #pragma unroll
                for (int dx = 0; dx < 3; ++dx) {
                    float2 w2 = *reinterpret_cast<const float2*>(lw + (dy * 3 + dx) * 32 + oc0);
                    float wv[2] = {w2.x, w2.y};
                    #pragma unroll
                    for (int p = 0; p < 4; ++p) {
                        float iv = rv[dy][p + dx];
                        acc[0][p] = fmaf(iv, wv[0], acc[0][p]);
                        acc[1][p] = fmaf(iv, wv[1], acc[1][p]);
                    }
                }
            }
        }
    }
    if (g == 0) {
        #pragma unroll
        for (int o = 0; o < 2; ++o)
            #pragma unroll
            for (int p = 0; p < 4; ++p) ts[o * 4 + p][t] = acc[o][p];
    }
    __syncthreads();
    if (g == 1) {
        #pragma unroll
        for (int o = 0; o < 2; ++o) {
            float4 v = make_float4(ts[o*4+0][t] + acc[o][0], ts[o*4+1][t] + acc[o][1],
                                   ts[o*4+2][t] + acc[o][2], ts[o*4+3][t] + acc[o][3]);
            float* op = out + (((size_t)b * 32 + oc0 + o) * 64 + y) * 64 + x0;
            *reinterpret_cast<float4*>(op) = v;
        }
    }
}

// ---------------- conv 1x1 on 64x64 (COUT must be 128) ----------------
template<int CIN, int COUT, int CC, bool IN_RELU, bool ADD_RES>
__global__ __launch_bounds__(256) void conv1x1_k(
    const float* __restrict__ in, const float* __restrict__ wT,
    const float* __restrict__ res, float* __restrict__ out)
{
    static_assert(COUT == 128, "tile assumes 128");
    __shared__ __align__(16) float ls_in[CC][64];
    __shared__ __align__(16) float ls_w[CC][COUT];
    int tid = threadIdx.x;
    int pxg = tid & 7, ocg = tid >> 3;
    int x0 = pxg * 8, oc0 = ocg * 4;
    int y = blockIdx.x & 63, b = blockIdx.x >> 6;

    float acc[4][8];
    #pragma unroll
    for (int o = 0; o < 4; ++o)
        #pragma unroll
        for (int p = 0; p < 8; ++p) acc[o][p] = 0.f;

    for (int c0 = 0; c0 < CIN; c0 += CC) {
        __syncthreads();
        for (int i = tid; i < CC * 64; i += 256) {
            int xx = i & 63, cc = i >> 6;
            float v = in[(((size_t)b * CIN + c0 + cc) * 64 + y) * 64 + xx];
            if (IN_RELU) v = fmaxf(v, 0.f);
            ls_in[cc][xx] = v;
        }
        const float* wsrc = wT + (size_t)c0 * COUT;
        for (int i = tid; i < CC * COUT; i += 256)
            (&ls_w[0][0])[i] = wsrc[i];
        __syncthreads();

        for (int cc = 0; cc < CC; ++cc) {
            float rv[8];
            const float* base = &ls_in[cc][x0];
            float4 v0 = *reinterpret_cast<const float4*>(base);
            float4 v1 = *reinterpret_cast<const float4*>(base + 4);
            rv[0]=v0.x; rv[1]=v0.y; rv[2]=v0.z; rv[3]=v0.w;
            rv[4]=v1.x; rv[5]=v1.y; rv[6]=v1.z; rv[7]=v1.w;
            float4 w4 = *reinterpret_cast<const float4*>(&ls_w[cc][oc0]);
            float wv[4] = {w4.x, w4.y, w4.z, w4.w};
            #pragma unroll
            for (int p = 0; p < 8; ++p)
                #pragma unroll
                for (int o = 0; o < 4; ++o)
                    acc[o][p] = fmaf(rv[p], wv[o], acc[o][p]);
        }
    }
    #pragma unroll
    for (int o = 0; o < 4; ++o) {
        float* op = out + (((size_t)b * COUT + oc0 + o) * 64 + y) * 64 + x0;
        const float* rp = res + (((size_t)b * COUT + oc0 + o) * 64 + y) * 64 + x0;
        #pragma unroll
        for (int q = 0; q < 2; ++q) {
            float4 v = make_float4(acc[o][4*q], acc[o][4*q+1],
                                   acc[o][4*q+2], acc[o][4*q+3]);
            if (ADD_RES) {
                float4 r4 = *reinterpret_cast<const float4*>(rp + 4 * q);
                v.x += r4.x; v.y += r4.y; v.z += r4.z; v.w += r4.w;
            }
            *reinterpret_cast<float4*>(op + 4 * q) = v;
        }
    }
}

// ---------------- conv 4x4 s2 p1, relu out, optional oc-slice ----------------
// ls_in rows padded +4 dwords every 16 (pi(xx) = xx + (xx>>4)*4): lane base
// becomes 20*pxg dwords -> the 8 bank-quads tile all 32 banks (was 8 banks).
template<int CIN, int COUT, int WOUT, int CC, int OCB, int WOC, int NSLICE>
__global__ __launch_bounds__(256) void conv4x4s2_k(
    const float* __restrict__ in, const float* __restrict__ wT,
    float* __restrict__ out)
{
    constexpr int WIN = WOUT * 2;
    constexpr int NPXG = WOUT / 8, NOCG = COUT / OCB;
    static_assert(NPXG * NOCG == 256, "bad tile");
    constexpr int WUSE = 2 * WOUT + 2;
    constexpr int PADLEN = ((WUSE + (WUSE / 16 + 1) * 4) + 3) & ~3;
    __shared__ __align__(16) float ls_in[CC][4][PADLEN];
    __shared__ __align__(16) float ls_w[CC][16][COUT];

    int tid = threadIdx.x;
    int pxg = tid % NPXG, ocg = tid / NPXG;
    int x0 = pxg * 8, oc0 = ocg * OCB;
    int blk = blockIdx.x;
    int y = blk % WOUT; int rest = blk / WOUT;
    int slice = rest % NSLICE; int b = rest / NSLICE;
    int oc_base = slice * COUT;
    const float* inb = in + (size_t)b * CIN * WIN * WIN;

    float acc[OCB][8];
    #pragma unroll
    for (int o = 0; o < OCB; ++o)
        #pragma unroll
        for (int p = 0; p < 8; ++p) acc[o][p] = 0.f;

    for (int c0 = 0; c0 < CIN; c0 += CC) {
        __syncthreads();
        for (int i = tid; i < CC * 4 * WUSE; i += 256) {
            int xx = i % WUSE; int t = i / WUSE; int r = t & 3; int cc = t >> 2;
            int gy = 2 * y - 1 + r, gx = xx - 1;
            float v = 0.f;
            if ((unsigned)gy < (unsigned)WIN && (unsigned)gx < (unsigned)WIN)
                v = inb[(c0 + cc) * WIN * WIN + gy * WIN + gx];
            ls_in[cc][r][xx + ((xx >> 4) << 2)] = v;
        }
        const float* wsrc = wT + (size_t)c0 * 16 * WOC + oc_base;
        for (int i = tid; i < CC * 16 * COUT; i += 256) {
            int o = i % COUT; int tt = (i / COUT) % 16; int cc = i / (16 * COUT);
            ls_w[cc][tt][o] = wsrc[(cc * 16 + tt) * WOC + o];
        }
        __syncthreads();

        for (int cc = 0; cc < CC; ++cc) {
            const float* lw = &ls_w[cc][0][0];
            #pragma unroll
            for (int ky = 0; ky < 4; ++ky) {
                float rv[18];
                const float* base = &ls_in[cc][ky][20 * pxg];
                #pragma unroll
                for (int q = 0; q < 4; ++q) {
                    float4 v = *reinterpret_cast<const float4*>(base + 4 * q);
                    rv[4*q]=v.x; rv[4*q+1]=v.y; rv[4*q+2]=v.z; rv[4*q+3]=v.w;
                }
                rv[16] = base[20]; rv[17] = base[21];   // cross one pad boundary
                #pragma unroll
                for (int kx = 0; kx < 4; ++kx) {
                    const float* wp = lw + (ky * 4 + kx) * COUT + oc0;
                    float wv[OCB];
                    if constexpr (OCB == 4) {
                        float4 w4 = *reinterpret_cast<const float4*>(wp);
                        wv[0]=w4.x; wv[1]=w4.y; wv[2]=w4.z; wv[3]=w4.w;
                    } else {
                        float2 w2 = *reinterpret_cast<const float2*>(wp);
                        wv[0]=w2.x; wv[1]=w2.y;
                    }
                    #pragma unroll
                    for (int p = 0; p < 8; ++p) {
                        float iv = rv[2 * p + kx];
                        #pragma unroll
                        for (int o = 0; o < OCB; ++o)
                            acc[o][p] = fmaf(iv, wv[o], acc[o][p]);
                    }
                }
            }
        }
    }
    #pragma unroll
    for (int o = 0; o < OCB; ++o) {
        float* op = out + (((size_t)b * (COUT * NSLICE) + oc_base + oc0 + o) * WOUT + y) * WOUT + x0;
        #pragma unroll
        for (int q = 0; q < 2; ++q) {
            float4 v = make_float4(fmaxf(acc[o][4*q],0.f), fmaxf(acc[o][4*q+1],0.f),
                                   fmaxf(acc[o][4*q+2],0.f), fmaxf(acc[o][4*q+3],0.f));
            *reinterpret_cast<float4*>(op + 4 * q) = v;
        }
    }
}

// ---------------- deconv 4x4 s2 p1, 128->64, relu(in) folded, relu out ------
#define DECONV_TAPS(RV, KY)                                                   \
    {                                                                         \
        int ky_ = (KY);                                                       \
        _Pragma("unroll")                                                     \
        for (int kx = 0; kx < 4; ++kx) {                                      \
            float4 w4 = *reinterpret_cast<const float4*>(                     \
                lw + (ky_ * 4 + kx) * 64 + oc0);                              \
            float wv[4] = {w4.x, w4.y, w4.z, w4.w};                           \
            if (kx & 1) {                                                     \
                _Pragma("unroll")                                             \
                for (int ph = 0; ph < 4; ++ph) {                              \
                    float iv = RV[(kx == 1) ? (ph + 1) : ph];                 \
                    _Pragma("unroll")                                         \
                    for (int o = 0; o < 4; ++o)                               \
                        acc[o][2*ph] = fmaf(iv, wv[o], acc[o][2*ph]);         \
                }                                                             \
            } else {                                                          \
                _Pragma("unroll")                                             \
                for (int ph = 0; ph < 4; ++ph) {                              \
                    float iv = RV[(kx == 0) ? (ph + 2) : (ph + 1)];           \
                    _Pragma("unroll")                                         \
                    for (int o = 0; o < 4; ++o)                               \
                        acc[o][2*ph+1] = fmaf(iv, wv[o], acc[o][2*ph+1]);     \
                }                                                             \
            }                                                                 \
        }                                                                     \
    }

template<int CC>
__global__ __launch_bounds__(256) void deconv_k(
    const float* __restrict__ in, const float* __restrict__ wT,
    float* __restrict__ out)
{
    __shared__ __align__(16) float ls_in[CC][2][68];
    __shared__ __align__(16) float ls_w[CC][16][64];
    int tid = threadIdx.x;
    int pxg = tid & 15, ocg = tid >> 4;
    int x0 = pxg * 8, oc0 = ocg * 4, xh = pxg * 4;
    int oy = blockIdx.x & 127, b = blockIdx.x >> 7;
    int r1 = (oy + 1) >> 1;
    int ky0 = (oy + 1) & 1;
    const float* inb = in + (size_t)b * 128 * 4096;

    float acc[4][8];
    #pragma unroll
    for (int o = 0; o < 4; ++o)
        #pragma unroll
        for (int p = 0; p < 8; ++p) acc[o][p] = 0.f;

    for (int c0 = 0; c0 < 128; c0 += CC) {
        __syncthreads();
        for (int i = tid; i < CC * 2 * 66; i += 256) {
            int xx = i % 66; int t = i / 66; int rr = t & 1; int cc = t >> 1;
            int iy = r1 - 1 + rr, gx = xx - 1;
            float v = 0.f;
            if ((unsigned)iy < 64u && (unsigned)gx < 64u)
                v = fmaxf(inb[(c0 + cc) * 4096 + iy * 64 + gx], 0.f);
            ls_in[cc][rr][xx] = v;
        }
        const float* wsrc = wT + (size_t)c0 * 16 * 64;
        for (int i = tid; i < CC * 16 * 64; i += 256)
            (&ls_w[0][0][0])[i] = wsrc[i];
        __syncthreads();

        for (int cc = 0; cc < CC; ++cc) {
            float rvA[6], rvB[6];
            {
                const float* bA = &ls_in[cc][1][xh];
                float4 v = *reinterpret_cast<const float4*>(bA);
                rvA[0]=v.x; rvA[1]=v.y; rvA[2]=v.z; rvA[3]=v.w;
                rvA[4]=bA[4]; rvA[5]=bA[5];
                const float* bB = &ls_in[cc][0][xh];
                float4 u = *reinterpret_cast<const float4*>(bB);
                rvB[0]=u.x; rvB[1]=u.y; rvB[2]=u.z; rvB[3]=u.w;
                rvB[4]=bB[4]; rvB[5]=bB[5];
            }
            const float* lw = &ls_w[cc][0][0];
            DECONV_TAPS(rvA, ky0);
            DECONV_TAPS(rvB, ky0 + 2);
        }
    }
    #pragma unroll
    for (int o = 0; o < 4; ++o) {
        float* op = out + (((size_t)b * 64 + oc0 + o) * 128 + oy) * 128 + x0;
        #pragma unroll
        for (int q = 0; q < 2; ++q) {
            float4 v = make_float4(fmaxf(acc[o][4*q],0.f), fmaxf(acc[o][4*q+1],0.f),
                                   fmaxf(acc[o][4*q+2],0.f), fmaxf(acc[o][4*q+3],0.f));
            *reinterpret_cast<float4*>(op + 4 * q) = v;
        }
    }
}

// ---------------- fused bilinear-2x(align) + conv3x3 64->3 + 2*sigmoid-1 ----
template<int CC>
__global__ __launch_bounds__(256) void upconv_k(
    const float* __restrict__ in, const float* __restrict__ wT3,
    float* __restrict__ out)
{
    __shared__ __align__(16) float ls_u[CC][6][260];
    __shared__ float ls_w[64 * 27];
    int tid = threadIdx.x;
    int pxg = tid & 63, row = tid >> 6;
    int x0 = pxg * 4;
    int yblk = blockIdx.x & 63, b = blockIdx.x >> 6;
    int y0 = yblk * 4, y = y0 + row;
    const float SCL = 127.0f / 255.0f;
    const float* hb = in + (size_t)b * 64 * 16384;

    for (int i = tid; i < 1728; i += 256) ls_w[i] = wT3[i];

    float acc[3][4];
    #pragma unroll
    for (int o = 0; o < 3; ++o)
        #pragma unroll
        for (int p = 0; p < 4; ++p) acc[o][p] = 0.f;

    for (int c0 = 0; c0 < 64; c0 += CC) {
        __syncthreads();
        for (int i = tid; i < CC * 6 * 258; i += 256) {
            int xx = i % 258; int t = i / 258; int r = t % 6; int cc = t / 6;
            int uy = y0 - 1 + r, gx = xx - 1;
            float v = 0.f;
            if ((unsigned)uy < 256u && (unsigned)gx < 256u) {
                float py = uy * SCL;
                int ylo = (int)py; int yhi = min(ylo + 1, 127); float fy = py - ylo;
                float px = gx * SCL;
                int xlo = (int)px; int xhi = min(xlo + 1, 127); float fx = px - xlo;
                const float* hp = hb + (c0 + cc) * 16384 + ylo * 128;
                const float* hq = hb + (c0 + cc) * 16384 + yhi * 128;
                float a = hp[xlo], b2 = hp[xhi], c2 = hq[xlo], d2 = hq[xhi];
                float top = a + (b2 - a) * fx;
                float bot = c2 + (d2 - c2) * fx;
                v = top + (bot - top) * fy;
            }
            ls_u[cc][r][xx] = v;
        }
        __syncthreads();

        for (int cc = 0; cc < CC; ++cc) {
            #pragma unroll
            for (int j = 0; j < 3; ++j) {
                float rv[6];
                const float* base = &ls_u[cc][row + j][x0];
                float4 v = *reinterpret_cast<const float4*>(base);
                rv[0]=v.x; rv[1]=v.y; rv[2]=v.z; rv[3]=v.w;
                rv[4]=base[4]; rv[5]=base[5];
                #pragma unroll
                for (int i2 = 0; i2 < 3; ++i2) {
                    const float* wp = &ls_w[((c0 + cc) * 9 + (j * 3 + i2)) * 3];
                    float w0 = wp[0], w1 = wp[1], w2 = wp[2];
                    #pragma unroll
                    for (int p = 0; p < 4; ++p) {
                        float iv = rv[p + i2];
                        acc[0][p] = fmaf(iv, w0, acc[0][p]);
                        acc[1][p] = fmaf(iv, w1, acc[1][p]);
                        acc[2][p] = fmaf(iv, w2, acc[2][p]);
                    }
                }
            }
        }
    }
    #pragma unroll
    for (int o = 0; o < 3; ++o) {
        float4 v;
        v.x = 2.f / (1.f + expf(-acc[o][0])) - 1.f;
        v.y = 2.f / (1.f + expf(-acc[o][1])) - 1.f;
        v.z = 2.f / (1.f + expf(-acc[o][2])) - 1.f;
        v.w = 2.f / (1.f + expf(-acc[o][3])) - 1.f;
        float* op = out + (((size_t)b * 3 + o) * 256 + y) * 256 + x0;
        *reinterpret_cast<float4*>(op) = v;
    }
}

// ---------------- codebook prep (also zeroes counts) ----------------
__global__ void prep_codebook(const float* __restrict__ cb,
                              float* __restrict__ cbT, float* __restrict__ ce2,
                              unsigned int* __restrict__ counts)
{
    int k = blockIdx.x * 256 + threadIdx.x;
    if (k >= 1024) return;
    float s = 0.f;
    for (int d = 0; d < 128; ++d) {
        float v = cb[k * 128 + d];
        cbT[d * 1024 + k] = v;
        s = fmaf(v, v, s);
    }
    ce2[k] = s;
    counts[k] = 0u;
}

// ---------------- fused VQ v2: 32 px/block, 1024 blocks ----------------
__global__ __launch_bounds__(512) void vq_fused(
    const float* __restrict__ z,     // NCHW [8,128,64,64]
    const float* __restrict__ cb,    // original [1024][128]
    const float* __restrict__ cbT,   // [128][1024]
    const float* __restrict__ ce2,   // [1024]
    unsigned int* __restrict__ counts,
    float* __restrict__ q,           // NCHW
    double* __restrict__ partial)    // [1024]
{
    __shared__ float zl[128][32];    // 16 KB
    __shared__ int sidx[32];
    __shared__ float red[8];

    int tid = threadIdx.x;
    int lane = tid & 63;
    int w = tid >> 6;                // 8 waves, 4 pixels each
    int b = blockIdx.x >> 7;
    int p0 = (blockIdx.x & 127) * 32;

    for (int i = tid; i < 4096; i += 512) {
        int d = i >> 5, pix = i & 31;
        zl[d][pix] = z[((size_t)b * 128 + d) * 4096 + p0 + pix];
    }
    __syncthreads();

    float best[4]; int bidx[4];
    #pragma unroll
    for (int j = 0; j < 4; ++j) { best[j] = 3.4e38f; bidx[j] = 0; }

    for (int kt = 0; kt < 2; ++kt) {
        int k0 = kt * 512 + lane * 8;
        float acc[4][8];
        #pragma unroll
        for (int p = 0; p < 4; ++p)
            #pragma unroll
            for (int c = 0; c < 8; ++c) acc[p][c] = 0.f;

        const float* cbp = cbT + k0;
        for (int d = 0; d < 128; ++d) {
            float4 zq = *reinterpret_cast<const float4*>(&zl[d][w * 4]);
            float zv[4] = {zq.x, zq.y, zq.z, zq.w};
            float4 c0 = *reinterpret_cast<const float4*>(cbp + (size_t)d * 1024);
            float4 c1 = *reinterpret_cast<const float4*>(cbp + (size_t)d * 1024 + 4);
            float cv[8] = {c0.x, c0.y, c0.z, c0.w, c1.x, c1.y, c1.z, c1.w};
            #pragma unroll
            for (int p = 0; p < 4; ++p)
                #pragma unroll
                for (int c = 0; c < 8; ++c)
                    acc[p][c] = fmaf(zv[p], cv[c], acc[p][c]);
        }
        float4 e0 = *reinterpret_cast<const float4*>(ce2 + k0);
        float4 e1 = *reinterpret_cast<const float4*>(ce2 + k0 + 4);
        float ev[8] = {e0.x, e0.y, e0.z, e0.w, e1.x, e1.y, e1.z, e1.w};
        #pragma unroll
        for (int c = 0; c < 8; ++c) {
            #pragma unroll
            for (int p = 0; p < 4; ++p) {
                float dist = ev[c] - 2.f * acc[p][c];
                if (dist < best[p]) { best[p] = dist; bidx[p] = k0 + c; }
            }
        }
    }

    #pragma unroll
    for (int j = 0; j < 4; ++j) {
        float bv = best[j]; int bi = bidx[j];
        #pragma unroll
        for (int off = 32; off > 0; off >>= 1) {
            float ov = __shfl_xor(bv, off);
            int   oi = __shfl_xor(bi, off);
            if (ov < bv || (ov == bv && oi < bi)) { bv = ov; bi = oi; }
        }
        if (lane == 0) {
            sidx[w * 4 + j] = bi;
            atomicAdd(&counts[bi], 1u);
        }
    }
    __syncthreads();

    // gather + q write + loss: pix = tid&31, dg = tid>>5 (16 groups x 8 d)
    int pix = tid & 31, dg = tid >> 5;
    int kidx = sidx[pix];
    const float* crow = cb + (size_t)kidx * 128 + dg * 8;
    float sq = 0.f;
    size_t qbase = ((size_t)b * 128 + dg * 8) * 4096 + p0 + pix;
    float4 c4a = *reinterpret_cast<const float4*>(crow);
    float4 c4b = *reinterpret_cast<const float4*>(crow + 4);
    float vals[8] = {c4a.x, c4a.y, c4a.z, c4a.w, c4b.x, c4b.y, c4b.z, c4b.w};
    #pragma unroll
    for (int jj = 0; jj < 8; ++jj) {
        float qv = vals[jj];
        float zv = zl[dg * 8 + jj][pix];
        float df = qv - zv;
        sq = fmaf(df, df, sq);
        q[qbase + (size_t)jj * 4096] = qv;
    }
    #pragma unroll
    for (int off = 32; off > 0; off >>= 1) sq += __shfl_xor(sq, off);
    if (lane == 0) red[w] = sq;
    __syncthreads();
    if (tid == 0) {
        double s = 0.0;
        #pragma unroll
        for (int ww = 0; ww < 8; ++ww) s += (double)red[ww];
        partial[blockIdx.x] = s;
    }
}

// ---------------- finalize ----------------
__global__ __launch_bounds__(256) void finalize_kernel(
    const double* __restrict__ partial, const unsigned int* __restrict__ counts,
    float* __restrict__ dout)
{
    __shared__ double sd[256];
    __shared__ double lossSh;
    int tid = threadIdx.x;
    double s = 0.0;
    for (int i = tid; i < 1024; i += 256) s += partial[i];
    sd[tid] = s; __syncthreads();
    for (int off = 128; off > 0; off >>= 1) {
        if (tid < off) sd[tid] += sd[tid + off];
        __syncthreads();
    }
    if (tid == 0) lossSh = CC_COST * sd[0] / 4194304.0;
    __syncthreads();

    double h = 0.0;
    for (int k = tid; k < 1024; k += 256) {
        double pp = (double)counts[k] / 32768.0;
        h += pp * log(pp + 1e-10);
    }
    sd[tid] = h; __syncthreads();
    for (int off = 128; off > 0; off >>= 1) {
        if (tid < off) sd[tid] += sd[tid + off];
        __syncthreads();
    }
    if (tid == 0) {
        dout[0]       = (float)lossSh;
        dout[1572865] = (float)exp(-sd[0]);
    }
}

// ===========================================================================
extern "C" void kernel_launch(void* const* d_in, const int* in_sizes, int n_in,
                              void* d_out, int out_size, void* d_ws, size_t ws_size,
                              hipStream_t stream)
{
    const float* x        = (const float*)d_in[0];
    const float* enc_c1   = (const float*)d_in[1];
    const float* enc_c2   = (const float*)d_in[2];
    const float* enc_c3   = (const float*)d_in[3];
    const float* enc_r1a  = (const float*)d_in[4];
    const float* enc_r1b  = (const float*)d_in[5];
    const float* enc_r2a  = (const float*)d_in[6];
    const float* enc_r2b  = (const float*)d_in[7];
    const float* pre_vq_w = (const float*)d_in[8];
    const float* codebook = (const float*)d_in[9];
    const float* dec_c1   = (const float*)d_in[10];
    const float* dec_r1a  = (const float*)d_in[11];
    const float* dec_r1b  = (const float*)d_in[12];
    const float* dec_r2a  = (const float*)d_in[13];
    const float* dec_r2b  = (const float*)d_in[14];
    const float* dec_dc   = (const float*)d_in[15];
    const float* dec_c3   = (const float*)d_in[16];
    float* dout = (float*)d_out;

    char* wsp = (char*)d_ws;
    auto alloc = [&](size_t bytes) {
        void* p = (void*)wsp;
        wsp += (bytes + 255) & ~(size_t)255;
        return p;
    };
    float* h1   = (float*)alloc(8ull*64*128*128*4);   // 32MB; also qb alias
    float* bufA = (float*)alloc(8ull*128*64*64*4);    // 16MB; also zb alias
    float* bufB = (float*)alloc(8ull*128*64*64*4);    // 16MB
    float* bufT = (float*)alloc(8ull*32*64*64*4);     // 4MB
    float* cbT  = (float*)alloc(128*1024*4);
    float* ce2  = (float*)alloc(1024*4);
    unsigned int* counts = (unsigned int*)alloc(1024*4);
    double* partial = (double*)alloc(1024*8);
    float* wt_ec1  = (float*)alloc(3072*4);
    float* wt_ec2  = (float*)alloc(131072*4);
    float* wt_ec3  = (float*)alloc(147456*4);
    float* wt_er1a = (float*)alloc(36864*4);
    float* wt_er1b = (float*)alloc(4096*4);
    float* wt_er2a = (float*)alloc(36864*4);
    float* wt_er2b = (float*)alloc(4096*4);
    float* wt_pvq  = (float*)alloc(16384*4);
    float* wt_dc1  = (float*)alloc(147456*4);
    float* wt_dr1a = (float*)alloc(36864*4);
    float* wt_dr1b = (float*)alloc(4096*4);
    float* wt_dr2a = (float*)alloc(36864*4);
    float* wt_dr2b = (float*)alloc(4096*4);
    float* wt_ddc  = (float*)alloc(131072*4);
    float* wt_dc3  = (float*)alloc(1728*4);
    float* zb = bufA;   // alias: pre_vq out, dead before dec_c1 writes bufA
    float* qb = h1;     // alias: dead before deconv overwrites h1

    // VQ prep (+counts zero)
    prep_codebook<<<4, 256, 0, stream>>>(codebook, cbT, ce2, counts);

    // batched weight transforms
    WtJobs J;
    const float* srcs[15] = {enc_c1, enc_c2, enc_c3, enc_r1a, enc_r1b, enc_r2a,
                             enc_r2b, pre_vq_w, dec_c1, dec_r1a, dec_r1b,
                             dec_r2a, dec_r2b, dec_dc, dec_c3};
    float* dsts[15] = {wt_ec1, wt_ec2, wt_ec3, wt_er1a, wt_er1b, wt_er2a,
                       wt_er2b, wt_pvq, wt_dc1, wt_dr1a, wt_dr1b,
                       wt_dr2a, wt_dr2b, wt_ddc, wt_dc3};
    int couts[15] = {64, 128, 128, 32, 128, 32, 128, 128, 128, 32, 128, 32, 128, 64, 3};
    int cins[15]  = {3, 64, 128, 128, 32, 128, 32, 128, 128, 128, 32, 128, 32, 128, 64};
    int kks[15]   = {16, 16, 9, 9, 1, 9, 1, 1, 9, 9, 1, 9, 1, 16, 9};
    int kinds[15] = {0, 0, 0, 0, 0, 0, 0, 0, 0, 0, 0, 0, 0, 1, 2};
    int off = 0;
    for (int j = 0; j < 15; ++j) {
        J.src[j] = srcs[j]; J.dst[j] = dsts[j];
        J.cout[j] = couts[j]; J.cin[j] = cins[j]; J.kk[j] = kks[j];
        J.kind[j] = kinds[j];
        J.blk0[j] = off;
        off += (couts[j] * cins[j] * kks[j] + 255) / 256;
    }
    J.blk0[15] = off;
    wt_batch_k<<<off, 256, 0, stream>>>(J);

    // ---- encoder ----
    conv4x4s2_k<3, 64, 128, 3, 4, 64, 1><<<1024, 256, 0, stream>>>(x, wt_ec1, h1);
    conv4x4s2_k<64, 64, 64, 4, 2, 128, 2><<<1024, 256, 0, stream>>>(h1, wt_ec2, bufA);
    conv3x3_k<128, 64, 4, 4, 8, false, 128, 2><<<1024, 256, 0, stream>>>(bufA, wt_ec3, bufB);
    conv3x3_res_k<<<512, 512, 0, stream>>>(bufB, wt_er1a, bufT);
    conv1x1_k<32, 128, 32, true, true><<<512, 256, 0, stream>>>(bufT, wt_er1b, bufB, bufB);
    conv3x3_res_k<<<512, 512, 0, stream>>>(bufB, wt_er2a, bufT);
    conv1x1_k<32, 128, 32, true, true><<<512, 256, 0, stream>>>(bufT, wt_er2b, bufB, bufB);
    conv1x1_k<128, 128, 32, true, false><<<512, 256, 0, stream>>>(bufB, wt_pvq, bufB, zb);

    // ---- VQ (fused argmin + gather + loss) ----
    vq_fused<<<1024, 512, 0, stream>>>(zb, codebook, cbT, ce2, counts, qb, partial);

    // ---- decoder ----
    conv3x3_k<128, 64, 4, 4, 8, false, 128, 2><<<1024, 256, 0, stream>>>(qb, wt_dc1, bufA);
    conv3x3_res_k<<<512, 512, 0, stream>>>(bufA, wt_dr1a, bufT);
    conv1x1_k<32, 128, 32, true, true><<<512, 256, 0, stream>>>(bufT, wt_dr1b, bufA, bufA);
    conv3x3_res_k<<<512, 512, 0, stream>>>(bufA, wt_dr2a, bufT);
    conv1x1_k<32, 128, 32, true, true><<<512, 256, 0, stream>>>(bufT, wt_dr2b, bufA, bufA);
    deconv_k<4><<<1024, 256, 0, stream>>>(bufA, wt_ddc, h1);
    upconv_k<2><<<512, 256, 0, stream>>>(h1, wt_dc3, dout + 1);

    // ---- scalars ----
    finalize_kernel<<<1, 256, 0, stream>>>(partial, counts, dout);
}

// Round 7
// 1222.456 us; speedup vs baseline: 8.9737x; 1.2033x over previous
//
#include <hip/hip_runtime.h>
#include <hip/hip_bf16.h>
#include <math.h>

#define CC_COST 0.25

typedef __attribute__((ext_vector_type(8))) short short8v;
typedef __attribute__((ext_vector_type(16))) float f32x16;

__device__ __forceinline__ unsigned short f2bf(float f) {
    unsigned u = __float_as_uint(f);
    unsigned r = (u + 0x7FFFu + ((u >> 16) & 1u)) >> 16;
    return (unsigned short)r;
}
__device__ __forceinline__ float bf2f(unsigned short h) {
    return __uint_as_float(((unsigned)h) << 16);
}

// ===========================================================================
// VQ-VAE forward. Big 3x3 convs on MFMA (bf16 hi/lo 3-product ~ fp32 exact),
// rest fp32 vector. d_out[0]=loss, [1..1572864]=recon, [1572865]=perplexity
// ===========================================================================

// ---------------- batched weight transforms (fp32 vector kernels) ----------
struct WtJobs {
    const float* src[15];
    float* dst[15];
    int cout[15], cin[15], kk[15], kind[15];
    int blk0[16];
};

__global__ void wt_batch_k(WtJobs J)
{
    int blk = blockIdx.x;
    int j = 0;
    while (j < 14 && blk >= J.blk0[j + 1]) ++j;
    int i = (blk - J.blk0[j]) * 256 + threadIdx.x;
    int total = J.cout[j] * J.cin[j] * J.kk[j];
    if (i >= total) return;
    const float* src = J.src[j];
    float* dst = J.dst[j];
    int kind = J.kind[j];
    if (kind == 0) {
        int Cout = J.cout[j], Cin = J.cin[j], KK = J.kk[j];
        int oc = i % Cout; int t2 = i / Cout; int t = t2 % KK; int c = t2 / KK;
        dst[i] = src[(oc * Cin + c) * KK + t];
    } else if (kind == 1) {
        int oc = i & 63; int t = (i >> 6) & 15; int c = i >> 10;
        dst[i] = src[(c * 64 + oc) * 16 + t];
    } else {
        int o = i % 3; int t = (i / 3) % 9; int c = i / 27;
        dst[i] = src[(o * 64 + c) * 9 + t];
    }
}

// split OIHW [128][128][3][3] fp32 -> whi/wlo bf16 in [9 tap][8 cb][128 oc][16 ci]
__global__ void wt_split_k(const float* __restrict__ w,
                           unsigned short* __restrict__ whi,
                           unsigned short* __restrict__ wlo)
{
    int i = blockIdx.x * 256 + threadIdx.x;
    if (i >= 147456) return;
    int ci = i & 15;
    int oc = (i >> 4) & 127;
    int rest = i >> 11;           // 0..71
    int cb = rest & 7;
    int tap = rest >> 3;          // 0..8
    float v = w[(oc * 128 + cb * 16 + ci) * 9 + tap];
    unsigned short h = f2bf(v);
    whi[i] = h;
    wlo[i] = f2bf(v - bf2f(h));
}

// ---------------- MFMA conv3x3 s1 p1, 128->128, 64x64, batch 8 -------------
// grid 256 = b(8) x rowpair(32); block 512 = 8 waves.
// wave w: output row y0+(w&1), oc range (w>>1)*32 .. +32, px 0..63 (2 tiles).
__global__ __launch_bounds__(512) void conv3x3_mfma(
    const float* __restrict__ in,           // [8,128,64,64]
    const unsigned short* __restrict__ whi, // [9][8][128][16] bf16
    const unsigned short* __restrict__ wlo,
    float* __restrict__ out)                // [8,128,64,64]
{
    constexpr int CST = 40;                 // 32 cc + 8 pad (80B: 16B-aligned)
    __shared__ unsigned short ls_hi[4 * 68 * CST];
    __shared__ unsigned short ls_lo[4 * 68 * CST];

    int tid = threadIdx.x;
    int lane = tid & 63;
    int w = tid >> 6;
    int myrow = w & 1;
    int oc0 = (w >> 1) * 32;
    int y0 = (blockIdx.x & 31) * 2;
    int b  = blockIdx.x >> 5;
    int ln31 = lane & 31;
    int lhf  = lane >> 5;

    f32x16 acc0 = {};
    f32x16 acc1 = {};

    const float* inb = in + (size_t)b * 128 * 4096;

    for (int chunk = 0; chunk < 4; ++chunk) {
        int c0 = chunk * 32;
        __syncthreads();
        // stage rows y0-1..y0+2, gx -1..64, cc c0..c0+31 as hi/lo bf16
        for (int i = tid; i < 4 * 66 * 16; i += 512) {
            int x = i % 66;               // slot; gx = x-1
            int t = i / 66;
            int cp = t & 15;              // cc pair
            int r = t >> 4;               // 0..3
            int gy = y0 - 1 + r, gx = x - 1;
            float v0 = 0.f, v1 = 0.f;
            if ((unsigned)gy < 64u && (unsigned)gx < 64u) {
                const float* p = inb + (size_t)(c0 + 2 * cp) * 4096 + gy * 64 + gx;
                v0 = p[0];
                v1 = p[4096];
            }
            unsigned short h0 = f2bf(v0), h1 = f2bf(v1);
            unsigned short l0 = f2bf(v0 - bf2f(h0)), l1 = f2bf(v1 - bf2f(h1));
            int a = (r * 68 + x) * CST + 2 * cp;
            *reinterpret_cast<unsigned int*>(&ls_hi[a]) = (unsigned)h0 | ((unsigned)h1 << 16);
            *reinterpret_cast<unsigned int*>(&ls_lo[a]) = (unsigned)l0 | ((unsigned)l1 << 16);
        }
        __syncthreads();

        #pragma unroll
        for (int tap = 0; tap < 9; ++tap) {
            int dy = tap / 3, dx = tap - 3 * (tap / 3);
            int rbase = (myrow + dy) * 68;
            #pragma unroll
            for (int cb = 0; cb < 2; ++cb) {
                int cbg = chunk * 2 + cb;
                size_t wofs = (((size_t)tap * 8 + cbg) * 128 + oc0 + ln31) * 16 + lhf * 8;
                short8v ah = *reinterpret_cast<const short8v*>(whi + wofs);
                short8v al = *reinterpret_cast<const short8v*>(wlo + wofs);
                int k0 = cb * 16 + lhf * 8;
                int xo0 = (rbase + ln31 + dx) * CST + k0;
                int xo1 = (rbase + 32 + ln31 + dx) * CST + k0;
                short8v bh0 = *reinterpret_cast<const short8v*>(&ls_hi[xo0]);
                short8v bl0 = *reinterpret_cast<const short8v*>(&ls_lo[xo0]);
                short8v bh1 = *reinterpret_cast<const short8v*>(&ls_hi[xo1]);
                short8v bl1 = *reinterpret_cast<const short8v*>(&ls_lo[xo1]);
                acc0 = __builtin_amdgcn_mfma_f32_32x32x16_bf16(ah, bh0, acc0, 0, 0, 0);
                acc1 = __builtin_amdgcn_mfma_f32_32x32x16_bf16(ah, bh1, acc1, 0, 0, 0);
                acc0 = __builtin_amdgcn_mfma_f32_32x32x16_bf16(ah, bl0, acc0, 0, 0, 0);
                acc1 = __builtin_amdgcn_mfma_f32_32x32x16_bf16(ah, bl1, acc1, 0, 0, 0);
                acc0 = __builtin_amdgcn_mfma_f32_32x32x16_bf16(al, bh0, acc0, 0, 0, 0);
                acc1 = __builtin_amdgcn_mfma_f32_32x32x16_bf16(al, bh1, acc1, 0, 0, 0);
            }
        }
    }

    float* ob = out + (size_t)b * 128 * 4096 + (size_t)(y0 + myrow) * 64;
    #pragma unroll
    for (int r = 0; r < 16; ++r) {
        int oc = oc0 + (r & 3) + 8 * (r >> 2) + 4 * lhf;
        ob[(size_t)oc * 4096 + ln31]      = acc0[r];
        ob[(size_t)oc * 4096 + 32 + ln31] = acc1[r];
    }
}

// ---------------- split-K res conv3x3: 128->32, relu(in), raw out ----------
__global__ __launch_bounds__(512) void conv3x3_res_k(
    const float* __restrict__ in, const float* __restrict__ wT,  // [c][9][32]
    float* __restrict__ out)
{
    constexpr int CC = 8;
    __shared__ __align__(16) float ls_in[2][CC][3][68];
    __shared__ __align__(16) float ls_w[2][CC][9][32];
    __shared__ float ts[8][256];
    int tid = threadIdx.x;
    int g = tid >> 8, t = tid & 255;
    int pxg = t & 15, ocg = t >> 4;
    int x0 = pxg * 4, oc0 = ocg * 2;
    int y = blockIdx.x & 63, b = blockIdx.x >> 6;
    const float* inb = in + ((size_t)b * 128 + g * 64) * 4096;

    float acc[2][4];
    #pragma unroll
    for (int o = 0; o < 2; ++o)
        #pragma unroll
        for (int p = 0; p < 4; ++p) acc[o][p] = 0.f;

    for (int c0 = 0; c0 < 64; c0 += CC) {
        __syncthreads();
        for (int i = t; i < CC * 3 * 66; i += 256) {
            int xx = i % 66; int tt = i / 66; int r = tt % 3; int cc = tt / 3;
            int gy = y - 1 + r, gx = xx - 1;
            float v = 0.f;
            if ((unsigned)gy < 64u && (unsigned)gx < 64u)
                v = fmaxf(inb[(c0 + cc) * 4096 + gy * 64 + gx], 0.f);
            ls_in[g][cc][r][xx] = v;
        }
        const float* wsrc = wT + (size_t)(g * 64 + c0) * 9 * 32;
        for (int i = t; i < CC * 9 * 32; i += 256)
            (&ls_w[g][0][0][0])[i] = wsrc[i];
        __syncthreads();

        for (int cc = 0; cc < CC; ++cc) {
            float rv[3][6];
            #pragma unroll
            for (int r = 0; r < 3; ++r) {
                const float* base = &ls_in[g][cc][r][x0];
                float4 v = *reinterpret_cast<const float4*>(base);
                rv[r][0]=v.x; rv[r][1]=v.y; rv[r][2]=v.z; rv[r][3]=v.w;
                rv[r][4]=base[4]; rv[r][5]=base[5];
            }
            const float* lw = &ls_w[g][cc][0][0];
            #pragma unroll
            for (int dy = 0; dy < 3; ++dy) {
                #pragma unroll
                for (int dx = 0; dx < 3; ++dx) {
                    float2 w2 = *reinterpret_cast<const float2*>(lw + (dy * 3 + dx) * 32 + oc0);
                    float wv[2] = {w2.x, w2.y};
                    #pragma unroll
                    for (int p = 0; p < 4; ++p) {
                        float iv = rv[dy][p + dx];
                        acc[0][p] = fmaf(iv, wv[0], acc[0][p]);
                        acc[1][p] = fmaf(iv, wv[1], acc[1][p]);
                    }
                }
            }
        }
    }
    if (g == 0) {
        #pragma unroll
        for (int o = 0; o < 2; ++o)
            #pragma unroll
            for (int p = 0; p < 4; ++p) ts[o * 4 + p][t] = acc[o][p];
    }
    __syncthreads();
    if (g == 1) {
        #pragma unroll
        for (int o = 0; o < 2; ++o) {
            float4 v = make_float4(ts[o*4+0][t] + acc[o][0], ts[o*4+1][t] + acc[o][1],
                                   ts[o*4+2][t] + acc[o][2], ts[o*4+3][t] + acc[o][3]);
            float* op = out + (((size_t)b * 32 + oc0 + o) * 64 + y) * 64 + x0;
            *reinterpret_cast<float4*>(op) = v;
        }
    }
}

// ---------------- conv 1x1 on 64x64 (COUT must be 128) ----------------
template<int CIN, int COUT, int CC, bool IN_RELU, bool ADD_RES>
__global__ __launch_bounds__(256) void conv1x1_k(
    const float* __restrict__ in, const float* __restrict__ wT,
    const float* __restrict__ res, float* __restrict__ out)
{
    static_assert(COUT == 128, "tile assumes 128");
    __shared__ __align__(16) float ls_in[CC][64];
    __shared__ __align__(16) float ls_w[CC][COUT];
    int tid = threadIdx.x;
    int pxg = tid & 7, ocg = tid >> 3;
    int x0 = pxg * 8, oc0 = ocg * 4;
    int y = blockIdx.x & 63, b = blockIdx.x >> 6;

    float acc[4][8];
    #pragma unroll
    for (int o = 0; o < 4; ++o)
        #pragma unroll
        for (int p = 0; p < 8; ++p) acc[o][p] = 0.f;

    for (int c0 = 0; c0 < CIN; c0 += CC) {
        __syncthreads();
        for (int i = tid; i < CC * 64; i += 256) {
            int xx = i & 63, cc = i >> 6;
            float v = in[(((size_t)b * CIN + c0 + cc) * 64 + y) * 64 + xx];
            if (IN_RELU) v = fmaxf(v, 0.f);
            ls_in[cc][xx] = v;
        }
        const float* wsrc = wT + (size_t)c0 * COUT;
        for (int i = tid; i < CC * COUT; i += 256)
            (&ls_w[0][0])[i] = wsrc[i];
        __syncthreads();

        for (int cc = 0; cc < CC; ++cc) {
            float rv[8];
            const float* base = &ls_in[cc][x0];
            float4 v0 = *reinterpret_cast<const float4*>(base);
            float4 v1 = *reinterpret_cast<const float4*>(base + 4);
            rv[0]=v0.x; rv[1]=v0.y; rv[2]=v0.z; rv[3]=v0.w;
            rv[4]=v1.x; rv[5]=v1.y; rv[6]=v1.z; rv[7]=v1.w;
            float4 w4 = *reinterpret_cast<const float4*>(&ls_w[cc][oc0]);
            float wv[4] = {w4.x, w4.y, w4.z, w4.w};
            #pragma unroll
            for (int p = 0; p < 8; ++p)
                #pragma unroll
                for (int o = 0; o < 4; ++o)
                    acc[o][p] = fmaf(rv[p], wv[o], acc[o][p]);
        }
    }
    #pragma unroll
    for (int o = 0; o < 4; ++o) {
        float* op = out + (((size_t)b * COUT + oc0 + o) * 64 + y) * 64 + x0;
        const float* rp = res + (((size_t)b * COUT + oc0 + o) * 64 + y) * 64 + x0;
        #pragma unroll
        for (int q = 0; q < 2; ++q) {
            float4 v = make_float4(acc[o][4*q], acc[o][4*q+1],
                                   acc[o][4*q+2], acc[o][4*q+3]);
            if (ADD_RES) {
                float4 r4 = *reinterpret_cast<const float4*>(rp + 4 * q);
                v.x += r4.x; v.y += r4.y; v.z += r4.z; v.w += r4.w;
            }
            *reinterpret_cast<float4*>(op + 4 * q) = v;
        }
    }
}

// ---------------- conv 4x4 s2 p1, relu out, optional oc-slice ----------------
template<int CIN, int COUT, int WOUT, int CC, int OCB, int WOC, int NSLICE>
__global__ __launch_bounds__(256) void conv4x4s2_k(
    const float* __restrict__ in, const float* __restrict__ wT,
    float* __restrict__ out)
{
    constexpr int WIN = WOUT * 2;
    constexpr int NPXG = WOUT / 8, NOCG = COUT / OCB;
    static_assert(NPXG * NOCG == 256, "bad tile");
    constexpr int WUSE = 2 * WOUT + 2;
    constexpr int PADLEN = ((WUSE + (WUSE / 16 + 1) * 4) + 3) & ~3;
    __shared__ __align__(16) float ls_in[CC][4][PADLEN];
    __shared__ __align__(16) float ls_w[CC][16][COUT];

    int tid = threadIdx.x;
    int pxg = tid % NPXG, ocg = tid / NPXG;
    int x0 = pxg * 8, oc0 = ocg * OCB;
    int blk = blockIdx.x;
    int y = blk % WOUT; int rest = blk / WOUT;
    int slice = rest % NSLICE; int b = rest / NSLICE;
    int oc_base = slice * COUT;
    const float* inb = in + (size_t)b * CIN * WIN * WIN;

    float acc[OCB][8];
    #pragma unroll
    for (int o = 0; o < OCB; ++o)
        #pragma unroll
        for (int p = 0; p < 8; ++p) acc[o][p] = 0.f;

    for (int c0 = 0; c0 < CIN; c0 += CC) {
        __syncthreads();
        for (int i = tid; i < CC * 4 * WUSE; i += 256) {
            int xx = i % WUSE; int t = i / WUSE; int r = t & 3; int cc = t >> 2;
            int gy = 2 * y - 1 + r, gx = xx - 1;
            float v = 0.f;
            if ((unsigned)gy < (unsigned)WIN && (unsigned)gx < (unsigned)WIN)
                v = inb[(c0 + cc) * WIN * WIN + gy * WIN + gx];
            ls_in[cc][r][xx + ((xx >> 4) << 2)] = v;
        }
        const float* wsrc = wT + (size_t)c0 * 16 * WOC + oc_base;
        for (int i = tid; i < CC * 16 * COUT; i += 256) {
            int o = i % COUT; int tt = (i / COUT) % 16; int cc = i / (16 * COUT);
            ls_w[cc][tt][o] = wsrc[(cc * 16 + tt) * WOC + o];
        }
        __syncthreads();

        for (int cc = 0; cc < CC; ++cc) {
            const float* lw = &ls_w[cc][0][0];
            #pragma unroll
            for (int ky = 0; ky < 4; ++ky) {
                float rv[18];
                const float* base = &ls_in[cc][ky][20 * pxg];
                #pragma unroll
                for (int q = 0; q < 4; ++q) {
                    float4 v = *reinterpret_cast<const float4*>(base + 4 * q);
                    rv[4*q]=v.x; rv[4*q+1]=v.y; rv[4*q+2]=v.z; rv[4*q+3]=v.w;
                }
                rv[16] = base[20]; rv[17] = base[21];
                #pragma unroll
                for (int kx = 0; kx < 4; ++kx) {
                    const float* wp = lw + (ky * 4 + kx) * COUT + oc0;
                    float wv[OCB];
                    if constexpr (OCB == 4) {
                        float4 w4 = *reinterpret_cast<const float4*>(wp);
                        wv[0]=w4.x; wv[1]=w4.y; wv[2]=w4.z; wv[3]=w4.w;
                    } else {
                        float2 w2 = *reinterpret_cast<const float2*>(wp);
                        wv[0]=w2.x; wv[1]=w2.y;
                    }
                    #pragma unroll
                    for (int p = 0; p < 8; ++p) {
                        float iv = rv[2 * p + kx];
                        #pragma unroll
                        for (int o = 0; o < OCB; ++o)
                            acc[o][p] = fmaf(iv, wv[o], acc[o][p]);
                    }
                }
            }
        }
    }
    #pragma unroll
    for (int o = 0; o < OCB; ++o) {
        float* op = out + (((size_t)b * (COUT * NSLICE) + oc_base + oc0 + o) * WOUT + y) * WOUT + x0;
        #pragma unroll
        for (int q = 0; q < 2; ++q) {
            float4 v = make_float4(fmaxf(acc[o][4*q],0.f), fmaxf(acc[o][4*q+1],0.f),
                                   fmaxf(acc[o][4*q+2],0.f), fmaxf(acc[o][4*q+3],0.f));
            *reinterpret_cast<float4*>(op + 4 * q) = v;
        }
    }
}

// ---------------- deconv 4x4 s2 p1, 128->64, relu(in) folded, relu out ------
#define DECONV_TAPS(RV, KY)                                                   \
    {                                                                         \
        int ky_ = (KY);                                                       \
        _Pragma("unroll")                                                     \
        for (int kx = 0; kx < 4; ++kx) {                                      \
            float4 w4 = *reinterpret_cast<const float4*>(                     \
                lw + (ky_ * 4 + kx) * 64 + oc0);                              \
            float wv[4] = {w4.x, w4.y, w4.z, w4.w};                           \
            if (kx & 1) {                                                     \
                _Pragma("unroll")                                             \
                for (int ph = 0; ph < 4; ++ph) {                              \
                    float iv = RV[(kx == 1) ? (ph + 1) : ph];                 \
                    _Pragma("unroll")                                         \
                    for (int o = 0; o < 4; ++o)                               \
                        acc[o][2*ph] = fmaf(iv, wv[o], acc[o][2*ph]);         \
                }                                                             \
            } else {                                                          \
                _Pragma("unroll")                                             \
                for (int ph = 0; ph < 4; ++ph) {                              \
                    float iv = RV[(kx == 0) ? (ph + 2) : (ph + 1)];           \
                    _Pragma("unroll")                                         \
                    for (int o = 0; o < 4; ++o)                               \
                        acc[o][2*ph+1] = fmaf(iv, wv[o], acc[o][2*ph+1]);     \
                }                                                             \
            }                                                                 \
        }                                                                     \
    }

template<int CC>
__global__ __launch_bounds__(256) void deconv_k(
    const float* __restrict__ in, const float* __restrict__ wT,
    float* __restrict__ out)
{
    __shared__ __align__(16) float ls_in[CC][2][68];
    __shared__ __align__(16) float ls_w[CC][16][64];
    int tid = threadIdx.x;
    int pxg = tid & 15, ocg = tid >> 4;
    int x0 = pxg * 8, oc0 = ocg * 4, xh = pxg * 4;
    int oy = blockIdx.x & 127, b = blockIdx.x >> 7;
    int r1 = (oy + 1) >> 1;
    int ky0 = (oy + 1) & 1;
    const float* inb = in + (size_t)b * 128 * 4096;

    float acc[4][8];
    #pragma unroll
    for (int o = 0; o < 4; ++o)
        #pragma unroll
        for (int p = 0; p < 8; ++p) acc[o][p] = 0.f;

    for (int c0 = 0; c0 < 128; c0 += CC) {
        __syncthreads();
        for (int i = tid; i < CC * 2 * 66; i += 256) {
            int xx = i % 66; int t = i / 66; int rr = t & 1; int cc = t >> 1;
            int iy = r1 - 1 + rr, gx = xx - 1;
            float v = 0.f;
            if ((unsigned)iy < 64u && (unsigned)gx < 64u)
                v = fmaxf(inb[(c0 + cc) * 4096 + iy * 64 + gx], 0.f);
            ls_in[cc][rr][xx] = v;
        }
        const float* wsrc = wT + (size_t)c0 * 16 * 64;
        for (int i = tid; i < CC * 16 * 64; i += 256)
            (&ls_w[0][0][0])[i] = wsrc[i];
        __syncthreads();

        for (int cc = 0; cc < CC; ++cc) {
            float rvA[6], rvB[6];
            {
                const float* bA = &ls_in[cc][1][xh];
                float4 v = *reinterpret_cast<const float4*>(bA);
                rvA[0]=v.x; rvA[1]=v.y; rvA[2]=v.z; rvA[3]=v.w;
                rvA[4]=bA[4]; rvA[5]=bA[5];
                const float* bB = &ls_in[cc][0][xh];
                float4 u = *reinterpret_cast<const float4*>(bB);
                rvB[0]=u.x; rvB[1]=u.y; rvB[2]=u.z; rvB[3]=u.w;
                rvB[4]=bB[4]; rvB[5]=bB[5];
            }
            const float* lw = &ls_w[cc][0][0];
            DECONV_TAPS(rvA, ky0);
            DECONV_TAPS(rvB, ky0 + 2);
        }
    }
    #pragma unroll
    for (int o = 0; o < 4; ++o) {
        float* op = out + (((size_t)b * 64 + oc0 + o) * 128 + oy) * 128 + x0;
        #pragma unroll
        for (int q = 0; q < 2; ++q) {
            float4 v = make_float4(fmaxf(acc[o][4*q],0.f), fmaxf(acc[o][4*q+1],0.f),
                                   fmaxf(acc[o][4*q+2],0.f), fmaxf(acc[o][4*q+3],0.f));
            *reinterpret_cast<float4*>(op + 4 * q) = v;
        }
    }
}

// ---------------- fused bilinear-2x(align) + conv3x3 64->3 + 2*sigmoid-1 ----
template<int CC>
__global__ __launch_bounds__(256) void upconv_k(
    const float* __restrict__ in, const float* __restrict__ wT3,
    float* __restrict__ out)
{
    __shared__ __align__(16) float ls_u[CC][6][260];
    __shared__ float ls_w[64 * 27];
    int tid = threadIdx.x;
    int pxg = tid & 63, row = tid >> 6;
    int x0 = pxg * 4;
    int yblk = blockIdx.x & 63, b = blockIdx.x >> 6;
    int y0 = yblk * 4, y = y0 + row;
    const float SCL = 127.0f / 255.0f;
    const float* hb = in + (size_t)b * 64 * 16384;

    for (int i = tid; i < 1728; i += 256) ls_w[i] = wT3[i];

    float acc[3][4];
    #pragma unroll
    for (int o = 0; o < 3; ++o)
        #pragma unroll
        for (int p = 0; p < 4; ++p) acc[o][p] = 0.f;

    for (int c0 = 0; c0 < 64; c0 += CC) {
        __syncthreads();
        for (int i = tid; i < CC * 6 * 258; i += 256) {
            int xx = i % 258; int t = i / 258; int r = t % 6; int cc = t / 6;
            int uy = y0 - 1 + r, gx = xx - 1;
            float v = 0.f;
            if ((unsigned)uy < 256u && (unsigned)gx < 256u) {
                float py = uy * SCL;
                int ylo = (int)py; int yhi = min(ylo + 1, 127); float fy = py - ylo;
                float px = gx * SCL;
                int xlo = (int)px; int xhi = min(xlo + 1, 127); float fx = px - xlo;
                const float* hp = hb + (c0 + cc) * 16384 + ylo * 128;
                const float* hq = hb + (c0 + cc) * 16384 + yhi * 128;
                float a = hp[xlo], b2 = hp[xhi], c2 = hq[xlo], d2 = hq[xhi];
                float top = a + (b2 - a) * fx;
                float bot = c2 + (d2 - c2) * fx;
                v = top + (bot - top) * fy;
            }
            ls_u[cc][r][xx] = v;
        }
        __syncthreads();

        for (int cc = 0; cc < CC; ++cc) {
            #pragma unroll
            for (int j = 0; j < 3; ++j) {
                float rv[6];
                const float* base = &ls_u[cc][row + j][x0];
                float4 v = *reinterpret_cast<const float4*>(base);
                rv[0]=v.x; rv[1]=v.y; rv[2]=v.z; rv[3]=v.w;
                rv[4]=base[4]; rv[5]=base[5];
                #pragma unroll
                for (int i2 = 0; i2 < 3; ++i2) {
                    const float* wp = &ls_w[((c0 + cc) * 9 + (j * 3 + i2)) * 3];
                    float w0 = wp[0], w1 = wp[1], w2 = wp[2];
                    #pragma unroll
                    for (int p = 0; p < 4; ++p) {
                        float iv = rv[p + i2];
                        acc[0][p] = fmaf(iv, w0, acc[0][p]);
                        acc[1][p] = fmaf(iv, w1, acc[1][p]);
                        acc[2][p] = fmaf(iv, w2, acc[2][p]);
                    }
                }
            }
        }
    }
    #pragma unroll
    for (int o = 0; o < 3; ++o) {
        float4 v;
        v.x = 2.f / (1.f + expf(-acc[o][0])) - 1.f;
        v.y = 2.f / (1.f + expf(-acc[o][1])) - 1.f;
        v.z = 2.f / (1.f + expf(-acc[o][2])) - 1.f;
        v.w = 2.f / (1.f + expf(-acc[o][3])) - 1.f;
        float* op = out + (((size_t)b * 3 + o) * 256 + y) * 256 + x0;
        *reinterpret_cast<float4*>(op) = v;
    }
}

// ---------------- codebook prep (also zeroes counts) ----------------
__global__ void prep_codebook(const float* __restrict__ cb,
                              float* __restrict__ cbT, float* __restrict__ ce2,
                              unsigned int* __restrict__ counts)
{
    int k = blockIdx.x * 256 + threadIdx.x;
    if (k >= 1024) return;
    float s = 0.f;
    for (int d = 0; d < 128; ++d) {
        float v = cb[k * 128 + d];
        cbT[d * 1024 + k] = v;
        s = fmaf(v, v, s);
    }
    ce2[k] = s;
    counts[k] = 0u;
}

// ---------------- fused VQ: 32 px/block, 1024 blocks ----------------
__global__ __launch_bounds__(512) void vq_fused(
    const float* __restrict__ z, const float* __restrict__ cb,
    const float* __restrict__ cbT, const float* __restrict__ ce2,
    unsigned int* __restrict__ counts, float* __restrict__ q,
    double* __restrict__ partial)
{
    __shared__ float zl[128][32];
    __shared__ int sidx[32];
    __shared__ float red[8];

    int tid = threadIdx.x;
    int lane = tid & 63;
    int w = tid >> 6;
    int b = blockIdx.x >> 7;
    int p0 = (blockIdx.x & 127) * 32;

    for (int i = tid; i < 4096; i += 512) {
        int d = i >> 5, pix = i & 31;
        zl[d][pix] = z[((size_t)b * 128 + d) * 4096 + p0 + pix];
    }
    __syncthreads();

    float best[4]; int bidx[4];
    #pragma unroll
    for (int j = 0; j < 4; ++j) { best[j] = 3.4e38f; bidx[j] = 0; }

    for (int kt = 0; kt < 2; ++kt) {
        int k0 = kt * 512 + lane * 8;
        float acc[4][8];
        #pragma unroll
        for (int p = 0; p < 4; ++p)
            #pragma unroll
            for (int c = 0; c < 8; ++c) acc[p][c] = 0.f;

        const float* cbp = cbT + k0;
        for (int d = 0; d < 128; ++d) {
            float4 zq = *reinterpret_cast<const float4*>(&zl[d][w * 4]);
            float zv[4] = {zq.x, zq.y, zq.z, zq.w};
            float4 c0 = *reinterpret_cast<const float4*>(cbp + (size_t)d * 1024);
            float4 c1 = *reinterpret_cast<const float4*>(cbp + (size_t)d * 1024 + 4);
            float cv[8] = {c0.x, c0.y, c0.z, c0.w, c1.x, c1.y, c1.z, c1.w};
            #pragma unroll
            for (int p = 0; p < 4; ++p)
                #pragma unroll
                for (int c = 0; c < 8; ++c)
                    acc[p][c] = fmaf(zv[p], cv[c], acc[p][c]);
        }
        float4 e0 = *reinterpret_cast<const float4*>(ce2 + k0);
        float4 e1 = *reinterpret_cast<const float4*>(ce2 + k0 + 4);
        float ev[8] = {e0.x, e0.y, e0.z, e0.w, e1.x, e1.y, e1.z, e1.w};
        #pragma unroll
        for (int c = 0; c < 8; ++c) {
            #pragma unroll
            for (int p = 0; p < 4; ++p) {
                float dist = ev[c] - 2.f * acc[p][c];
                if (dist < best[p]) { best[p] = dist; bidx[p] = k0 + c; }
            }
        }
    }

    #pragma unroll
    for (int j = 0; j < 4; ++j) {
        float bv = best[j]; int bi = bidx[j];
        #pragma unroll
        for (int off = 32; off > 0; off >>= 1) {
            float ov = __shfl_xor(bv, off);
            int   oi = __shfl_xor(bi, off);
            if (ov < bv || (ov == bv && oi < bi)) { bv = ov; bi = oi; }
        }
        if (lane == 0) {
            sidx[w * 4 + j] = bi;
            atomicAdd(&counts[bi], 1u);
        }
    }
    __syncthreads();

    int pix = tid & 31, dg = tid >> 5;
    int kidx = sidx[pix];
    const float* crow = cb + (size_t)kidx * 128 + dg * 8;
    float sq = 0.f;
    size_t qbase = ((size_t)b * 128 + dg * 8) * 4096 + p0 + pix;
    float4 c4a = *reinterpret_cast<const float4*>(crow);
    float4 c4b = *reinterpret_cast<const float4*>(crow + 4);
    float vals[8] = {c4a.x, c4a.y, c4a.z, c4a.w, c4b.x, c4b.y, c4b.z, c4b.w};
    #pragma unroll
    for (int jj = 0; jj < 8; ++jj) {
        float qv = vals[jj];
        float zv = zl[dg * 8 + jj][pix];
        float df = qv - zv;
        sq = fmaf(df, df, sq);
        q[qbase + (size_t)jj * 4096] = qv;
    }
    #pragma unroll
    for (int off = 32; off > 0; off >>= 1) sq += __shfl_xor(sq, off);
    if (lane == 0) red[w] = sq;
    __syncthreads();
    if (tid == 0) {
        double s = 0.0;
        #pragma unroll
        for (int ww = 0; ww < 8; ++ww) s += (double)red[ww];
        partial[blockIdx.x] = s;
    }
}

// ---------------- finalize ----------------
__global__ __launch_bounds__(256) void finalize_kernel(
    const double* __restrict__ partial, const unsigned int* __restrict__ counts,
    float* __restrict__ dout)
{
    __shared__ double sd[256];
    __shared__ double lossSh;
    int tid = threadIdx.x;
    double s = 0.0;
    for (int i = tid; i < 1024; i += 256) s += partial[i];
    sd[tid] = s; __syncthreads();
    for (int off = 128; off > 0; off >>= 1) {
        if (tid < off) sd[tid] += sd[tid + off];
        __syncthreads();
    }
    if (tid == 0) lossSh = CC_COST * sd[0] / 4194304.0;
    __syncthreads();

    double h = 0.0;
    for (int k = tid; k < 1024; k += 256) {
        double pp = (double)counts[k] / 32768.0;
        h += pp * log(pp + 1e-10);
    }
    sd[tid] = h; __syncthreads();
    for (int off = 128; off > 0; off >>= 1) {
        if (tid < off) sd[tid] += sd[tid + off];
        __syncthreads();
    }
    if (tid == 0) {
        dout[0]       = (float)lossSh;
        dout[1572865] = (float)exp(-sd[0]);
    }
}

// ===========================================================================
extern "C" void kernel_launch(void* const* d_in, const int* in_sizes, int n_in,
                              void* d_out, int out_size, void* d_ws, size_t ws_size,
                              hipStream_t stream)
{
    const float* x        = (const float*)d_in[0];
    const float* enc_c1   = (const float*)d_in[1];
    const float* enc_c2   = (const float*)d_in[2];
    const float* enc_c3   = (const float*)d_in[3];
    const float* enc_r1a  = (const float*)d_in[4];
    const float* enc_r1b  = (const float*)d_in[5];
    const float* enc_r2a  = (const float*)d_in[6];
    const float* enc_r2b  = (const float*)d_in[7];
    const float* pre_vq_w = (const float*)d_in[8];
    const float* codebook = (const float*)d_in[9];
    const float* dec_c1   = (const float*)d_in[10];
    const float* dec_r1a  = (const float*)d_in[11];
    const float* dec_r1b  = (const float*)d_in[12];
    const float* dec_r2a  = (const float*)d_in[13];
    const float* dec_r2b  = (const float*)d_in[14];
    const float* dec_dc   = (const float*)d_in[15];
    const float* dec_c3   = (const float*)d_in[16];
    float* dout = (float*)d_out;

    char* wsp = (char*)d_ws;
    auto alloc = [&](size_t bytes) {
        void* p = (void*)wsp;
        wsp += (bytes + 255) & ~(size_t)255;
        return p;
    };
    float* h1   = (float*)alloc(8ull*64*128*128*4);   // 32MB; also qb alias
    float* bufA = (float*)alloc(8ull*128*64*64*4);    // 16MB; also zb alias
    float* bufB = (float*)alloc(8ull*128*64*64*4);    // 16MB
    float* bufT = (float*)alloc(8ull*32*64*64*4);     // 4MB
    float* cbT  = (float*)alloc(128*1024*4);
    float* ce2  = (float*)alloc(1024*4);
    unsigned int* counts = (unsigned int*)alloc(1024*4);
    double* partial = (double*)alloc(1024*8);
    float* wt_ec1  = (float*)alloc(3072*4);
    float* wt_ec2  = (float*)alloc(131072*4);
    float* wt_er1a = (float*)alloc(36864*4);
    float* wt_er1b = (float*)alloc(4096*4);
    float* wt_er2a = (float*)alloc(36864*4);
    float* wt_er2b = (float*)alloc(4096*4);
    float* wt_pvq  = (float*)alloc(16384*4);
    float* wt_dr1a = (float*)alloc(36864*4);
    float* wt_dr1b = (float*)alloc(4096*4);
    float* wt_dr2a = (float*)alloc(36864*4);
    float* wt_dr2b = (float*)alloc(4096*4);
    float* wt_ddc  = (float*)alloc(131072*4);
    float* wt_dc3  = (float*)alloc(1728*4);
    unsigned short* w3hi_e = (unsigned short*)alloc(147456*2);
    unsigned short* w3lo_e = (unsigned short*)alloc(147456*2);
    unsigned short* w3hi_d = (unsigned short*)alloc(147456*2);
    unsigned short* w3lo_d = (unsigned short*)alloc(147456*2);
    float* zb = bufA;   // alias: pre_vq out, dead before dec_c1 writes bufA
    float* qb = h1;     // alias: dead before deconv overwrites h1

    auto nb = [](int n) { return (n + 255) / 256; };

    // VQ prep (+counts zero)
    prep_codebook<<<4, 256, 0, stream>>>(codebook, cbT, ce2, counts);

    // batched weight transforms (13 jobs; conv3x3 layers use MFMA split path)
    WtJobs J;
    const float* srcs[13] = {enc_c1, enc_c2, enc_r1a, enc_r1b, enc_r2a,
                             enc_r2b, pre_vq_w, dec_r1a, dec_r1b,
                             dec_r2a, dec_r2b, dec_dc, dec_c3};
    float* dsts[13] = {wt_ec1, wt_ec2, wt_er1a, wt_er1b, wt_er2a,
                       wt_er2b, wt_pvq, wt_dr1a, wt_dr1b,
                       wt_dr2a, wt_dr2b, wt_ddc, wt_dc3};
    int couts[13] = {64, 128, 32, 128, 32, 128, 128, 32, 128, 32, 128, 64, 3};
    int cins[13]  = {3, 64, 128, 32, 128, 32, 128, 128, 32, 128, 32, 128, 64};
    int kks[13]   = {16, 16, 9, 1, 9, 1, 1, 9, 1, 9, 1, 16, 9};
    int kinds[13] = {0, 0, 0, 0, 0, 0, 0, 0, 0, 0, 0, 1, 2};
    int off = 0;
    for (int j = 0; j < 13; ++j) {
        J.src[j] = srcs[j]; J.dst[j] = dsts[j];
        J.cout[j] = couts[j]; J.cin[j] = cins[j]; J.kk[j] = kks[j];
        J.kind[j] = kinds[j];
        J.blk0[j] = off;
        off += (couts[j] * cins[j] * kks[j] + 255) / 256;
    }
    for (int j = 13; j < 16; ++j) J.blk0[j] = off + 1000000;  // sentinels
    J.blk0[13] = off;
    wt_batch_k<<<off, 256, 0, stream>>>(J);
    wt_split_k<<<576, 256, 0, stream>>>(enc_c3, w3hi_e, w3lo_e);
    wt_split_k<<<576, 256, 0, stream>>>(dec_c1, w3hi_d, w3lo_d);

    // ---- encoder ----
    conv4x4s2_k<3, 64, 128, 3, 4, 64, 1><<<1024, 256, 0, stream>>>(x, wt_ec1, h1);
    conv4x4s2_k<64, 64, 64, 4, 2, 128, 2><<<1024, 256, 0, stream>>>(h1, wt_ec2, bufA);
    conv3x3_mfma<<<256, 512, 0, stream>>>(bufA, w3hi_e, w3lo_e, bufB);
    conv3x3_res_k<<<512, 512, 0, stream>>>(bufB, wt_er1a, bufT);
    conv1x1_k<32, 128, 32, true, true><<<512, 256, 0, stream>>>(bufT, wt_er1b, bufB, bufB);
    conv3x3_res_k<<<512, 512, 0, stream>>>(bufB, wt_er2a, bufT);
    conv1x1_k<32, 128, 32, true, true><<<512, 256, 0, stream>>>(bufT, wt_er2b, bufB, bufB);
    conv1x1_k<128, 128, 32, true, false><<<512, 256, 0, stream>>>(bufB, wt_pvq, bufB, zb);

    // ---- VQ ----
    vq_fused<<<1024, 512, 0, stream>>>(zb, codebook, cbT, ce2, counts, qb, partial);

    // ---- decoder ----
    conv3x3_mfma<<<256, 512, 0, stream>>>(qb, w3hi_d, w3lo_d, bufA);
    conv3x3_res_k<<<512, 512, 0, stream>>>(bufA, wt_dr1a, bufT);
    conv1x1_k<32, 128, 32, true, true><<<512, 256, 0, stream>>>(bufT, wt_dr1b, bufA, bufA);
    conv3x3_res_k<<<512, 512, 0, stream>>>(bufA, wt_dr2a, bufT);
    conv1x1_k<32, 128, 32, true, true><<<512, 256, 0, stream>>>(bufT, wt_dr2b, bufA, bufA);
    deconv_k<4><<<1024, 256, 0, stream>>>(bufA, wt_ddc, h1);
    upconv_k<2><<<512, 256, 0, stream>>>(h1, wt_dc3, dout + 1);

    // ---- scalars ----
    finalize_kernel<<<1, 256, 0, stream>>>(partial, counts, dout);
}